// Round 13
// baseline (2322.146 us; speedup 1.0000x reference)
//
#include <hip/hip_runtime.h>
#include <stdint.h>

#define N_TOK 2048
#define IN_D  1024
#define NEXP  10
#define NSTEP 4
#define INNER 768
#define SHD   2048
#define DMAX  3328
#define DSUM  24064

typedef __attribute__((ext_vector_type(4))) float f32x4;
typedef __attribute__((ext_vector_type(8))) short bf16x8;

__device__ const int c_dims[10] = {1536,2048,2560,3072,1792,2304,2816,2048,2560,3328};
__device__ const int c_offs[10] = {0,1536,3584,6144,9216,11008,13312,16128,18176,20736};
__device__ const int c_acts[10] = {0,1,2,3,4,5,6,7,0,1};
__device__ const int c_cum[11]  = {0,12,28,48,72,86,104,126,142,162,188};

__device__ __forceinline__ float wred(float v){
#pragma unroll
  for (int s = 32; s > 0; s >>= 1) v += __shfl_xor(v, s, 64);
  return v;
}
__device__ __forceinline__ float wmax(float v){
#pragma unroll
  for (int s = 32; s > 0; s >>= 1) v = fmaxf(v, __shfl_xor(v, s, 64));
  return v;
}
__device__ __forceinline__ float bf2f(uint16_t u){
  return __uint_as_float(((uint32_t)u) << 16);
}
__device__ __forceinline__ uint16_t f2bf(float f){
  uint32_t u = __float_as_uint(f);
  return (uint16_t)((u + 0x7FFFu + ((u >> 16) & 1u)) >> 16);
}
// float -> OCP e4m3 (RNE, saturate-finite)
__device__ __forceinline__ uint8_t f2fp8(float f){
  uint32_t u = __float_as_uint(f);
  uint8_t sign = (uint8_t)((u >> 24) & 0x80u);
  uint32_t absu = u & 0x7FFFFFFFu;
  if (absu >= 0x43E00000u) return sign | 0x7Eu;
  if (absu < 0x3C800000u){
    float af = __uint_as_float(absu);
    int q = (int)rintf(af * 512.0f);
    return sign | (uint8_t)q;
  }
  uint32_t mant = absu & 0x7FFFFFu;
  uint32_t exp = absu >> 23;
  uint32_t lsb = (mant >> 20) & 1u;
  uint32_t rounded = mant + 0x7FFFFu + lsb;
  if (rounded >= 0x800000u){ exp += 1; rounded = 0; }
  uint32_t e8 = exp - 120;
  uint32_t m8 = (rounded >> 20) & 7u;
  if (e8 > 15u || (e8 == 15u && m8 == 7u)) return sign | 0x7Eu;
  return sign | (uint8_t)((e8 << 3) | m8);
}
__device__ __forceinline__ void gload16(const uint16_t* g, uint16_t* l){
  __builtin_amdgcn_global_load_lds(
      (const __attribute__((address_space(1))) uint32_t*)(const void*)g,
      (__attribute__((address_space(3))) uint32_t*)(void*)l, 16, 0, 0);
}
__device__ __forceinline__ void gload16b(const void* g, void* l){
  __builtin_amdgcn_global_load_lds(
      (const __attribute__((address_space(1))) uint32_t*)g,
      (__attribute__((address_space(3))) uint32_t*)l, 16, 0, 0);
}

__device__ __forceinline__ float actf(int a, float x){
  switch(a){
    case 0: return x / (1.f + expf(-x));
    case 1: return 0.5f * x * (1.f + erff(x * 0.7071067811865475f));
    case 2: { float sp = fmaxf(x,0.f) + log1pf(expf(-fabsf(x)));
              return x * tanhf(sp); }
    case 3: return fmaxf(x, 0.f);
    case 4: return x > 0.f ? 1.0507009873554805f * x
                           : 1.7580993408473768f * expm1f(x);
    case 5: return tanhf(x);
    case 6: return fmaxf(x,0.f) + log1pf(expf(-fabsf(x)));
    default: return x > 0.f ? x : expm1f(x);
  }
}

// ---------------- f32 -> (hi, lo) bf16 split ------------------------------------
__global__ void split_kernel(const float* __restrict__ src, uint16_t* __restrict__ hi,
                             uint16_t* __restrict__ lo, size_t n){
  size_t i = ((size_t)blockIdx.x * blockDim.x + threadIdx.x) << 2;
  size_t stride = ((size_t)gridDim.x * blockDim.x) << 2;
  for (; i < n; i += stride){
    float4 v = *(const float4*)(src + i);
    ushort4 h, l;
    h.x = f2bf(v.x); l.x = f2bf(v.x - bf2f(h.x));
    h.y = f2bf(v.y); l.y = f2bf(v.y - bf2f(h.y));
    h.z = f2bf(v.z); l.z = f2bf(v.z - bf2f(h.z));
    h.w = f2bf(v.w); l.w = f2bf(v.w - bf2f(h.w));
    *(ushort4*)(hi + i) = h;
    *(ushort4*)(lo + i) = l;
  }
}
__global__ void split_strided(const float* __restrict__ src, uint16_t* __restrict__ hi,
                              uint16_t* __restrict__ lo, int rows, int cols, int ldd){
  int nq = rows * (cols >> 2);
  for (int i = blockIdx.x * blockDim.x + threadIdx.x; i < nq; i += gridDim.x * blockDim.x){
    int r = i / (cols >> 2), c4 = (i - r * (cols >> 2)) << 2;
    float4 v = *(const float4*)(src + (size_t)r * cols + c4);
    ushort4 h, l;
    h.x = f2bf(v.x); l.x = f2bf(v.x - bf2f(h.x));
    h.y = f2bf(v.y); l.y = f2bf(v.y - bf2f(h.y));
    h.z = f2bf(v.z); l.z = f2bf(v.z - bf2f(h.z));
    h.w = f2bf(v.w); l.w = f2bf(v.w - bf2f(h.w));
    size_t d = (size_t)r * ldd + c4;
    *(ushort4*)(hi + d) = h;
    *(ushort4*)(lo + d) = l;
  }
}
__global__ void cvt_fp8_kernel(const float* __restrict__ src, uint8_t* __restrict__ dst, size_t n){
  size_t i = ((size_t)blockIdx.x * blockDim.x + threadIdx.x) << 2;
  size_t stride = ((size_t)gridDim.x * blockDim.x) << 2;
  for (; i < n; i += stride){
    float4 v = *(const float4*)(src + i);
    uchar4 q;
    q.x = f2fp8(v.x); q.y = f2fp8(v.y); q.z = f2fp8(v.z); q.w = f2fp8(v.w);
    *(uchar4*)(dst + i) = q;
  }
}
__global__ void fill1_kernel(float* __restrict__ p, int n){
  int i = blockIdx.x * blockDim.x + threadIdx.x;
  if (i < n) p[i] = 1.f;
}

// ---------------- K2 = keys @ mqw  [24,1024] ------------------------------------
__global__ __launch_bounds__(256)
void k2_kernel(const float* __restrict__ keys, const float* __restrict__ mqw,
               float* __restrict__ K2){
  int m = blockIdx.x;
  int j = blockIdx.y * 256 + threadIdx.x;
  float acc = 0.f;
  for (int d = 0; d < 1024; d++)
    acc = fmaf(keys[m * 1024 + d], mqw[d * 1024 + j], acc);
  K2[m * 1024 + j] = acc;
}

// ---------------- route weight builder: 4 x [128 rows x 3072] -------------------
__global__ void build_routew(const float* __restrict__ msw, const float* __restrict__ mmw,
                             const float* __restrict__ bw, const float* __restrict__ wgw,
                             const float* __restrict__ hw, const float* __restrict__ mow,
                             const float* __restrict__ dow, uint16_t* __restrict__ Wh,
                             uint16_t* __restrict__ Wl){
  const int TOT = 4 * 128 * 3072;
  for (int i = blockIdx.x * 256 + threadIdx.x; i < TOT; i += gridDim.x * 256){
    int t = i / (128 * 3072);
    int rem = i - t * (128 * 3072);
    int row = rem / 3072, col = rem - row * 3072;
    float v = 0.f;
    if (row < 40){ if (col < 1024) v = msw[row * 1024 + col]; }
    else if (row < 44){ if (col < 1024) v = mmw[(row - 40) * 1024 + col]; }
    else if (row < 48){ if (col < 1024) v = bw[(row - 44) * 1024 + col]; }
    else if (row < 72){ if (col < 2048) v = wgw[(row - 48) * 2048 + col]; }
    else if (row == 72){
      if (col < 1024) v = hw[t * 1024 + col];
      else if (col < 2048) v = 0.2f * hw[t * 1024 + col - 1024];
      else v = 0.1f * hw[t * 1024 + col - 2048];
    }
    else if (row < 83){ if (col >= 1024 && col < 2048) v = mow[(row - 73) * 1024 + col - 1024]; }
    else if (row < 93){ if (col >= 2048) v = dow[(row - 83) * 1024 + col - 2048]; }
    else if (row < 103){ if (col < 1024) v = mow[(row - 93) * 1024 + col]; }
    uint16_t h = f2bf(v);
    Wh[i] = h; Wl[i] = f2bf(v - bf2f(h));
  }
}

// ================= device cores ==================================================
enum { EPI_GELU=0, EPI_CUR=1, EPI_PRE=2, EPI_QROUTE=3 };

template<int EPI>
__device__ __forceinline__
void gemm_core(uint16_t (*sm)[2][4096], int bx, int by,
               const uint16_t* __restrict__ Ah, const uint16_t* __restrict__ Al, int lda,
               const uint16_t* __restrict__ Wh, const uint16_t* __restrict__ Wl,
               const uint16_t* __restrict__ W2h, const uint16_t* __restrict__ W2l,
               const float* __restrict__ bias, const float* __restrict__ addend,
               float* __restrict__ D0, float* __restrict__ D1, float* __restrict__ D2,
               float* __restrict__ D3, uint8_t* __restrict__ o8,
               uint16_t* __restrict__ oH, uint16_t* __restrict__ oL,
               int K, int D)
{
  int tid = threadIdx.x, lane = tid & 63, wave = tid >> 6;
  int wr = wave >> 1, wc = wave & 1;
  int arow = lane & 15, agrp = lane >> 4;
  int rowBase = by * 128;
  bool isRoute = (EPI == EPI_QROUTE) && (bx < 4);
  const uint16_t* Wsh = isRoute ? W2h : Wh;
  const uint16_t* Wsl = isRoute ? W2l : Wl;
  int wst     = isRoute ? 3072 : K;
  int colBase = isRoute ? 0 : ((EPI == EPI_QROUTE ? bx - 4 : bx) * 128);
  int kBase   = isRoute ? bx * 768 : 0;
  int kLen    = isRoute ? 768 : K;
  f32x4 acc[4][4];
#pragma unroll
  for (int m = 0; m < 4; m++)
#pragma unroll
    for (int n = 0; n < 4; n++){ f32x4 z = {0.f,0.f,0.f,0.f}; acc[m][n] = z; }

#define STAGE_G(buf, k0) do { \
  _Pragma("unroll") \
  for (int s = 0; s < 2; s++){ \
    int u = tid + s * 256; \
    int rr = u >> 2; \
    int ch = (u & 3) ^ ((rr >> 1) & 3); \
    size_t ga = (size_t)(rowBase + rr) * lda + kBase + (k0) + ch * 8; \
    size_t gw = (size_t)(colBase + rr) * wst + kBase + (k0) + ch * 8; \
    gload16(&Ah[ga], &sm[0][buf][u << 3]); \
    gload16(&Al[ga], &sm[1][buf][u << 3]); \
    gload16(&Wsh[gw], &sm[2][buf][u << 3]); \
    gload16(&Wsl[gw], &sm[3][buf][u << 3]); \
  } } while(0)

  int nk = kLen >> 5;
  STAGE_G(0, 0);
  if (nk > 1) STAGE_G(1, 32);
  int perm = (arow >> 1) & 3;
#pragma unroll 1
  for (int ki = 0; ki < nk; ki++){
    int cb = ki & 1;
    if (ki + 1 < nk) asm volatile("s_waitcnt vmcnt(8)" ::: "memory");
    else             asm volatile("s_waitcnt vmcnt(0)" ::: "memory");
    __builtin_amdgcn_s_barrier();
    bf16x8 ah[4], al[4], bh[4], bl[4];
#pragma unroll
    for (int m = 0; m < 4; m++){
      int u = ((wr*64 + m*16 + arow) << 2) + (agrp ^ perm);
      ah[m] = *(const bf16x8*)&sm[0][cb][u << 3];
      al[m] = *(const bf16x8*)&sm[1][cb][u << 3];
    }
#pragma unroll
    for (int n = 0; n < 4; n++){
      int u = ((wc*64 + n*16 + arow) << 2) + (agrp ^ perm);
      bh[n] = *(const bf16x8*)&sm[2][cb][u << 3];
      bl[n] = *(const bf16x8*)&sm[3][cb][u << 3];
    }
#pragma unroll
    for (int m = 0; m < 4; m++)
#pragma unroll
      for (int n = 0; n < 4; n++){
        acc[m][n] = __builtin_amdgcn_mfma_f32_16x16x32_bf16(ah[m], bh[n], acc[m][n], 0, 0, 0);
        acc[m][n] = __builtin_amdgcn_mfma_f32_16x16x32_bf16(ah[m], bl[n], acc[m][n], 0, 0, 0);
        acc[m][n] = __builtin_amdgcn_mfma_f32_16x16x32_bf16(al[m], bh[n], acc[m][n], 0, 0, 0);
      }
    __builtin_amdgcn_s_barrier();
    asm volatile("" ::: "memory");
    if (ki + 2 < nk) STAGE_G(cb, (ki + 2) << 5);
  }
#undef STAGE_G
#pragma unroll
  for (int m = 0; m < 4; m++){
#pragma unroll
    for (int n = 0; n < 4; n++){
      int col = colBase + wc*64 + n*16 + arow;
#pragma unroll
      for (int r2 = 0; r2 < 4; r2++){
        int row = rowBase + wr*64 + m*16 + agrp*4 + r2;
        float v = acc[m][n][r2];
        if (EPI == EPI_GELU){
          v += bias[col];
          v = 0.5f * v * (1.f + erff(v * 0.7071067811865475f));
          size_t idx = (size_t)row * D + col;
          uint16_t h = f2bf(v); oH[idx] = h; oL[idx] = f2bf(v - bf2f(h));
        }
        if (EPI == EPI_CUR){
          v += bias[col] + addend[(size_t)row * 1024 + col];
          D0[(size_t)row * 1024 + col] = v;
          size_t idx = (size_t)row * 3072 + col;
          uint16_t h = f2bf(v); oH[idx] = h; oL[idx] = f2bf(v - bf2f(h));
          o8[(size_t)row * 1024 + col] = f2fp8(v);
        }
        if (EPI == EPI_PRE){
          if (col < 2048) D0[(size_t)row * 2048 + col] = v / (1.f + expf(-v));
          else D1[(size_t)row * 128 + col - 2048] = v;
        }
        if (EPI == EPI_QROUTE){
          if (isRoute){
            D3[((size_t)bx * N_TOK + row) * 128 + col] = v;
          } else {
            if (col < 1024) D0[(size_t)row * 1024 + col] = v;
            else if (col < 4096) D1[(size_t)row * 3072 + col - 1024] = v + bias[col - 1024];
            else if (col < 4160) D2[(size_t)row * 128 + col - 4096] = v;
          }
        }
      }
    }
  }
}

// fp8 expert core: persistent depth-3 pipeline, both-sides 16B swizzle
__device__ __forceinline__
void expert_core(uint8_t* smem, int ex, int ey,
                 const uint8_t* __restrict__ A8, const uint8_t* __restrict__ U8,
                 const int* __restrict__ cnt, const int* __restrict__ gidx,
                 uint16_t* __restrict__ HH)
{
  int e = 0;
#pragma unroll
  for (int i = 1; i < 11; i++) if (ey >= c_cum[i]) e = i;
  int ct = ey - c_cum[e];
  int dcols = c_dims[e];
  int ne = cnt[e];
  const uint8_t* W = U8 + (size_t)e * DMAX * IN_D + (size_t)ct * 128 * IN_D;

  int tid = threadIdx.x, lane = tid & 63, wave = tid >> 6;
  int wr = wave >> 1, wc = wave & 1;
  int arow = lane & 15, agrp = lane >> 4;
  int actid = c_acts[e];
  size_t base_e = (size_t)N_TOK * c_offs[e];
  int rHalf = tid >> 1;
  // pre-swizzled global source half (inverts the read swizzle)
  int h16 = (((tid & 1) ^ ((tid >> 3) & 1)) << 4);
  // lane-constant read offset within the 32B row-pair
  int off = ((((agrp >> 1) ^ ((arow >> 2) & 1)) << 4) | ((agrp & 1) << 3));

#define STAGE_E(b, k0) do { \
    gload16b(&A8[(size_t)tok * IN_D + (k0) + h16], &smem[(b)*8192 + tid*16]); \
    gload16b(&W[(size_t)rHalf * IN_D + (k0) + h16], &smem[(b)*8192 + 4096 + tid*16]); \
  } while(0)

#pragma unroll 1
  for (int rowBase = ex * 128; rowBase < ne; rowBase += 4 * 128){
    int slot = rowBase + rHalf;
    int tok = (slot < ne) ? gidx[e * N_TOK + slot] : 0;

    f32x4 acc[4][4];
#pragma unroll
    for (int m = 0; m < 4; m++)
#pragma unroll
      for (int n = 0; n < 4; n++){ f32x4 z = {0.f,0.f,0.f,0.f}; acc[m][n] = z; }

    STAGE_E(0, 0);
    STAGE_E(1, 32);
    STAGE_E(2, 64);
    int cb = 0;
#pragma unroll 1
    for (int ki = 0; ki < 32; ki++){
      if (ki < 30)       asm volatile("s_waitcnt vmcnt(4)" ::: "memory");
      else if (ki == 30) asm volatile("s_waitcnt vmcnt(2)" ::: "memory");
      else               asm volatile("s_waitcnt vmcnt(0)" ::: "memory");
      __builtin_amdgcn_s_barrier();
      long a[4], b[4];
#pragma unroll
      for (int m = 0; m < 4; m++)
        a[m] = *(const long*)&smem[cb*8192 + (wr*64 + m*16 + arow)*32 + off];
#pragma unroll
      for (int n = 0; n < 4; n++)
        b[n] = *(const long*)&smem[cb*8192 + 4096 + (wc*64 + n*16 + arow)*32 + off];
#pragma unroll
      for (int m = 0; m < 4; m++)
#pragma unroll
        for (int n = 0; n < 4; n++)
          acc[m][n] = __builtin_amdgcn_mfma_f32_16x16x32_fp8_fp8(a[m], b[n], acc[m][n], 0, 0, 0);
      __builtin_amdgcn_s_barrier();
      asm volatile("" ::: "memory");
      if (ki + 3 < 32) STAGE_E(cb, (ki + 3) << 5);
      cb = (cb == 2) ? 0 : cb + 1;
    }
    uint16_t* Ht = (uint16_t*)smem;
#pragma unroll
    for (int m = 0; m < 4; m++){
      int rb0 = wr*64 + m*16 + agrp*4;
#pragma unroll
      for (int n = 0; n < 4; n++){
        int col = wc*64 + n*16 + arow;
#pragma unroll
        for (int r2 = 0; r2 < 4; r2++){
          int row = rb0 + r2;
          float v = actf(actid, acc[m][n][r2]);
          Ht[row * 128 + (col ^ ((row & 7) << 3))] = f2bf(v);
        }
      }
    }
    __syncthreads();
#pragma unroll
    for (int i = 0; i < 8; i++){
      int c = tid + i * 256;
      int row = c >> 4, chunk = c & 15;
      int schunk = (chunk & 8) | ((chunk ^ row) & 7);
      int4 val = *(const int4*)&Ht[row * 128 + schunk * 8];
      *(int4*)&HH[base_e + (size_t)(rowBase + row) * dcols
                  + (size_t)ct * 128 + chunk * 8] = val;
    }
    __syncthreads();
  }
#undef STAGE_E
}

// ctx core: mem softmax, depth attn, mctx/dctx/enriched/LN for step t
__device__ __forceinline__
void ctx_core(int row, int t,
              const float* __restrict__ qaux, const float* __restrict__ dqbuf,
              const float* __restrict__ Ac, const float* __restrict__ W0,
              const float* __restrict__ W1, const float* __restrict__ W2,
              const float* __restrict__ mvi,
              const float* __restrict__ t0, const float* __restrict__ t1,
              const float* __restrict__ t2, const float* __restrict__ cur,
              const float* __restrict__ sab, const float* __restrict__ sbw,
              const float* __restrict__ sbb, const float* __restrict__ lng,
              const float* __restrict__ lnbv,
              float* __restrict__ enr, uint16_t* __restrict__ lnh,
              uint16_t* __restrict__ lnl, uint16_t* __restrict__ Arh,
              uint16_t* __restrict__ Arl)
{
  int tid = threadIdx.x;
  __shared__ float su[24], ss[3], s40[40], red[12], redm[8];
  if (tid < 64){
    float pj = (tid < 24) ? qaux[(size_t)row * 128 + tid] * 0.03125f : -1e30f;
    float mx = wmax(pj);
    float ex = (tid < 24) ? expf(pj - mx) : 0.f;
    float sum = wred(ex);
    float attn = ex / sum;
    if (tid < 24) su[tid] = attn * Ac[row * 24 + tid];
    float w0v = (t > 0 && tid < 24) ? W0[row * 24 + tid] : 0.f;
    float s0 = wred(attn * w0v);
    float w1v = (t > 1 && tid < 24) ? W1[row * 24 + tid] : 0.f;
    float s1 = wred(attn * w1v);
    float w2v = (t > 2 && tid < 24) ? W2[row * 24 + tid] : 0.f;
    float s2 = wred(attn * w2v);
    if (tid == 0){ ss[0] = s0; ss[1] = s1; ss[2] = s2; }
    if (tid < 40) s40[tid] = tanhf(qaux[(size_t)row * 128 + 24 + tid] + sab[tid]);
  }
  size_t tb = (size_t)row * 3072;
  if (t > 0){
    float a0 = 0.f, a1 = 0.f, a2 = 0.f;
#pragma unroll
    for (int j = 0; j < 4; j++){
      int d = tid + j * 256;
      float dq = dqbuf[(size_t)row * 1024 + d];
      a0 = fmaf(dq, t0[tb + d], a0);
      if (t > 1) a1 = fmaf(dq, t1[tb + d], a1);
      if (t > 2) a2 = fmaf(dq, t2[tb + d], a2);
    }
    a0 = wred(a0); a1 = wred(a1); a2 = wred(a2);
    if ((tid & 63) == 0){ int w = tid >> 6; red[w] = a0; red[4+w] = a1; red[8+w] = a2; }
  }
  __syncthreads();
  float e0 = 0.f, e1 = 0.f, e2 = 0.f;
  if (t > 0){
    float A0 = (red[0]+red[1]+red[2]+red[3]) * 0.03125f;
    float A1 = (red[4]+red[5]+red[6]+red[7]) * 0.03125f;
    float A2 = (red[8]+red[9]+red[10]+red[11]) * 0.03125f;
    float dmx = A0;
    if (t > 1) dmx = fmaxf(dmx, A1);
    if (t > 2) dmx = fmaxf(dmx, A2);
    e0 = expf(A0 - dmx);
    e1 = (t > 1) ? expf(A1 - dmx) : 0.f;
    e2 = (t > 2) ? expf(A2 - dmx) : 0.f;
    float dinv = 1.f / (e0 + e1 + e2);
    e0 *= dinv; e1 *= dinv; e2 *= dinv;
  }
  size_t ar = (size_t)row * 3072;
  float ev[4];
  float part = 0.f;
#pragma unroll
  for (int j = 0; j < 4; j++){
    int d = tid + j * 256;
    size_t idx = (size_t)row * IN_D + d;
    float mv = 0.f;
#pragma unroll
    for (int m = 0; m < 24; m++) mv = fmaf(su[m], mvi[m * IN_D + d], mv);
    float dv = 0.f;
    if (t > 0){
      mv = fmaf(ss[0], t0[tb + 2048 + d], mv);
      dv = e0 * t0[tb + 1024 + d];
      if (t > 1){ mv = fmaf(ss[1], t1[tb + 2048 + d], mv); dv = fmaf(e1, t1[tb + 1024 + d], dv); }
      if (t > 2){ mv = fmaf(ss[2], t2[tb + 2048 + d], mv); dv = fmaf(e2, t2[tb + 1024 + d], dv); }
    }
    float sv = sbb[d];
#pragma unroll
    for (int o = 0; o < 40; o++) sv = fmaf(s40[o], sbw[d * 40 + o], sv);
    float v = cur[idx] + 0.34f * mv + 0.22f * dv + 0.18f * sv;
    uint16_t mh = f2bf(mv);
    Arh[ar + 1024 + d] = mh; Arl[ar + 1024 + d] = f2bf(mv - bf2f(mh));
    uint16_t dh = f2bf(dv);
    Arh[ar + 2048 + d] = dh; Arl[ar + 2048 + d] = f2bf(dv - bf2f(dh));
    ev[j] = v; part += v;
  }
  part = wred(part);
  if ((tid & 63) == 0) redm[tid >> 6] = part;
  __syncthreads();
  float mean = (redm[0] + redm[1] + redm[2] + redm[3]) * (1.f / 1024.f);
  float vp = 0.f;
#pragma unroll
  for (int j = 0; j < 4; j++){ float dd = ev[j] - mean; vp += dd * dd; }
  vp = wred(vp);
  if ((tid & 63) == 0) redm[4 + (tid >> 6)] = vp;
  __syncthreads();
  float var = (redm[4] + redm[5] + redm[6] + redm[7]) * (1.f / 1024.f);
  float rs = 1.f / sqrtf(var + 1e-5f);
#pragma unroll
  for (int j = 0; j < 4; j++){
    int d = tid + j * 256;
    size_t idx = (size_t)row * IN_D + d;
    enr[idx] = ev[j];
    float v = (ev[j] - mean) * rs * lng[t * IN_D + d] + lnbv[t * IN_D + d];
    uint16_t h = f2bf(v);
    lnh[idx] = h;
    lnl[idx] = f2bf(v - bf2f(h));
  }
}

// downfin core
__device__ __forceinline__
void down_core(int rowblk,
               const uint16_t* __restrict__ HH, const int* __restrict__ pos,
               const float* __restrict__ ED, const float* __restrict__ sg,
               const float* __restrict__ eng, const float* __restrict__ enb,
               const float* __restrict__ routeS, const float* __restrict__ haltb,
               float* __restrict__ total, float* __restrict__ cumh)
{
  int lane = threadIdx.x & 63;
  int row = rowblk * 4 + (threadIdx.x >> 6);
  float out[10] = {};
  for (int e = 0; e < NEXP; e++){
    float g = sg[row * 10 + e];
    if (g != 0.0f){
      int d = c_dims[e];
      int slot = pos[row * 10 + e];
      const uint16_t* hr = HH + (size_t)N_TOK * c_offs[e] + (size_t)slot * d;
      const float* wd = ED + (size_t)e * 10 * DMAX;
      float p[10] = {};
      for (int k = lane * 4; k < d; k += 256){
        uint2 hv = *(const uint2*)&hr[k];
        float h0 = bf2f((uint16_t)hv.x), h1 = bf2f((uint16_t)(hv.x >> 16));
        float h2 = bf2f((uint16_t)hv.y), h3 = bf2f((uint16_t)(hv.y >> 16));
#pragma unroll
        for (int o = 0; o < 10; o++){
          float4 w4 = *(const float4*)&wd[o * DMAX + k];
          p[o] = fmaf(h0, w4.x, fmaf(h1, w4.y, fmaf(h2, w4.z, fmaf(h3, w4.w, p[o]))));
        }
      }
#pragma unroll
      for (int o = 0; o < 10; o++) p[o] = wred(p[o]);
      float mean = 0.f;
#pragma unroll
      for (int o = 0; o < 10; o++) mean += p[o];
      mean *= 0.1f;
      float var = 0.f;
#pragma unroll
      for (int o = 0; o < 10; o++){ float dd = p[o] - mean; var += dd * dd; }
      var *= 0.1f;
      float rs = 1.f / sqrtf(var + 1e-5f);
#pragma unroll
      for (int o = 0; o < 10; o++)
        out[o] += g * ((p[o] - mean) * rs * eng[e * 10 + o] + enb[e * 10 + o]);
    }
  }
  if (lane == 0){
    const float* r = routeS + (size_t)row * 32;
    float rem = 1.f - cumh[row];
#pragma unroll
    for (int o = 0; o < 10; o++)
      total[row * 10 + o] += rem * (out[o] + 0.22f * r[o] + 0.14f * r[10 + o]);
    cumh[row] += rem * haltb[row];
  }
}

// ================= kernels =======================================================
template<int EPI>
__global__ __launch_bounds__(256)
void gemm_sp(const uint16_t* __restrict__ Ah, const uint16_t* __restrict__ Al, int lda,
             const uint16_t* __restrict__ Wh, const uint16_t* __restrict__ Wl,
             const uint16_t* __restrict__ W2h, const uint16_t* __restrict__ W2l,
             const float* __restrict__ bias, const float* __restrict__ addend,
             float* __restrict__ D0, float* __restrict__ D1, float* __restrict__ D2,
             float* __restrict__ D3, uint8_t* __restrict__ o8,
             uint16_t* __restrict__ oH, uint16_t* __restrict__ oL,
             int K, int D)
{
  __shared__ __align__(16) uint16_t sm[4][2][4096];
  gemm_core<EPI>(sm, blockIdx.x, blockIdx.y, Ah, Al, lda, Wh, Wl, W2h, W2l,
                 bias, addend, D0, D1, D2, D3, o8, oH, oL, K, D);
}

// fused: fc1(t) gemm (96 blocks) || downfin(t-1) (512 blocks)
__global__ __launch_bounds__(256)
void fused_fc1_down(const uint16_t* __restrict__ lnh, const uint16_t* __restrict__ lnl,
                    const uint16_t* __restrict__ fc1h, const uint16_t* __restrict__ fc1l,
                    const float* __restrict__ fc1b,
                    uint16_t* __restrict__ h7h, uint16_t* __restrict__ h7l,
                    const uint16_t* __restrict__ HH, const int* __restrict__ pos,
                    const float* __restrict__ ED, const float* __restrict__ sg,
                    const float* __restrict__ eng, const float* __restrict__ enb,
                    const float* __restrict__ routeS, const float* __restrict__ haltb,
                    float* __restrict__ total, float* __restrict__ cumh)
{
  __shared__ __align__(16) uint16_t sm[4][2][4096];
  int bid = blockIdx.x;
  if (bid < 96){
    gemm_core<EPI_GELU>(sm, bid % 6, bid / 6, lnh, lnl, 1024, fc1h, fc1l,
                        nullptr, nullptr, fc1b, nullptr,
                        nullptr, nullptr, nullptr, nullptr, nullptr,
                        h7h, h7l, IN_D, INNER);
  } else {
    down_core(bid - 96, HH, pos, ED, sg, eng, enb, routeS, haltb, total, cumh);
  }
}

// fused: expert_up(t) (752 blocks) || ctx_enr(t+1) (2048 blocks)
__global__ __launch_bounds__(256)
void fused_exp_ctx(const uint8_t* __restrict__ A8, const uint8_t* __restrict__ U8,
                   const int* __restrict__ cnt, const int* __restrict__ gidx,
                   uint16_t* __restrict__ HH,
                   const float* __restrict__ qaux, const float* __restrict__ dqbuf,
                   const float* __restrict__ Ac, const float* __restrict__ W0,
                   const float* __restrict__ W1, const float* __restrict__ W2,
                   const float* __restrict__ mvi,
                   const float* __restrict__ t0, const float* __restrict__ t1,
                   const float* __restrict__ t2, const float* __restrict__ cur,
                   const float* __restrict__ sab, const float* __restrict__ sbw,
                   const float* __restrict__ sbb, const float* __restrict__ lng,
                   const float* __restrict__ lnbv,
                   float* __restrict__ enr, uint16_t* __restrict__ lnh,
                   uint16_t* __restrict__ lnl, uint16_t* __restrict__ Arh,
                   uint16_t* __restrict__ Arl, int tn)
{
  __shared__ __align__(16) uint8_t smem[32768];
  int bid = blockIdx.x;
  if (bid < 752){
    expert_core(smem, bid & 3, bid >> 2, A8, U8, cnt, gidx, HH);
  } else {
    ctx_core(bid - 752, tn, qaux, dqbuf, Ac, W0, W1, W2, mvi, t0, t1, t2,
             cur, sab, sbw, sbb, lng, lnbv, enr, lnh, lnl, Arh, Arl);
  }
}

// standalone wrappers
__global__ __launch_bounds__(256)
void ctx_kernel(const float* __restrict__ qaux, const float* __restrict__ dqbuf,
                const float* __restrict__ Ac, const float* __restrict__ W0,
                const float* __restrict__ W1, const float* __restrict__ W2,
                const float* __restrict__ mvi,
                const float* __restrict__ t0, const float* __restrict__ t1,
                const float* __restrict__ t2, const float* __restrict__ cur,
                const float* __restrict__ sab, const float* __restrict__ sbw,
                const float* __restrict__ sbb, const float* __restrict__ lng,
                const float* __restrict__ lnbv,
                float* __restrict__ enr, uint16_t* __restrict__ lnh,
                uint16_t* __restrict__ lnl, uint16_t* __restrict__ Arh,
                uint16_t* __restrict__ Arl, int t)
{
  ctx_core(blockIdx.x, t, qaux, dqbuf, Ac, W0, W1, W2, mvi, t0, t1, t2,
           cur, sab, sbw, sbb, lng, lnbv, enr, lnh, lnl, Arh, Arl);
}
__global__ __launch_bounds__(256)
void down_kernel(const uint16_t* __restrict__ HH, const int* __restrict__ pos,
                 const float* __restrict__ ED, const float* __restrict__ sg,
                 const float* __restrict__ eng, const float* __restrict__ enb,
                 const float* __restrict__ routeS, const float* __restrict__ haltb,
                 float* __restrict__ total, float* __restrict__ cumh)
{
  down_core(blockIdx.x, HH, pos, ED, sg, eng, enb, routeS, haltb, total, cumh);
}

// ---------------- route_fin ------------------------------------------------------
__global__ __launch_bounds__(256)
void route_fin(const float* __restrict__ ROq, const float* __restrict__ mmb,
               const float* __restrict__ msb, const float* __restrict__ ebias,
               const float* __restrict__ bb, const float* __restrict__ wgb,
               const float* __restrict__ hb,
               float* __restrict__ sg, float* __restrict__ haltb,
               float* __restrict__ Ac, float* __restrict__ W0,
               float* __restrict__ W1, float* __restrict__ W2,
               int* __restrict__ cnt, int* __restrict__ gidx,
               int* __restrict__ pos, float* __restrict__ routeS, int t)
{
  int row = blockIdx.x * 256 + threadIdx.x;
  int lane = threadIdx.x & 63;
  const size_t P = (size_t)N_TOK * 128;
  const float* r0 = ROq + (size_t)row * 128;
  const float* r1 = r0 + P;
  const float* r2 = r0 + 2 * P;
  const float* r3 = r0 + 3 * P;
  auto R = [&](int j){ return r0[j] + r1[j] + r2[j] + r3[j]; };
  float pm[4];
#pragma unroll
  for (int o = 0; o < 4; o++) pm[o] = R(40 + o) + mmb[o];
  float mmx = fmaxf(fmaxf(pm[0], pm[1]), fmaxf(pm[2], pm[3]));
  float msum = 0.f;
#pragma unroll
  for (int o = 0; o < 4; o++){ pm[o] = expf(pm[o] - mmx); msum += pm[o]; }
  float minv = 1.f / msum;
  float gl[10];
#pragma unroll
  for (int e = 0; e < 10; e++){
    float g = ebias[e];
#pragma unroll
    for (int s2 = 0; s2 < 4; s2++)
      g = fmaf(pm[s2] * minv, R(s2 * 10 + e) + msb[s2 * 10 + e], g);
    gl[e] = g;
  }
  float gmx = gl[0];
#pragma unroll
  for (int e = 1; e < 10; e++) gmx = fmaxf(gmx, gl[e]);
  float gs = 0.f;
#pragma unroll
  for (int e = 0; e < 10; e++){ gl[e] = expf(gl[e] - gmx); gs += gl[e]; }
  float ginv = 1.f / gs;
#pragma unroll
  for (int e = 0; e < 10; e++) gl[e] *= ginv;
  float pb0 = R(44) + bb[0], pb1 = R(45) + bb[1], pb2 = R(46) + bb[2], pb3 = R(47) + bb[3];
  int bud = 1; float bbest = pb0;
  if (pb1 > bbest){ bbest = pb1; bud = 2; }
  if (pb2 > bbest){ bbest = pb2; bud = 3; }
  if (pb3 > bbest){ bbest = pb3; bud = 4; }
  float tv[4]; int ti[4]; unsigned used = 0;
#pragma unroll
  for (int j = 0; j < 4; j++){
    float best = -1e30f; int bi = 0;
#pragma unroll
    for (int e = 0; e < 10; e++){
      bool ok = (!((used >> e) & 1u)) && (gl[e] > best);
      if (ok){ best = gl[e]; bi = e; }
    }
    tv[j] = best; ti[j] = bi; used |= (1u << bi);
  }
  float ssum = tv[0];
  if (bud > 1) ssum += tv[1];
  if (bud > 2) ssum += tv[2];
  if (bud > 3) ssum += tv[3];
  float den = fmaxf(ssum, 1e-6f);
  float sup = 1.f - tv[0] / den;
  float sgv[10];
#pragma unroll
  for (int e = 0; e < 10; e++){
    float sv = 0.f;
#pragma unroll
    for (int j = 0; j < 4; j++) if (j < bud && ti[j] == e) sv = tv[j] / den;
    sgv[e] = sv;
    sg[row * 10 + e] = sv;
  }
  float pw[24];
#pragma unroll
  for (int m = 0; m < 24; m++) pw[m] = R(48 + m) + wgb[m];
  float wmx2 = pw[0];
#pragma unroll
  for (int m = 1; m < 24; m++) wmx2 = fmaxf(wmx2, pw[m]);
  float wsum = 0.f;
#pragma unroll
  for (int m = 0; m < 24; m++){ pw[m] = expf(pw[m] - wmx2); wsum += pw[m]; }
  float winv = 1.f / wsum;
#pragma unroll
  for (int m = 0; m < 24; m++){
    float c = sup * pw[m] * winv;
    float om = 1.f - c;
    Ac[row * 24 + m] *= om;
    if (t > 0) W0[row * 24 + m] *= om;
    if (t > 1) W1[row * 24 + m] *= om;
    if (t > 2) W2[row * 24 + m] *= om;
    if (t == 0)      W0[row * 24 + m] = c;
    else if (t == 1) W1[row * 24 + m] = c;
    else if (t == 2) W2[row * 24 + m] = c;
  }
  haltb[row] = 1.f / (1.f + expf(-(R(72) + hb[t])));
#pragma unroll
  for (int i = 0; i < 30; i++) routeS[row * 32 + i] = R(73 + i);
#pragma unroll
  for (int e = 0; e < 10; e++){
    bool act = sgv[e] != 0.f;
    unsigned long long mask = __ballot(act);
    int cw = __popcll(mask);
    int b0 = 0;
    if (lane == 0 && cw > 0) b0 = atomicAdd(&cnt[e], cw);
    b0 = __shfl(b0, 0, 64);
    if (act){
      int slot = b0 + __popcll(mask & ((1ull << lane) - 1ull));
      gidx[e * N_TOK + slot] = row;
      pos[row * 10 + e] = slot;
    }
  }
}

// ---------------- shared branch --------------------------------------------------
__global__ __launch_bounds__(256)
void shared_kernel(const float* __restrict__ shpre, const float* __restrict__ sdw,
                   const float* __restrict__ g, const float* __restrict__ b,
                   float* __restrict__ outp)
{
  int lane = threadIdx.x & 63;
  int row = blockIdx.x * 4 + (threadIdx.x >> 6);
  const float* xr = shpre + (size_t)row * SHD;
  float p[10];
#pragma unroll
  for (int o = 0; o < 10; o++) p[o] = 0.f;
  for (int k = lane; k < SHD; k += 64){
    float xv = xr[k];
#pragma unroll
    for (int o = 0; o < 10; o++) p[o] = fmaf(xv, sdw[o * SHD + k], p[o]);
  }
#pragma unroll
  for (int o = 0; o < 10; o++) p[o] = wred(p[o]);
  float mean = 0.f;
#pragma unroll
  for (int o = 0; o < 10; o++) mean += p[o];
  mean *= 0.1f;
  float var = 0.f;
#pragma unroll
  for (int o = 0; o < 10; o++){ float dd = p[o] - mean; var += dd * dd; }
  var *= 0.1f;
  float rs = 1.f / sqrtf(var + 1e-5f);
  if (lane == 0){
#pragma unroll
    for (int o = 0; o < 10; o++) outp[row * 10 + o] = (p[o] - mean) * rs * g[o] + b[o];
  }
}

// ---------------- final output (lite) --------------------------------------------
__global__ __launch_bounds__(256)
void final_lite(const float* __restrict__ qaux, const float* __restrict__ biasp,
                const float* __restrict__ sharedp, const float* __restrict__ total,
                const float* __restrict__ routeS, const float* __restrict__ sscale,
                const float* __restrict__ alphap, const float* __restrict__ betap,
                float* __restrict__ outp)
{
  int row = blockIdx.x * 256 + threadIdx.x;
  float ss = sscale[0], av = alphap[0] + 1e-4f, bv = betap[0];
#pragma unroll
  for (int o = 0; o < 10; o++)
    outp[row * 10 + o] = (qaux[(size_t)row * 128 + 64 + o] + biasp[o])
                       + ss * sharedp[row * 10 + o]
                       + av * (total[row * 10 + o] * 0.25f)
                       + bv * routeS[(size_t)row * 32 + 20 + o];
}

// ====================================================================================
extern "C" void kernel_launch(void* const* d_in, const int* in_sizes, int n_in,
                              void* d_out, int out_size, void* d_ws, size_t ws_size,
                              hipStream_t stream)
{
  const float* x     = (const float*)d_in[0];
  const float* wgt   = (const float*)d_in[1];
  const float* bias  = (const float*)d_in[2];
  const float* suw   = (const float*)d_in[3];
  const float* sdw   = (const float*)d_in[4];
  const float* sng   = (const float*)d_in[5];
  const float* snb   = (const float*)d_in[6];
  const float* sscale= (const float*)d_in[7];
  const float* keys  = (const float*)d_in[8];
  const float* mvi   = (const float*)d_in[9];
  const float* mqw   = (const float*)d_in[10];
  const float* mow   = (const float*)d_in[11];
  const float* wgw   = (const float*)d_in[12];
  const float* wgb   = (const float*)d_in[13];
  const float* wvw   = (const float*)d_in[14];
  const float* wvb   = (const float*)d_in[15];
  const float* dqw   = (const float*)d_in[16];
  const float* dkw   = (const float*)d_in[17];
  const float* dvw   = (const float*)d_in[18];
  const float* dow   = (const float*)d_in[19];
  const float* clng  = (const float*)d_in[20];
  const float* clnb  = (const float*)d_in[21];
  const float* fc1w  = (const float*)d_in[22];
  const float* fc1b  = (const float*)d_in[23];
  const float* fc2w  = (const float*)d_in[24];
  const float* fc2b  = (const float*)d_in[25];
  const float* saw   = (const float*)d_in[26];
  const float* sab   = (const float*)d_in[27];
  const float* sbw   = (const float*)d_in[28];
  const float* sbb   = (const float*)d_in[29];
  const float* msw   = (const float*)d_in[30];
  const float* msb   = (const float*)d_in[31];
  const float* mmw   = (const float*)d_in[32];
  const float* mmb   = (const float*)d_in[33];
  const float* ebias = (const float*)d_in[34];
  const float* bw    = (const float*)d_in[35];
  const float* bb    = (const float*)d_in[36];
  const float* eup   = (const float*)d_in[37];
  const float* edn   = (const float*)d_in[38];
  const float* eng   = (const float*)d_in[39];
  const float* enb   = (const float*)d_in[40];
  const float* hw    = (const float*)d_in[41];
  const float* hb    = (const float*)d_in[42];
  const float* alphap= (const float*)d_in[43];
  const float* betap = (const float*)d_in[44];
  float* outp = (float*)d_out;

  char* wsb = (char*)d_ws;
  size_t off = 0;
  auto AL = [&](size_t bytes) -> void* {
    void* p = wsb + off;
    off = (off + bytes + 255) & ~(size_t)255;
    return p;
  };
  const size_t NI = (size_t)N_TOK * IN_D;
  float* cur    = (float*)AL(NI * 4);
  float* enr    = (float*)AL(NI * 4);
  float* dqbuf  = (float*)AL(NI * 4);
  float* qaux   = (float*)AL((size_t)N_TOK * 128 * 4);
  float* routeQ = (float*)AL((size_t)4 * N_TOK * 128 * 4);
  float* routeS = (float*)AL((size_t)N_TOK * 32 * 4);
  float* trio0  = (float*)AL((size_t)N_TOK * 3072 * 4);
  float* trio1  = (float*)AL((size_t)N_TOK * 3072 * 4);
  float* trio2  = (float*)AL((size_t)N_TOK * 3072 * 4);
  float* Ac     = (float*)AL((size_t)N_TOK * 24 * 4);
  float* W0     = (float*)AL((size_t)N_TOK * 24 * 4);
  float* W1     = (float*)AL((size_t)N_TOK * 24 * 4);
  float* W2     = (float*)AL((size_t)N_TOK * 24 * 4);
  float* sg     = (float*)AL((size_t)N_TOK * 10 * 4);
  float* haltb  = (float*)AL((size_t)N_TOK * 4);
  char*  zblk   = (char*)AL((size_t)N_TOK * 10 * 4 + N_TOK * 4 + 4 * 16 * 4);
  float* total  = (float*)zblk;
  float* cumh   = (float*)(zblk + (size_t)N_TOK * 10 * 4);
  int*   cnt    = (int*)(zblk + (size_t)N_TOK * 10 * 4 + N_TOK * 4);
  int*   gidx   = (int*)AL((size_t)NEXP * N_TOK * 4);
  int*   pos    = (int*)AL((size_t)N_TOK * NEXP * 4);
  float* sharedp= (float*)AL((size_t)N_TOK * 10 * 4);
  float* cbias  = (float*)AL(3072 * 4);
  float* K2f    = (float*)AL((size_t)24 * 1024 * 4);
  uint16_t* lnh  = (uint16_t*)AL(NI * 2);
  uint16_t* lnl  = (uint16_t*)AL(NI * 2);
  uint16_t* h7h  = (uint16_t*)AL((size_t)N_TOK * INNER * 2);
  uint16_t* h7l  = (uint16_t*)AL((size_t)N_TOK * INNER * 2);
  uint16_t* Arh  = (uint16_t*)AL((size_t)N_TOK * 3072 * 2);
  uint16_t* Arl  = (uint16_t*)AL((size_t)N_TOK * 3072 * 2);
  const size_t W1M = (size_t)IN_D * IN_D;
  uint16_t* preWh  = (uint16_t*)AL((size_t)2176 * 1024 * 2);
  uint16_t* preWl  = (uint16_t*)AL((size_t)2176 * 1024 * 2);
  uint16_t* qtWh   = (uint16_t*)AL((size_t)4224 * 1024 * 2);
  uint16_t* qtWl   = (uint16_t*)AL((size_t)4224 * 1024 * 2);
  uint16_t* rtWh   = (uint16_t*)AL((size_t)4 * 128 * 3072 * 2);
  uint16_t* rtWl   = (uint16_t*)AL((size_t)4 * 128 * 3072 * 2);
  const size_t WFC = (size_t)NSTEP * INNER * IN_D;
  uint16_t* fc1wh = (uint16_t*)AL(WFC * 2); uint16_t* fc1wl = (uint16_t*)AL(WFC * 2);
  uint16_t* fc2wh = (uint16_t*)AL(WFC * 2); uint16_t* fc2wl = (uint16_t*)AL(WFC * 2);
  uint8_t* upbf8 = (uint8_t*)AL((size_t)NEXP * DMAX * IN_D);
  uint8_t* A8    = (uint8_t*)AL(NI);
  uint16_t* HHc  = (uint16_t*)AL((size_t)N_TOK * DSUM * 2);
  float* shpre  = (float*)HHc;   // alias: consumed before HHc is written

  // ---- init ----
  hipMemsetAsync(zblk, 0, (size_t)N_TOK * 10 * 4 + N_TOK * 4 + 4 * 16 * 4, stream);
  hipMemsetAsync(cbias, 0, 3072 * 4, stream);
  hipMemcpyAsync(cbias + 2048, wvb, 1024 * 4, hipMemcpyDeviceToDevice, stream);
  hipMemcpyAsync(cur, x, NI * 4, hipMemcpyDeviceToDevice, stream);
  fill1_kernel<<<(N_TOK * 24 + 255) / 256, 256, 0, stream>>>(Ac, N_TOK * 24);
  cvt_fp8_kernel<<<2048, 256, 0, stream>>>(eup, upbf8, (size_t)NEXP * DMAX * IN_D);

  split_strided<<<1024, 256, 0, stream>>>(x, Arh, Arl, N_TOK, 1024, 3072);
  split_kernel<<<1024, 256, 0, stream>>>(suw, preWh, preWl, (size_t)SHD * 1024);
  split_kernel<<<256, 256, 0, stream>>>(saw, preWh + (size_t)2072*1024, preWl + (size_t)2072*1024, (size_t)40 * 1024);
  split_kernel<<<256, 256, 0, stream>>>(wgt, preWh + (size_t)2112*1024, preWl + (size_t)2112*1024, (size_t)10 * 1024);
  hipMemsetAsync(preWh + (size_t)2122*1024, 0, (size_t)54 * 1024 * 2, stream);
  hipMemsetAsync(preWl + (size_t)2122*1024, 0, (size_t)54 * 1024 * 2, stream);
  split_kernel<<<1024, 256, 0, stream>>>(dqw, qtWh, qtWl, W1M);
  split_kernel<<<1024, 256, 0, stream>>>(dkw, qtWh + W1M, qtWl + W1M, W1M);
  split_kernel<<<1024, 256, 0, stream>>>(dvw, qtWh + 2*W1M, qtWl + 2*W1M, W1M);
  split_kernel<<<1024, 256, 0, stream>>>(wvw, qtWh + 3*W1M, qtWl + 3*W1M, W1M);
  split_kernel<<<256, 256, 0, stream>>>(saw, qtWh + (size_t)4120*1024, qtWl + (size_t)4120*1024, (size_t)40 * 1024);
  hipMemsetAsync(qtWh + (size_t)4160*1024, 0, (size_t)64 * 1024 * 2, stream);
  hipMemsetAsync(qtWl + (size_t)4160*1024, 0, (size_t)64 * 1024 * 2, stream);
  k2_kernel<<<dim3(24, 4), 256, 0, stream>>>(keys, mqw, K2f);
  split_kernel<<<256, 256, 0, stream>>>(K2f, preWh + (size_t)2048*1024, preWl + (size_t)2048*1024, (size_t)24 * 1024);
  split_kernel<<<256, 256, 0, stream>>>(K2f, qtWh + (size_t)4096*1024, qtWl + (size_t)4096*1024, (size_t)24 * 1024);
  build_routew<<<2048, 256, 0, stream>>>(msw, mmw, bw, wgw, hw, mow, dow, rtWh, rtWl);
  split_kernel<<<1024, 256, 0, stream>>>(fc1w, fc1wh, fc1wl, WFC);
  split_kernel<<<1024, 256, 0, stream>>>(fc2w, fc2wh, fc2wl, WFC);

  gemm_sp<EPI_PRE><<<dim3(17, 16), 256, 0, stream>>>(
      Arh, Arl, 3072, preWh, preWl, nullptr, nullptr, nullptr, nullptr,
      shpre, qaux, nullptr, nullptr, nullptr, nullptr, nullptr, IN_D, 2176);
  shared_kernel<<<512, 256, 0, stream>>>(shpre, sdw, sng, snb, sharedp);

  float* trioB[3] = {trio0, trio1, trio2};

  // step 0 context
  ctx_kernel<<<2048, 256, 0, stream>>>(qaux, dqbuf, Ac, W0, W1, W2, mvi,
                                       trio0, trio1, trio2, cur, sab, sbw, sbb,
                                       clng, clnb, enr, lnh, lnl, Arh, Arl, 0);

  for (int t = 0; t < NSTEP; t++){
    // fc1(t)  || downfin(t-1)
    fused_fc1_down<<<(t > 0 ? 608 : 96), 256, 0, stream>>>(
        lnh, lnl, fc1wh + (size_t)t * INNER * IN_D, fc1wl + (size_t)t * INNER * IN_D,
        fc1b + t * INNER, h7h, h7l,
        HHc, pos, edn, sg, eng, enb, routeS, haltb, total, cumh);
    gemm_sp<EPI_CUR><<<dim3(8, 16), 256, 0, stream>>>(
        h7h, h7l, 768, fc2wh + (size_t)t * IN_D * INNER, fc2wl + (size_t)t * IN_D * INNER,
        nullptr, nullptr, fc2b + t * IN_D, enr,
        cur, nullptr, nullptr, nullptr, A8, Arh, Arl, INNER, IN_D);
    gemm_sp<EPI_QROUTE><<<dim3(t < 3 ? 37 : 4, 16), 256, 0, stream>>>(
        Arh, Arl, 3072, qtWh, qtWl,
        rtWh + (size_t)t * 128 * 3072, rtWl + (size_t)t * 128 * 3072,
        cbias, nullptr, dqbuf, t < 3 ? trioB[t] : nullptr, qaux, routeQ,
        nullptr, nullptr, nullptr, IN_D, 4224);
    route_fin<<<8, 256, 0, stream>>>(routeQ, mmb, msb, ebias, bb, wgb, hb,
                                     sg, haltb, Ac, W0, W1, W2,
                                     cnt + t * 16, gidx, pos, routeS, t);
    // expert_up(t) || ctx_enr(t+1)
    fused_exp_ctx<<<(t < 3 ? 2800 : 752), 256, 0, stream>>>(
        A8, upbf8, cnt + t * 16, gidx, HHc,
        qaux, dqbuf, Ac, W0, W1, W2, mvi, trio0, trio1, trio2, cur,
        sab, sbw, sbb, clng, clnb, enr, lnh, lnl, Arh, Arl, t + 1);
  }
  down_kernel<<<512, 256, 0, stream>>>(HHc, pos, edn, sg, eng, enb,
                                       routeS, haltb, total, cumh);
  final_lite<<<8, 256, 0, stream>>>(qaux, bias, sharedp, total, routeS,
                                    sscale, alphap, betap, outp);
}

// Round 14
// 2162.928 us; speedup vs baseline: 1.0736x; 1.0736x over previous
//
#include <hip/hip_runtime.h>
#include <stdint.h>

#define N_TOK 2048
#define IN_D  1024
#define NEXP  10
#define NSTEP 4
#define INNER 768
#define SHD   2048
#define DMAX  3328
#define DSUM  24064

typedef __attribute__((ext_vector_type(4))) float f32x4;
typedef __attribute__((ext_vector_type(8))) short bf16x8;

__device__ const int c_dims[10] = {1536,2048,2560,3072,1792,2304,2816,2048,2560,3328};
__device__ const int c_offs[10] = {0,1536,3584,6144,9216,11008,13312,16128,18176,20736};
__device__ const int c_acts[10] = {0,1,2,3,4,5,6,7,0,1};
__device__ const int c_cum[11]  = {0,12,28,48,72,86,104,126,142,162,188};

__device__ __forceinline__ float wred(float v){
#pragma unroll
  for (int s = 32; s > 0; s >>= 1) v += __shfl_xor(v, s, 64);
  return v;
}
__device__ __forceinline__ float wmax(float v){
#pragma unroll
  for (int s = 32; s > 0; s >>= 1) v = fmaxf(v, __shfl_xor(v, s, 64));
  return v;
}
__device__ __forceinline__ float bf2f(uint16_t u){
  return __uint_as_float(((uint32_t)u) << 16);
}
__device__ __forceinline__ uint16_t f2bf(float f){
  uint32_t u = __float_as_uint(f);
  return (uint16_t)((u + 0x7FFFu + ((u >> 16) & 1u)) >> 16);
}
// float -> OCP e4m3 (RNE, saturate-finite)
__device__ __forceinline__ uint8_t f2fp8(float f){
  uint32_t u = __float_as_uint(f);
  uint8_t sign = (uint8_t)((u >> 24) & 0x80u);
  uint32_t absu = u & 0x7FFFFFFFu;
  if (absu >= 0x43E00000u) return sign | 0x7Eu;
  if (absu < 0x3C800000u){
    float af = __uint_as_float(absu);
    int q = (int)rintf(af * 512.0f);
    return sign | (uint8_t)q;
  }
  uint32_t mant = absu & 0x7FFFFFu;
  uint32_t exp = absu >> 23;
  uint32_t lsb = (mant >> 20) & 1u;
  uint32_t rounded = mant + 0x7FFFFu + lsb;
  if (rounded >= 0x800000u){ exp += 1; rounded = 0; }
  uint32_t e8 = exp - 120;
  uint32_t m8 = (rounded >> 20) & 7u;
  if (e8 > 15u || (e8 == 15u && m8 == 7u)) return sign | 0x7Eu;
  return sign | (uint8_t)((e8 << 3) | m8);
}
__device__ __forceinline__ void gload16(const uint16_t* g, uint16_t* l){
  __builtin_amdgcn_global_load_lds(
      (const __attribute__((address_space(1))) uint32_t*)(const void*)g,
      (__attribute__((address_space(3))) uint32_t*)(void*)l, 16, 0, 0);
}
__device__ __forceinline__ void gload16b(const void* g, void* l){
  __builtin_amdgcn_global_load_lds(
      (const __attribute__((address_space(1))) uint32_t*)g,
      (__attribute__((address_space(3))) uint32_t*)l, 16, 0, 0);
}

__device__ __forceinline__ float actf(int a, float x){
  switch(a){
    case 0: return x / (1.f + expf(-x));
    case 1: return 0.5f * x * (1.f + erff(x * 0.7071067811865475f));
    case 2: { float sp = fmaxf(x,0.f) + log1pf(expf(-fabsf(x)));
              return x * tanhf(sp); }
    case 3: return fmaxf(x, 0.f);
    case 4: return x > 0.f ? 1.0507009873554805f * x
                           : 1.7580993408473768f * expm1f(x);
    case 5: return tanhf(x);
    case 6: return fmaxf(x,0.f) + log1pf(expf(-fabsf(x)));
    default: return x > 0.f ? x : expm1f(x);
  }
}

// ---------------- f32 -> (hi, lo) bf16 split ------------------------------------
__global__ void split_kernel(const float* __restrict__ src, uint16_t* __restrict__ hi,
                             uint16_t* __restrict__ lo, size_t n){
  size_t i = ((size_t)blockIdx.x * blockDim.x + threadIdx.x) << 2;
  size_t stride = ((size_t)gridDim.x * blockDim.x) << 2;
  for (; i < n; i += stride){
    float4 v = *(const float4*)(src + i);
    ushort4 h, l;
    h.x = f2bf(v.x); l.x = f2bf(v.x - bf2f(h.x));
    h.y = f2bf(v.y); l.y = f2bf(v.y - bf2f(h.y));
    h.z = f2bf(v.z); l.z = f2bf(v.z - bf2f(h.z));
    h.w = f2bf(v.w); l.w = f2bf(v.w - bf2f(h.w));
    *(ushort4*)(hi + i) = h;
    *(ushort4*)(lo + i) = l;
  }
}
__global__ void split_strided(const float* __restrict__ src, uint16_t* __restrict__ hi,
                              uint16_t* __restrict__ lo, int rows, int cols, int ldd){
  int nq = rows * (cols >> 2);
  for (int i = blockIdx.x * blockDim.x + threadIdx.x; i < nq; i += gridDim.x * blockDim.x){
    int r = i / (cols >> 2), c4 = (i - r * (cols >> 2)) << 2;
    float4 v = *(const float4*)(src + (size_t)r * cols + c4);
    ushort4 h, l;
    h.x = f2bf(v.x); l.x = f2bf(v.x - bf2f(h.x));
    h.y = f2bf(v.y); l.y = f2bf(v.y - bf2f(h.y));
    h.z = f2bf(v.z); l.z = f2bf(v.z - bf2f(h.z));
    h.w = f2bf(v.w); l.w = f2bf(v.w - bf2f(h.w));
    size_t d = (size_t)r * ldd + c4;
    *(ushort4*)(hi + d) = h;
    *(ushort4*)(lo + d) = l;
  }
}
__global__ void cvt_fp8_kernel(const float* __restrict__ src, uint8_t* __restrict__ dst, size_t n){
  size_t i = ((size_t)blockIdx.x * blockDim.x + threadIdx.x) << 2;
  size_t stride = ((size_t)gridDim.x * blockDim.x) << 2;
  for (; i < n; i += stride){
    float4 v = *(const float4*)(src + i);
    uchar4 q;
    q.x = f2fp8(v.x); q.y = f2fp8(v.y); q.z = f2fp8(v.z); q.w = f2fp8(v.w);
    *(uchar4*)(dst + i) = q;
  }
}
__global__ void fill1_kernel(float* __restrict__ p, int n){
  int i = blockIdx.x * blockDim.x + threadIdx.x;
  if (i < n) p[i] = 1.f;
}

// ---------------- K2 = keys @ mqw  [24,1024] ------------------------------------
__global__ __launch_bounds__(256)
void k2_kernel(const float* __restrict__ keys, const float* __restrict__ mqw,
               float* __restrict__ K2){
  int m = blockIdx.x;
  int j = blockIdx.y * 256 + threadIdx.x;
  float acc = 0.f;
  for (int d = 0; d < 1024; d++)
    acc = fmaf(keys[m * 1024 + d], mqw[d * 1024 + j], acc);
  K2[m * 1024 + j] = acc;
}

// ---------------- route weight builder: 4 x [128 rows x 3072] -------------------
__global__ void build_routew(const float* __restrict__ msw, const float* __restrict__ mmw,
                             const float* __restrict__ bw, const float* __restrict__ wgw,
                             const float* __restrict__ hw, const float* __restrict__ mow,
                             const float* __restrict__ dow, uint16_t* __restrict__ Wh,
                             uint16_t* __restrict__ Wl){
  const int TOT = 4 * 128 * 3072;
  for (int i = blockIdx.x * 256 + threadIdx.x; i < TOT; i += gridDim.x * 256){
    int t = i / (128 * 3072);
    int rem = i - t * (128 * 3072);
    int row = rem / 3072, col = rem - row * 3072;
    float v = 0.f;
    if (row < 40){ if (col < 1024) v = msw[row * 1024 + col]; }
    else if (row < 44){ if (col < 1024) v = mmw[(row - 40) * 1024 + col]; }
    else if (row < 48){ if (col < 1024) v = bw[(row - 44) * 1024 + col]; }
    else if (row < 72){ if (col < 2048) v = wgw[(row - 48) * 2048 + col]; }
    else if (row == 72){
      if (col < 1024) v = hw[t * 1024 + col];
      else if (col < 2048) v = 0.2f * hw[t * 1024 + col - 1024];
      else v = 0.1f * hw[t * 1024 + col - 2048];
    }
    else if (row < 83){ if (col >= 1024 && col < 2048) v = mow[(row - 73) * 1024 + col - 1024]; }
    else if (row < 93){ if (col >= 2048) v = dow[(row - 83) * 1024 + col - 2048]; }
    else if (row < 103){ if (col < 1024) v = mow[(row - 93) * 1024 + col]; }
    uint16_t h = f2bf(v);
    Wh[i] = h; Wl[i] = f2bf(v - bf2f(h));
  }
}

// ---------------- split-bf16 MFMA GEMM, counted-vmcnt 2-deep pipeline -----------
enum { EPI_GELU=0, EPI_CUR=1, EPI_PRE=2, EPI_QROUTE=3 };

template<int EPI>
__global__ __launch_bounds__(256)
void gemm_sp(const uint16_t* __restrict__ Ah, const uint16_t* __restrict__ Al, int lda,
             const uint16_t* __restrict__ Wh, const uint16_t* __restrict__ Wl,
             const uint16_t* __restrict__ W2h, const uint16_t* __restrict__ W2l,
             const float* __restrict__ bias, const float* __restrict__ addend,
             float* __restrict__ D0, float* __restrict__ D1, float* __restrict__ D2,
             float* __restrict__ D3, uint8_t* __restrict__ o8,
             uint16_t* __restrict__ oH, uint16_t* __restrict__ oL,
             int K, int D)
{
  __shared__ __align__(16) uint16_t sm[4][2][4096];
  int tid = threadIdx.x, lane = tid & 63, wave = tid >> 6;
  int wr = wave >> 1, wc = wave & 1;
  int arow = lane & 15, agrp = lane >> 4;
  int rowBase = blockIdx.y * 128;
  bool isRoute = (EPI == EPI_QROUTE) && ((int)blockIdx.x < 4);
  const uint16_t* Wsh = isRoute ? W2h : Wh;
  const uint16_t* Wsl = isRoute ? W2l : Wl;
  int wst     = isRoute ? 3072 : K;
  int colBase = isRoute ? 0 : ((EPI == EPI_QROUTE ? (int)blockIdx.x - 4 : (int)blockIdx.x) * 128);
  int kBase   = isRoute ? (int)blockIdx.x * 768 : 0;
  int kLen    = isRoute ? 768 : K;
  f32x4 acc[4][4];
#pragma unroll
  for (int m = 0; m < 4; m++)
#pragma unroll
    for (int n = 0; n < 4; n++){ f32x4 z = {0.f,0.f,0.f,0.f}; acc[m][n] = z; }

#define STAGE_G(buf, k0) do { \
  _Pragma("unroll") \
  for (int s = 0; s < 2; s++){ \
    int u = tid + s * 256; \
    int rr = u >> 2; \
    int ch = (u & 3) ^ ((rr >> 1) & 3); \
    size_t ga = (size_t)(rowBase + rr) * lda + kBase + (k0) + ch * 8; \
    size_t gw = (size_t)(colBase + rr) * wst + kBase + (k0) + ch * 8; \
    gload16(&Ah[ga], &sm[0][buf][u << 3]); \
    gload16(&Al[ga], &sm[1][buf][u << 3]); \
    gload16(&Wsh[gw], &sm[2][buf][u << 3]); \
    gload16(&Wsl[gw], &sm[3][buf][u << 3]); \
  } } while(0)

  int nk = kLen >> 5;
  STAGE_G(0, 0);
  if (nk > 1) STAGE_G(1, 32);
  int perm = (arow >> 1) & 3;
#pragma unroll 1
  for (int ki = 0; ki < nk; ki++){
    int cb = ki & 1;
    if (ki + 1 < nk) asm volatile("s_waitcnt vmcnt(8)" ::: "memory");
    else             asm volatile("s_waitcnt vmcnt(0)" ::: "memory");
    __builtin_amdgcn_s_barrier();
    bf16x8 ah[4], al[4], bh[4], bl[4];
#pragma unroll
    for (int m = 0; m < 4; m++){
      int u = ((wr*64 + m*16 + arow) << 2) + (agrp ^ perm);
      ah[m] = *(const bf16x8*)&sm[0][cb][u << 3];
      al[m] = *(const bf16x8*)&sm[1][cb][u << 3];
    }
#pragma unroll
    for (int n = 0; n < 4; n++){
      int u = ((wc*64 + n*16 + arow) << 2) + (agrp ^ perm);
      bh[n] = *(const bf16x8*)&sm[2][cb][u << 3];
      bl[n] = *(const bf16x8*)&sm[3][cb][u << 3];
    }
#pragma unroll
    for (int m = 0; m < 4; m++)
#pragma unroll
      for (int n = 0; n < 4; n++){
        acc[m][n] = __builtin_amdgcn_mfma_f32_16x16x32_bf16(ah[m], bh[n], acc[m][n], 0, 0, 0);
        acc[m][n] = __builtin_amdgcn_mfma_f32_16x16x32_bf16(ah[m], bl[n], acc[m][n], 0, 0, 0);
        acc[m][n] = __builtin_amdgcn_mfma_f32_16x16x32_bf16(al[m], bh[n], acc[m][n], 0, 0, 0);
      }
    __builtin_amdgcn_s_barrier();
    asm volatile("" ::: "memory");
    if (ki + 2 < nk) STAGE_G(cb, (ki + 2) << 5);
  }
#undef STAGE_G
#pragma unroll
  for (int m = 0; m < 4; m++){
#pragma unroll
    for (int n = 0; n < 4; n++){
      int col = colBase + wc*64 + n*16 + arow;
#pragma unroll
      for (int r2 = 0; r2 < 4; r2++){
        int row = rowBase + wr*64 + m*16 + agrp*4 + r2;
        float v = acc[m][n][r2];
        if (EPI == EPI_GELU){
          v += bias[col];
          v = 0.5f * v * (1.f + erff(v * 0.7071067811865475f));
          size_t idx = (size_t)row * D + col;
          uint16_t h = f2bf(v); oH[idx] = h; oL[idx] = f2bf(v - bf2f(h));
        }
        if (EPI == EPI_CUR){
          v += bias[col] + addend[(size_t)row * 1024 + col];
          D0[(size_t)row * 1024 + col] = v;
          size_t idx = (size_t)row * 3072 + col;
          uint16_t h = f2bf(v); oH[idx] = h; oL[idx] = f2bf(v - bf2f(h));
          o8[(size_t)row * 1024 + col] = f2fp8(v);
        }
        if (EPI == EPI_PRE){
          if (col < 2048) D0[(size_t)row * 2048 + col] = v / (1.f + expf(-v));
          else D1[(size_t)row * 128 + col - 2048] = v;
        }
        if (EPI == EPI_QROUTE){
          if (isRoute){
            D3[((size_t)blockIdx.x * N_TOK + row) * 128 + col] = v;
          } else {
            if (col < 1024) D0[(size_t)row * 1024 + col] = v;
            else if (col < 4096) D1[(size_t)row * 3072 + col - 1024] = v + bias[col - 1024];
            else if (col < 4160) D2[(size_t)row * 128 + col - 4096] = v;
          }
        }
      }
    }
  }
}

// ---------------- sparse expert up: fp8, persistent, depth-3, swizzled LDS ------
__global__ __launch_bounds__(256)
void expert_up_mfma(const uint8_t* __restrict__ A8, const uint8_t* __restrict__ U8,
                    const int* __restrict__ cnt, const int* __restrict__ gidx,
                    uint16_t* __restrict__ HH)
{
  int y = blockIdx.y;
  int e = 0;
#pragma unroll
  for (int i = 1; i < 11; i++) if (y >= c_cum[i]) e = i;
  int ct = y - c_cum[e];
  int dcols = c_dims[e];
  int ne = cnt[e];
  const uint8_t* W = U8 + (size_t)e * DMAX * IN_D + (size_t)ct * 128 * IN_D;

  __shared__ __align__(16) uint8_t smem[32768];
  int tid = threadIdx.x, lane = tid & 63, wave = tid >> 6;
  int wr = wave >> 1, wc = wave & 1;
  int arow = lane & 15, agrp = lane >> 4;
  int actid = c_acts[e];
  size_t base_e = (size_t)N_TOK * c_offs[e];
  int rHalf = tid >> 1;
  // both-sides 16B swizzle: source half inverts the read swizzle
  int h16 = (((tid & 1) ^ ((tid >> 3) & 1)) << 4);
  // lane-constant read offset within the 32B row-pair (2-way banks = free)
  int off = ((((agrp >> 1) ^ ((arow >> 2) & 1)) << 4) | ((agrp & 1) << 3));

#define STAGE_E(b, k0) do { \
    gload16b(&A8[(size_t)tok * IN_D + (k0) + h16], &smem[(b)*8192 + tid*16]); \
    gload16b(&W[(size_t)rHalf * IN_D + (k0) + h16], &smem[(b)*8192 + 4096 + tid*16]); \
  } while(0)

#pragma unroll 1
  for (int rowBase = blockIdx.x * 128; rowBase < ne; rowBase += 4 * 128){
    int slot = rowBase + rHalf;
    int tok = (slot < ne) ? gidx[e * N_TOK + slot] : 0;

    f32x4 acc[4][4];
#pragma unroll
    for (int m = 0; m < 4; m++)
#pragma unroll
      for (int n = 0; n < 4; n++){ f32x4 z = {0.f,0.f,0.f,0.f}; acc[m][n] = z; }

    STAGE_E(0, 0);
    STAGE_E(1, 32);
    STAGE_E(2, 64);
    int cb = 0;
#pragma unroll 1
    for (int ki = 0; ki < 32; ki++){
      if (ki < 30)       asm volatile("s_waitcnt vmcnt(4)" ::: "memory");
      else if (ki == 30) asm volatile("s_waitcnt vmcnt(2)" ::: "memory");
      else               asm volatile("s_waitcnt vmcnt(0)" ::: "memory");
      __builtin_amdgcn_s_barrier();
      long a[4], b[4];
#pragma unroll
      for (int m = 0; m < 4; m++)
        a[m] = *(const long*)&smem[cb*8192 + (wr*64 + m*16 + arow)*32 + off];
#pragma unroll
      for (int n = 0; n < 4; n++)
        b[n] = *(const long*)&smem[cb*8192 + 4096 + (wc*64 + n*16 + arow)*32 + off];
#pragma unroll
      for (int m = 0; m < 4; m++)
#pragma unroll
        for (int n = 0; n < 4; n++)
          acc[m][n] = __builtin_amdgcn_mfma_f32_16x16x32_fp8_fp8(a[m], b[n], acc[m][n], 0, 0, 0);
      __builtin_amdgcn_s_barrier();
      asm volatile("" ::: "memory");
      if (ki + 3 < 32) STAGE_E(cb, (ki + 3) << 5);
      cb = (cb == 2) ? 0 : cb + 1;
    }
    uint16_t* Ht = (uint16_t*)smem;
#pragma unroll
    for (int m = 0; m < 4; m++){
      int rb0 = wr*64 + m*16 + agrp*4;
#pragma unroll
      for (int n = 0; n < 4; n++){
        int col = wc*64 + n*16 + arow;
#pragma unroll
        for (int r2 = 0; r2 < 4; r2++){
          int row = rb0 + r2;
          float v = actf(actid, acc[m][n][r2]);
          Ht[row * 128 + (col ^ ((row & 7) << 3))] = f2bf(v);
        }
      }
    }
    __syncthreads();
#pragma unroll
    for (int i = 0; i < 8; i++){
      int c = tid + i * 256;
      int row = c >> 4, chunk = c & 15;
      int schunk = (chunk & 8) | ((chunk ^ row) & 7);
      int4 val = *(const int4*)&Ht[row * 128 + schunk * 8];
      *(int4*)&HH[base_e + (size_t)(rowBase + row) * dcols
                  + (size_t)ct * 128 + chunk * 8] = val;
    }
    __syncthreads();
  }
#undef STAGE_E
}

// ---------------- ctx_enr: mem softmax, depth attn, mctx/dctx/enriched/LN ------
__global__ __launch_bounds__(256)
void ctx_enr_kernel(const float* __restrict__ qaux, const float* __restrict__ dqbuf,
                    const float* __restrict__ Ac, const float* __restrict__ W0,
                    const float* __restrict__ W1, const float* __restrict__ W2,
                    const float* __restrict__ mvi,
                    const float* __restrict__ t0, const float* __restrict__ t1,
                    const float* __restrict__ t2, const float* __restrict__ cur,
                    const float* __restrict__ sab, const float* __restrict__ sbw,
                    const float* __restrict__ sbb, const float* __restrict__ lng,
                    const float* __restrict__ lnbv,
                    float* __restrict__ enr, uint16_t* __restrict__ lnh,
                    uint16_t* __restrict__ lnl, uint16_t* __restrict__ Arh,
                    uint16_t* __restrict__ Arl, int t)
{
  int row = blockIdx.x, tid = threadIdx.x;
  __shared__ float su[24], ss[3], s40[40], red[12], redm[8];
  if (tid < 64){
    float pj = (tid < 24) ? qaux[(size_t)row * 128 + tid] * 0.03125f : -1e30f;
    float mx = wmax(pj);
    float ex = (tid < 24) ? expf(pj - mx) : 0.f;
    float sum = wred(ex);
    float attn = ex / sum;
    if (tid < 24) su[tid] = attn * Ac[row * 24 + tid];
    float w0v = (t > 0 && tid < 24) ? W0[row * 24 + tid] : 0.f;
    float s0 = wred(attn * w0v);
    float w1v = (t > 1 && tid < 24) ? W1[row * 24 + tid] : 0.f;
    float s1 = wred(attn * w1v);
    float w2v = (t > 2 && tid < 24) ? W2[row * 24 + tid] : 0.f;
    float s2 = wred(attn * w2v);
    if (tid == 0){ ss[0] = s0; ss[1] = s1; ss[2] = s2; }
    if (tid < 40) s40[tid] = tanhf(qaux[(size_t)row * 128 + 24 + tid] + sab[tid]);
  }
  size_t tb = (size_t)row * 3072;
  if (t > 0){
    float a0 = 0.f, a1 = 0.f, a2 = 0.f;
#pragma unroll
    for (int j = 0; j < 4; j++){
      int d = tid + j * 256;
      float dq = dqbuf[(size_t)row * 1024 + d];
      a0 = fmaf(dq, t0[tb + d], a0);
      if (t > 1) a1 = fmaf(dq, t1[tb + d], a1);
      if (t > 2) a2 = fmaf(dq, t2[tb + d], a2);
    }
    a0 = wred(a0); a1 = wred(a1); a2 = wred(a2);
    if ((tid & 63) == 0){ int w = tid >> 6; red[w] = a0; red[4+w] = a1; red[8+w] = a2; }
  }
  __syncthreads();
  float e0 = 0.f, e1 = 0.f, e2 = 0.f;
  if (t > 0){
    float A0 = (red[0]+red[1]+red[2]+red[3]) * 0.03125f;
    float A1 = (red[4]+red[5]+red[6]+red[7]) * 0.03125f;
    float A2 = (red[8]+red[9]+red[10]+red[11]) * 0.03125f;
    float dmx = A0;
    if (t > 1) dmx = fmaxf(dmx, A1);
    if (t > 2) dmx = fmaxf(dmx, A2);
    e0 = expf(A0 - dmx);
    e1 = (t > 1) ? expf(A1 - dmx) : 0.f;
    e2 = (t > 2) ? expf(A2 - dmx) : 0.f;
    float dinv = 1.f / (e0 + e1 + e2);
    e0 *= dinv; e1 *= dinv; e2 *= dinv;
  }
  size_t ar = (size_t)row * 3072;
  float ev[4];
  float part = 0.f;
#pragma unroll
  for (int j = 0; j < 4; j++){
    int d = tid + j * 256;
    size_t idx = (size_t)row * IN_D + d;
    float mv = 0.f;
#pragma unroll
    for (int m = 0; m < 24; m++) mv = fmaf(su[m], mvi[m * IN_D + d], mv);
    float dv = 0.f;
    if (t > 0){
      mv = fmaf(ss[0], t0[tb + 2048 + d], mv);
      dv = e0 * t0[tb + 1024 + d];
      if (t > 1){ mv = fmaf(ss[1], t1[tb + 2048 + d], mv); dv = fmaf(e1, t1[tb + 1024 + d], dv); }
      if (t > 2){ mv = fmaf(ss[2], t2[tb + 2048 + d], mv); dv = fmaf(e2, t2[tb + 1024 + d], dv); }
    }
    float sv = sbb[d];
#pragma unroll
    for (int o = 0; o < 40; o++) sv = fmaf(s40[o], sbw[d * 40 + o], sv);
    float v = cur[idx] + 0.34f * mv + 0.22f * dv + 0.18f * sv;
    uint16_t mh = f2bf(mv);
    Arh[ar + 1024 + d] = mh; Arl[ar + 1024 + d] = f2bf(mv - bf2f(mh));
    uint16_t dh = f2bf(dv);
    Arh[ar + 2048 + d] = dh; Arl[ar + 2048 + d] = f2bf(dv - bf2f(dh));
    ev[j] = v; part += v;
  }
  part = wred(part);
  if ((tid & 63) == 0) redm[tid >> 6] = part;
  __syncthreads();
  float mean = (redm[0] + redm[1] + redm[2] + redm[3]) * (1.f / 1024.f);
  float vp = 0.f;
#pragma unroll
  for (int j = 0; j < 4; j++){ float dd = ev[j] - mean; vp += dd * dd; }
  vp = wred(vp);
  if ((tid & 63) == 0) redm[4 + (tid >> 6)] = vp;
  __syncthreads();
  float var = (redm[4] + redm[5] + redm[6] + redm[7]) * (1.f / 1024.f);
  float rs = 1.f / sqrtf(var + 1e-5f);
#pragma unroll
  for (int j = 0; j < 4; j++){
    int d = tid + j * 256;
    size_t idx = (size_t)row * IN_D + d;
    enr[idx] = ev[j];
    float v = (ev[j] - mean) * rs * lng[t * IN_D + d] + lnbv[t * IN_D + d];
    uint16_t h = f2bf(v);
    lnh[idx] = h;
    lnl[idx] = f2bf(v - bf2f(h));
  }
}

// ---------------- route_fin: sums 4 K-split partials, softmaxes, top-k ----------
__global__ __launch_bounds__(256)
void route_fin(const float* __restrict__ ROq, const float* __restrict__ mmb,
               const float* __restrict__ msb, const float* __restrict__ ebias,
               const float* __restrict__ bb, const float* __restrict__ wgb,
               const float* __restrict__ hb,
               float* __restrict__ sg, float* __restrict__ haltb,
               float* __restrict__ Ac, float* __restrict__ W0,
               float* __restrict__ W1, float* __restrict__ W2,
               int* __restrict__ cnt, int* __restrict__ gidx,
               int* __restrict__ pos, float* __restrict__ routeS, int t)
{
  int row = blockIdx.x * 256 + threadIdx.x;
  int lane = threadIdx.x & 63;
  const size_t P = (size_t)N_TOK * 128;
  const float* r0 = ROq + (size_t)row * 128;
  const float* r1 = r0 + P;
  const float* r2 = r0 + 2 * P;
  const float* r3 = r0 + 3 * P;
  auto R = [&](int j){ return r0[j] + r1[j] + r2[j] + r3[j]; };
  float pm[4];
#pragma unroll
  for (int o = 0; o < 4; o++) pm[o] = R(40 + o) + mmb[o];
  float mmx = fmaxf(fmaxf(pm[0], pm[1]), fmaxf(pm[2], pm[3]));
  float msum = 0.f;
#pragma unroll
  for (int o = 0; o < 4; o++){ pm[o] = expf(pm[o] - mmx); msum += pm[o]; }
  float minv = 1.f / msum;
  float gl[10];
#pragma unroll
  for (int e = 0; e < 10; e++){
    float g = ebias[e];
#pragma unroll
    for (int s2 = 0; s2 < 4; s2++)
      g = fmaf(pm[s2] * minv, R(s2 * 10 + e) + msb[s2 * 10 + e], g);
    gl[e] = g;
  }
  float gmx = gl[0];
#pragma unroll
  for (int e = 1; e < 10; e++) gmx = fmaxf(gmx, gl[e]);
  float gs = 0.f;
#pragma unroll
  for (int e = 0; e < 10; e++){ gl[e] = expf(gl[e] - gmx); gs += gl[e]; }
  float ginv = 1.f / gs;
#pragma unroll
  for (int e = 0; e < 10; e++) gl[e] *= ginv;
  float pb0 = R(44) + bb[0], pb1 = R(45) + bb[1], pb2 = R(46) + bb[2], pb3 = R(47) + bb[3];
  int bud = 1; float bbest = pb0;
  if (pb1 > bbest){ bbest = pb1; bud = 2; }
  if (pb2 > bbest){ bbest = pb2; bud = 3; }
  if (pb3 > bbest){ bbest = pb3; bud = 4; }
  float tv[4]; int ti[4]; unsigned used = 0;
#pragma unroll
  for (int j = 0; j < 4; j++){
    float best = -1e30f; int bi = 0;
#pragma unroll
    for (int e = 0; e < 10; e++){
      bool ok = (!((used >> e) & 1u)) && (gl[e] > best);
      if (ok){ best = gl[e]; bi = e; }
    }
    tv[j] = best; ti[j] = bi; used |= (1u << bi);
  }
  float ssum = tv[0];
  if (bud > 1) ssum += tv[1];
  if (bud > 2) ssum += tv[2];
  if (bud > 3) ssum += tv[3];
  float den = fmaxf(ssum, 1e-6f);
  float sup = 1.f - tv[0] / den;
  float sgv[10];
#pragma unroll
  for (int e = 0; e < 10; e++){
    float sv = 0.f;
#pragma unroll
    for (int j = 0; j < 4; j++) if (j < bud && ti[j] == e) sv = tv[j] / den;
    sgv[e] = sv;
    sg[row * 10 + e] = sv;
  }
  float pw[24];
#pragma unroll
  for (int m = 0; m < 24; m++) pw[m] = R(48 + m) + wgb[m];
  float wmx2 = pw[0];
#pragma unroll
  for (int m = 1; m < 24; m++) wmx2 = fmaxf(wmx2, pw[m]);
  float wsum = 0.f;
#pragma unroll
  for (int m = 0; m < 24; m++){ pw[m] = expf(pw[m] - wmx2); wsum += pw[m]; }
  float winv = 1.f / wsum;
#pragma unroll
  for (int m = 0; m < 24; m++){
    float c = sup * pw[m] * winv;
    float om = 1.f - c;
    Ac[row * 24 + m] *= om;
    if (t > 0) W0[row * 24 + m] *= om;
    if (t > 1) W1[row * 24 + m] *= om;
    if (t > 2) W2[row * 24 + m] *= om;
    if (t == 0)      W0[row * 24 + m] = c;
    else if (t == 1) W1[row * 24 + m] = c;
    else if (t == 2) W2[row * 24 + m] = c;
  }
  haltb[row] = 1.f / (1.f + expf(-(R(72) + hb[t])));
#pragma unroll
  for (int i = 0; i < 30; i++) routeS[row * 32 + i] = R(73 + i);
#pragma unroll
  for (int e = 0; e < 10; e++){
    bool act = sgv[e] != 0.f;
    unsigned long long mask = __ballot(act);
    int cw = __popcll(mask);
    int b0 = 0;
    if (lane == 0 && cw > 0) b0 = atomicAdd(&cnt[e], cw);
    b0 = __shfl(b0, 0, 64);
    if (act){
      int slot = b0 + __popcll(mask & ((1ull << lane) - 1ull));
      gidx[e * N_TOK + slot] = row;
      pos[row * 10 + e] = slot;
    }
  }
}

// ---------------- downfin: expert down + LN + gated acc + step finalize --------
__global__ __launch_bounds__(256)
void downfin_kernel(const uint16_t* __restrict__ HH, const int* __restrict__ pos,
                    const float* __restrict__ ED, const float* __restrict__ sg,
                    const float* __restrict__ eng, const float* __restrict__ enb,
                    const float* __restrict__ routeS, const float* __restrict__ haltb,
                    float* __restrict__ total, float* __restrict__ cumh)
{
  int lane = threadIdx.x & 63;
  int row = blockIdx.x * 4 + (threadIdx.x >> 6);
  float out[10] = {};
  for (int e = 0; e < NEXP; e++){
    float g = sg[row * 10 + e];
    if (g != 0.0f){
      int d = c_dims[e];
      int slot = pos[row * 10 + e];
      const uint16_t* hr = HH + (size_t)N_TOK * c_offs[e] + (size_t)slot * d;
      const float* wd = ED + (size_t)e * 10 * DMAX;
      float p[10] = {};
      for (int k = lane * 4; k < d; k += 256){
        uint2 hv = *(const uint2*)&hr[k];
        float h0 = bf2f((uint16_t)hv.x), h1 = bf2f((uint16_t)(hv.x >> 16));
        float h2 = bf2f((uint16_t)hv.y), h3 = bf2f((uint16_t)(hv.y >> 16));
#pragma unroll
        for (int o = 0; o < 10; o++){
          float4 w4 = *(const float4*)&wd[o * DMAX + k];
          p[o] = fmaf(h0, w4.x, fmaf(h1, w4.y, fmaf(h2, w4.z, fmaf(h3, w4.w, p[o]))));
        }
      }
#pragma unroll
      for (int o = 0; o < 10; o++) p[o] = wred(p[o]);
      float mean = 0.f;
#pragma unroll
      for (int o = 0; o < 10; o++) mean += p[o];
      mean *= 0.1f;
      float var = 0.f;
#pragma unroll
      for (int o = 0; o < 10; o++){ float dd = p[o] - mean; var += dd * dd; }
      var *= 0.1f;
      float rs = 1.f / sqrtf(var + 1e-5f);
#pragma unroll
      for (int o = 0; o < 10; o++)
        out[o] += g * ((p[o] - mean) * rs * eng[e * 10 + o] + enb[e * 10 + o]);
    }
  }
  if (lane == 0){
    const float* r = routeS + (size_t)row * 32;
    float rem = 1.f - cumh[row];
#pragma unroll
    for (int o = 0; o < 10; o++)
      total[row * 10 + o] += rem * (out[o] + 0.22f * r[o] + 0.14f * r[10 + o]);
    cumh[row] += rem * haltb[row];
  }
}

// ---------------- shared branch --------------------------------------------------
__global__ __launch_bounds__(256)
void shared_kernel(const float* __restrict__ shpre, const float* __restrict__ sdw,
                   const float* __restrict__ g, const float* __restrict__ b,
                   float* __restrict__ outp)
{
  int lane = threadIdx.x & 63;
  int row = blockIdx.x * 4 + (threadIdx.x >> 6);
  const float* xr = shpre + (size_t)row * SHD;
  float p[10];
#pragma unroll
  for (int o = 0; o < 10; o++) p[o] = 0.f;
  for (int k = lane; k < SHD; k += 64){
    float xv = xr[k];
#pragma unroll
    for (int o = 0; o < 10; o++) p[o] = fmaf(xv, sdw[o * SHD + k], p[o]);
  }
#pragma unroll
  for (int o = 0; o < 10; o++) p[o] = wred(p[o]);
  float mean = 0.f;
#pragma unroll
  for (int o = 0; o < 10; o++) mean += p[o];
  mean *= 0.1f;
  float var = 0.f;
#pragma unroll
  for (int o = 0; o < 10; o++){ float dd = p[o] - mean; var += dd * dd; }
  var *= 0.1f;
  float rs = 1.f / sqrtf(var + 1e-5f);
  if (lane == 0){
#pragma unroll
    for (int o = 0; o < 10; o++) outp[row * 10 + o] = (p[o] - mean) * rs * g[o] + b[o];
  }
}

// ---------------- final output (lite) --------------------------------------------
__global__ __launch_bounds__(256)
void final_lite(const float* __restrict__ qaux, const float* __restrict__ biasp,
                const float* __restrict__ sharedp, const float* __restrict__ total,
                const float* __restrict__ routeS, const float* __restrict__ sscale,
                const float* __restrict__ alphap, const float* __restrict__ betap,
                float* __restrict__ outp)
{
  int row = blockIdx.x * 256 + threadIdx.x;
  float ss = sscale[0], av = alphap[0] + 1e-4f, bv = betap[0];
#pragma unroll
  for (int o = 0; o < 10; o++)
    outp[row * 10 + o] = (qaux[(size_t)row * 128 + 64 + o] + biasp[o])
                       + ss * sharedp[row * 10 + o]
                       + av * (total[row * 10 + o] * 0.25f)
                       + bv * routeS[(size_t)row * 32 + 20 + o];
}

// ====================================================================================
extern "C" void kernel_launch(void* const* d_in, const int* in_sizes, int n_in,
                              void* d_out, int out_size, void* d_ws, size_t ws_size,
                              hipStream_t stream)
{
  const float* x     = (const float*)d_in[0];
  const float* wgt   = (const float*)d_in[1];
  const float* bias  = (const float*)d_in[2];
  const float* suw   = (const float*)d_in[3];
  const float* sdw   = (const float*)d_in[4];
  const float* sng   = (const float*)d_in[5];
  const float* snb   = (const float*)d_in[6];
  const float* sscale= (const float*)d_in[7];
  const float* keys  = (const float*)d_in[8];
  const float* mvi   = (const float*)d_in[9];
  const float* mqw   = (const float*)d_in[10];
  const float* mow   = (const float*)d_in[11];
  const float* wgw   = (const float*)d_in[12];
  const float* wgb   = (const float*)d_in[13];
  const float* wvw   = (const float*)d_in[14];
  const float* wvb   = (const float*)d_in[15];
  const float* dqw   = (const float*)d_in[16];
  const float* dkw   = (const float*)d_in[17];
  const float* dvw   = (const float*)d_in[18];
  const float* dow   = (const float*)d_in[19];
  const float* clng  = (const float*)d_in[20];
  const float* clnb  = (const float*)d_in[21];
  const float* fc1w  = (const float*)d_in[22];
  const float* fc1b  = (const float*)d_in[23];
  const float* fc2w  = (const float*)d_in[24];
  const float* fc2b  = (const float*)d_in[25];
  const float* saw   = (const float*)d_in[26];
  const float* sab   = (const float*)d_in[27];
  const float* sbw   = (const float*)d_in[28];
  const float* sbb   = (const float*)d_in[29];
  const float* msw   = (const float*)d_in[30];
  const float* msb   = (const float*)d_in[31];
  const float* mmw   = (const float*)d_in[32];
  const float* mmb   = (const float*)d_in[33];
  const float* ebias = (const float*)d_in[34];
  const float* bw    = (const float*)d_in[35];
  const float* bb    = (const float*)d_in[36];
  const float* eup   = (const float*)d_in[37];
  const float* edn   = (const float*)d_in[38];
  const float* eng   = (const float*)d_in[39];
  const float* enb   = (const float*)d_in[40];
  const float* hw    = (const float*)d_in[41];
  const float* hb    = (const float*)d_in[42];
  const float* alphap= (const float*)d_in[43];
  const float* betap = (const float*)d_in[44];
  float* outp = (float*)d_out;

  char* wsb = (char*)d_ws;
  size_t off = 0;
  auto AL = [&](size_t bytes) -> void* {
    void* p = wsb + off;
    off = (off + bytes + 255) & ~(size_t)255;
    return p;
  };
  const size_t NI = (size_t)N_TOK * IN_D;
  float* cur    = (float*)AL(NI * 4);
  float* enr    = (float*)AL(NI * 4);
  float* dqbuf  = (float*)AL(NI * 4);
  float* qaux   = (float*)AL((size_t)N_TOK * 128 * 4);
  float* routeQ = (float*)AL((size_t)4 * N_TOK * 128 * 4);
  float* routeS = (float*)AL((size_t)N_TOK * 32 * 4);
  float* trio0  = (float*)AL((size_t)N_TOK * 3072 * 4);
  float* trio1  = (float*)AL((size_t)N_TOK * 3072 * 4);
  float* trio2  = (float*)AL((size_t)N_TOK * 3072 * 4);
  float* Ac     = (float*)AL((size_t)N_TOK * 24 * 4);
  float* W0     = (float*)AL((size_t)N_TOK * 24 * 4);
  float* W1     = (float*)AL((size_t)N_TOK * 24 * 4);
  float* W2     = (float*)AL((size_t)N_TOK * 24 * 4);
  float* sg     = (float*)AL((size_t)N_TOK * 10 * 4);
  float* haltb  = (float*)AL((size_t)N_TOK * 4);
  char*  zblk   = (char*)AL((size_t)N_TOK * 10 * 4 + N_TOK * 4 + 4 * 16 * 4);
  float* total  = (float*)zblk;
  float* cumh   = (float*)(zblk + (size_t)N_TOK * 10 * 4);
  int*   cnt    = (int*)(zblk + (size_t)N_TOK * 10 * 4 + N_TOK * 4);
  int*   gidx   = (int*)AL((size_t)NEXP * N_TOK * 4);
  int*   pos    = (int*)AL((size_t)N_TOK * NEXP * 4);
  float* sharedp= (float*)AL((size_t)N_TOK * 10 * 4);
  float* cbias  = (float*)AL(3072 * 4);
  float* K2f    = (float*)AL((size_t)24 * 1024 * 4);
  uint16_t* lnh  = (uint16_t*)AL(NI * 2);
  uint16_t* lnl  = (uint16_t*)AL(NI * 2);
  uint16_t* h7h  = (uint16_t*)AL((size_t)N_TOK * INNER * 2);
  uint16_t* h7l  = (uint16_t*)AL((size_t)N_TOK * INNER * 2);
  uint16_t* Arh  = (uint16_t*)AL((size_t)N_TOK * 3072 * 2);
  uint16_t* Arl  = (uint16_t*)AL((size_t)N_TOK * 3072 * 2);
  const size_t W1M = (size_t)IN_D * IN_D;
  uint16_t* preWh  = (uint16_t*)AL((size_t)2176 * 1024 * 2);
  uint16_t* preWl  = (uint16_t*)AL((size_t)2176 * 1024 * 2);
  uint16_t* qtWh   = (uint16_t*)AL((size_t)4224 * 1024 * 2);
  uint16_t* qtWl   = (uint16_t*)AL((size_t)4224 * 1024 * 2);
  uint16_t* rtWh   = (uint16_t*)AL((size_t)4 * 128 * 3072 * 2);
  uint16_t* rtWl   = (uint16_t*)AL((size_t)4 * 128 * 3072 * 2);
  const size_t WFC = (size_t)NSTEP * INNER * IN_D;
  uint16_t* fc1wh = (uint16_t*)AL(WFC * 2); uint16_t* fc1wl = (uint16_t*)AL(WFC * 2);
  uint16_t* fc2wh = (uint16_t*)AL(WFC * 2); uint16_t* fc2wl = (uint16_t*)AL(WFC * 2);
  uint8_t* upbf8 = (uint8_t*)AL((size_t)NEXP * DMAX * IN_D);
  uint8_t* A8    = (uint8_t*)AL(NI);
  uint16_t* HHc  = (uint16_t*)AL((size_t)N_TOK * DSUM * 2);
  float* shpre  = (float*)HHc;   // alias: consumed before HHc is written

  // ---- init ----
  hipMemsetAsync(zblk, 0, (size_t)N_TOK * 10 * 4 + N_TOK * 4 + 4 * 16 * 4, stream);
  hipMemsetAsync(cbias, 0, 3072 * 4, stream);
  hipMemcpyAsync(cbias + 2048, wvb, 1024 * 4, hipMemcpyDeviceToDevice, stream);
  hipMemcpyAsync(cur, x, NI * 4, hipMemcpyDeviceToDevice, stream);
  fill1_kernel<<<(N_TOK * 24 + 255) / 256, 256, 0, stream>>>(Ac, N_TOK * 24);
  cvt_fp8_kernel<<<2048, 256, 0, stream>>>(eup, upbf8, (size_t)NEXP * DMAX * IN_D);

  split_strided<<<1024, 256, 0, stream>>>(x, Arh, Arl, N_TOK, 1024, 3072);
  split_kernel<<<1024, 256, 0, stream>>>(suw, preWh, preWl, (size_t)SHD * 1024);
  split_kernel<<<256, 256, 0, stream>>>(saw, preWh + (size_t)2072*1024, preWl + (size_t)2072*1024, (size_t)40 * 1024);
  split_kernel<<<256, 256, 0, stream>>>(wgt, preWh + (size_t)2112*1024, preWl + (size_t)2112*1024, (size_t)10 * 1024);
  hipMemsetAsync(preWh + (size_t)2122*1024, 0, (size_t)54 * 1024 * 2, stream);
  hipMemsetAsync(preWl + (size_t)2122*1024, 0, (size_t)54 * 1024 * 2, stream);
  split_kernel<<<1024, 256, 0, stream>>>(dqw, qtWh, qtWl, W1M);
  split_kernel<<<1024, 256, 0, stream>>>(dkw, qtWh + W1M, qtWl + W1M, W1M);
  split_kernel<<<1024, 256, 0, stream>>>(dvw, qtWh + 2*W1M, qtWl + 2*W1M, W1M);
  split_kernel<<<1024, 256, 0, stream>>>(wvw, qtWh + 3*W1M, qtWl + 3*W1M, W1M);
  split_kernel<<<256, 256, 0, stream>>>(saw, qtWh + (size_t)4120*1024, qtWl + (size_t)4120*1024, (size_t)40 * 1024);
  hipMemsetAsync(qtWh + (size_t)4160*1024, 0, (size_t)64 * 1024 * 2, stream);
  hipMemsetAsync(qtWl + (size_t)4160*1024, 0, (size_t)64 * 1024 * 2, stream);
  k2_kernel<<<dim3(24, 4), 256, 0, stream>>>(keys, mqw, K2f);
  split_kernel<<<256, 256, 0, stream>>>(K2f, preWh + (size_t)2048*1024, preWl + (size_t)2048*1024, (size_t)24 * 1024);
  split_kernel<<<256, 256, 0, stream>>>(K2f, qtWh + (size_t)4096*1024, qtWl + (size_t)4096*1024, (size_t)24 * 1024);
  build_routew<<<2048, 256, 0, stream>>>(msw, mmw, bw, wgw, hw, mow, dow, rtWh, rtWl);
  split_kernel<<<1024, 256, 0, stream>>>(fc1w, fc1wh, fc1wl, WFC);
  split_kernel<<<1024, 256, 0, stream>>>(fc2w, fc2wh, fc2wl, WFC);

  gemm_sp<EPI_PRE><<<dim3(17, 16), 256, 0, stream>>>(
      Arh, Arl, 3072, preWh, preWl, nullptr, nullptr, nullptr, nullptr,
      shpre, qaux, nullptr, nullptr, nullptr, nullptr, nullptr, IN_D, 2176);
  shared_kernel<<<512, 256, 0, stream>>>(shpre, sdw, sng, snb, sharedp);

  float* trioB[3] = {trio0, trio1, trio2};

  for (int t = 0; t < NSTEP; t++){
    ctx_enr_kernel<<<2048, 256, 0, stream>>>(qaux, dqbuf, Ac, W0, W1, W2, mvi,
                                             trio0, trio1, trio2, cur, sab, sbw, sbb,
                                             clng, clnb, enr, lnh, lnl, Arh, Arl, t);
    gemm_sp<EPI_GELU><<<dim3(INNER/128, 16), 256, 0, stream>>>(
        lnh, lnl, 1024, fc1wh + (size_t)t * INNER * IN_D, fc1wl + (size_t)t * INNER * IN_D,
        nullptr, nullptr, fc1b + t * INNER, nullptr,
        nullptr, nullptr, nullptr, nullptr, nullptr, h7h, h7l, IN_D, INNER);
    gemm_sp<EPI_CUR><<<dim3(8, 16), 256, 0, stream>>>(
        h7h, h7l, 768, fc2wh + (size_t)t * IN_D * INNER, fc2wl + (size_t)t * IN_D * INNER,
        nullptr, nullptr, fc2b + t * IN_D, enr,
        cur, nullptr, nullptr, nullptr, A8, Arh, Arl, INNER, IN_D);
    gemm_sp<EPI_QROUTE><<<dim3(t < 3 ? 37 : 4, 16), 256, 0, stream>>>(
        Arh, Arl, 3072, qtWh, qtWl,
        rtWh + (size_t)t * 128 * 3072, rtWl + (size_t)t * 128 * 3072,
        cbias, nullptr, dqbuf, t < 3 ? trioB[t] : nullptr, qaux, routeQ,
        nullptr, nullptr, nullptr, IN_D, 4224);
    route_fin<<<8, 256, 0, stream>>>(routeQ, mmb, msb, ebias, bb, wgb, hb,
                                     sg, haltb, Ac, W0, W1, W2,
                                     cnt + t * 16, gidx, pos, routeS, t);
    expert_up_mfma<<<dim3(4, 188), 256, 0, stream>>>(A8, upbf8, cnt + t * 16, gidx, HHc);
    downfin_kernel<<<512, 256, 0, stream>>>(HHc, pos, edn, sg, eng, enb,
                                            routeS, haltb, total, cumh);
  }
  final_lite<<<8, 256, 0, stream>>>(qaux, bias, sharedp, total, routeS,
                                    sscale, alphap, betap, outp);
}

// Round 15
// 2089.233 us; speedup vs baseline: 1.1115x; 1.0353x over previous
//
#include <hip/hip_runtime.h>
#include <stdint.h>

#define N_TOK 2048
#define IN_D  1024
#define NEXP  10
#define NSTEP 4
#define INNER 768
#define SHD   2048
#define DMAX  3328
#define DSUM  24064

typedef __attribute__((ext_vector_type(4))) float f32x4;
typedef __attribute__((ext_vector_type(8))) short bf16x8;

__device__ const int c_dims[10] = {1536,2048,2560,3072,1792,2304,2816,2048,2560,3328};
__device__ const int c_offs[10] = {0,1536,3584,6144,9216,11008,13312,16128,18176,20736};
__device__ const int c_acts[10] = {0,1,2,3,4,5,6,7,0,1};
__device__ const int c_cum[11]  = {0,12,28,48,72,86,104,126,142,162,188};

__device__ __forceinline__ float wred(float v){
#pragma unroll
  for (int s = 32; s > 0; s >>= 1) v += __shfl_xor(v, s, 64);
  return v;
}
__device__ __forceinline__ float wmax(float v){
#pragma unroll
  for (int s = 32; s > 0; s >>= 1) v = fmaxf(v, __shfl_xor(v, s, 64));
  return v;
}
__device__ __forceinline__ float bf2f(uint16_t u){
  return __uint_as_float(((uint32_t)u) << 16);
}
__device__ __forceinline__ uint16_t f2bf(float f){
  uint32_t u = __float_as_uint(f);
  return (uint16_t)((u + 0x7FFFu + ((u >> 16) & 1u)) >> 16);
}
// float -> OCP e4m3 (RNE, saturate-finite)
__device__ __forceinline__ uint8_t f2fp8(float f){
  uint32_t u = __float_as_uint(f);
  uint8_t sign = (uint8_t)((u >> 24) & 0x80u);
  uint32_t absu = u & 0x7FFFFFFFu;
  if (absu >= 0x43E00000u) return sign | 0x7Eu;
  if (absu < 0x3C800000u){
    float af = __uint_as_float(absu);
    int q = (int)rintf(af * 512.0f);
    return sign | (uint8_t)q;
  }
  uint32_t mant = absu & 0x7FFFFFu;
  uint32_t exp = absu >> 23;
  uint32_t lsb = (mant >> 20) & 1u;
  uint32_t rounded = mant + 0x7FFFFu + lsb;
  if (rounded >= 0x800000u){ exp += 1; rounded = 0; }
  uint32_t e8 = exp - 120;
  uint32_t m8 = (rounded >> 20) & 7u;
  if (e8 > 15u || (e8 == 15u && m8 == 7u)) return sign | 0x7Eu;
  return sign | (uint8_t)((e8 << 3) | m8);
}
__device__ __forceinline__ void gload16(const uint16_t* g, uint16_t* l){
  __builtin_amdgcn_global_load_lds(
      (const __attribute__((address_space(1))) uint32_t*)(const void*)g,
      (__attribute__((address_space(3))) uint32_t*)(void*)l, 16, 0, 0);
}
__device__ __forceinline__ void gload16b(const void* g, void* l){
  __builtin_amdgcn_global_load_lds(
      (const __attribute__((address_space(1))) uint32_t*)g,
      (__attribute__((address_space(3))) uint32_t*)l, 16, 0, 0);
}

__device__ __forceinline__ float actf(int a, float x){
  switch(a){
    case 0: return x / (1.f + expf(-x));
    case 1: return 0.5f * x * (1.f + erff(x * 0.7071067811865475f));
    case 2: { float sp = fmaxf(x,0.f) + log1pf(expf(-fabsf(x)));
              return x * tanhf(sp); }
    case 3: return fmaxf(x, 0.f);
    case 4: return x > 0.f ? 1.0507009873554805f * x
                           : 1.7580993408473768f * expm1f(x);
    case 5: return tanhf(x);
    case 6: return fmaxf(x,0.f) + log1pf(expf(-fabsf(x)));
    default: return x > 0.f ? x : expm1f(x);
  }
}

// ---------------- f32 -> (hi, lo) bf16 split ------------------------------------
__global__ void split_kernel(const float* __restrict__ src, uint16_t* __restrict__ hi,
                             uint16_t* __restrict__ lo, size_t n){
  size_t i = ((size_t)blockIdx.x * blockDim.x + threadIdx.x) << 2;
  size_t stride = ((size_t)gridDim.x * blockDim.x) << 2;
  for (; i < n; i += stride){
    float4 v = *(const float4*)(src + i);
    ushort4 h, l;
    h.x = f2bf(v.x); l.x = f2bf(v.x - bf2f(h.x));
    h.y = f2bf(v.y); l.y = f2bf(v.y - bf2f(h.y));
    h.z = f2bf(v.z); l.z = f2bf(v.z - bf2f(h.z));
    h.w = f2bf(v.w); l.w = f2bf(v.w - bf2f(h.w));
    *(ushort4*)(hi + i) = h;
    *(ushort4*)(lo + i) = l;
  }
}
__global__ void split_strided(const float* __restrict__ src, uint16_t* __restrict__ hi,
                              uint16_t* __restrict__ lo, int rows, int cols, int ldd){
  int nq = rows * (cols >> 2);
  for (int i = blockIdx.x * blockDim.x + threadIdx.x; i < nq; i += gridDim.x * blockDim.x){
    int r = i / (cols >> 2), c4 = (i - r * (cols >> 2)) << 2;
    float4 v = *(const float4*)(src + (size_t)r * cols + c4);
    ushort4 h, l;
    h.x = f2bf(v.x); l.x = f2bf(v.x - bf2f(h.x));
    h.y = f2bf(v.y); l.y = f2bf(v.y - bf2f(h.y));
    h.z = f2bf(v.z); l.z = f2bf(v.z - bf2f(h.z));
    h.w = f2bf(v.w); l.w = f2bf(v.w - bf2f(h.w));
    size_t d = (size_t)r * ldd + c4;
    *(ushort4*)(hi + d) = h;
    *(ushort4*)(lo + d) = l;
  }
}
__global__ void cvt_fp8_kernel(const float* __restrict__ src, uint8_t* __restrict__ dst, size_t n){
  size_t i = ((size_t)blockIdx.x * blockDim.x + threadIdx.x) << 2;
  size_t stride = ((size_t)gridDim.x * blockDim.x) << 2;
  for (; i < n; i += stride){
    float4 v = *(const float4*)(src + i);
    uchar4 q;
    q.x = f2fp8(v.x); q.y = f2fp8(v.y); q.z = f2fp8(v.z); q.w = f2fp8(v.w);
    *(uchar4*)(dst + i) = q;
  }
}
__global__ void fill1_kernel(float* __restrict__ p, int n){
  int i = blockIdx.x * blockDim.x + threadIdx.x;
  if (i < n) p[i] = 1.f;
}

// ---------------- K2 = keys @ mqw  [24,1024] ------------------------------------
__global__ __launch_bounds__(256)
void k2_kernel(const float* __restrict__ keys, const float* __restrict__ mqw,
               float* __restrict__ K2){
  int m = blockIdx.x;
  int j = blockIdx.y * 256 + threadIdx.x;
  float acc = 0.f;
  for (int d = 0; d < 1024; d++)
    acc = fmaf(keys[m * 1024 + d], mqw[d * 1024 + j], acc);
  K2[m * 1024 + j] = acc;
}

// ---------------- route weight builder: 4 x [128 rows x 3072] -------------------
__global__ void build_routew(const float* __restrict__ msw, const float* __restrict__ mmw,
                             const float* __restrict__ bw, const float* __restrict__ wgw,
                             const float* __restrict__ hw, const float* __restrict__ mow,
                             const float* __restrict__ dow, uint16_t* __restrict__ Wh,
                             uint16_t* __restrict__ Wl){
  const int TOT = 4 * 128 * 3072;
  for (int i = blockIdx.x * 256 + threadIdx.x; i < TOT; i += gridDim.x * 256){
    int t = i / (128 * 3072);
    int rem = i - t * (128 * 3072);
    int row = rem / 3072, col = rem - row * 3072;
    float v = 0.f;
    if (row < 40){ if (col < 1024) v = msw[row * 1024 + col]; }
    else if (row < 44){ if (col < 1024) v = mmw[(row - 40) * 1024 + col]; }
    else if (row < 48){ if (col < 1024) v = bw[(row - 44) * 1024 + col]; }
    else if (row < 72){ if (col < 2048) v = wgw[(row - 48) * 2048 + col]; }
    else if (row == 72){
      if (col < 1024) v = hw[t * 1024 + col];
      else if (col < 2048) v = 0.2f * hw[t * 1024 + col - 1024];
      else v = 0.1f * hw[t * 1024 + col - 2048];
    }
    else if (row < 83){ if (col >= 1024 && col < 2048) v = mow[(row - 73) * 1024 + col - 1024]; }
    else if (row < 93){ if (col >= 2048) v = dow[(row - 83) * 1024 + col - 2048]; }
    else if (row < 103){ if (col < 1024) v = mow[(row - 93) * 1024 + col]; }
    uint16_t h = f2bf(v);
    Wh[i] = h; Wl[i] = f2bf(v - bf2f(h));
  }
}

// ---------------- split-bf16 MFMA GEMM, counted-vmcnt 2-deep pipeline -----------
enum { EPI_GELU=0, EPI_CUR=1, EPI_PRE=2, EPI_QROUTE=3 };

template<int EPI>
__global__ __launch_bounds__(256)
void gemm_sp(const uint16_t* __restrict__ Ah, const uint16_t* __restrict__ Al, int lda,
             const uint16_t* __restrict__ Wh, const uint16_t* __restrict__ Wl,
             const uint16_t* __restrict__ W2h, const uint16_t* __restrict__ W2l,
             const float* __restrict__ bias, const float* __restrict__ addend,
             float* __restrict__ D0, float* __restrict__ D1, float* __restrict__ D2,
             float* __restrict__ D3, uint8_t* __restrict__ o8,
             uint16_t* __restrict__ oH, uint16_t* __restrict__ oL,
             int K, int D)
{
  __shared__ __align__(16) uint16_t sm[4][2][4096];
  int tid = threadIdx.x, lane = tid & 63, wave = tid >> 6;
  int wr = wave >> 1, wc = wave & 1;
  int arow = lane & 15, agrp = lane >> 4;
  int rowBase = blockIdx.y * 128;
  bool isRoute = (EPI == EPI_QROUTE) && ((int)blockIdx.x < 4);
  const uint16_t* Wsh = isRoute ? W2h : Wh;
  const uint16_t* Wsl = isRoute ? W2l : Wl;
  int wst     = isRoute ? 3072 : K;
  int colBase = isRoute ? 0 : ((EPI == EPI_QROUTE ? (int)blockIdx.x - 4 : (int)blockIdx.x) * 128);
  int kBase   = isRoute ? (int)blockIdx.x * 768 : 0;
  int kLen    = isRoute ? 768 : K;
  f32x4 acc[4][4];
#pragma unroll
  for (int m = 0; m < 4; m++)
#pragma unroll
    for (int n = 0; n < 4; n++){ f32x4 z = {0.f,0.f,0.f,0.f}; acc[m][n] = z; }

#define STAGE_G(buf, k0) do { \
  _Pragma("unroll") \
  for (int s = 0; s < 2; s++){ \
    int u = tid + s * 256; \
    int rr = u >> 2; \
    int ch = (u & 3) ^ ((rr >> 1) & 3); \
    size_t ga = (size_t)(rowBase + rr) * lda + kBase + (k0) + ch * 8; \
    size_t gw = (size_t)(colBase + rr) * wst + kBase + (k0) + ch * 8; \
    gload16(&Ah[ga], &sm[0][buf][u << 3]); \
    gload16(&Al[ga], &sm[1][buf][u << 3]); \
    gload16(&Wsh[gw], &sm[2][buf][u << 3]); \
    gload16(&Wsl[gw], &sm[3][buf][u << 3]); \
  } } while(0)

  int nk = kLen >> 5;
  STAGE_G(0, 0);
  if (nk > 1) STAGE_G(1, 32);
  int perm = (arow >> 1) & 3;
#pragma unroll 1
  for (int ki = 0; ki < nk; ki++){
    int cb = ki & 1;
    if (ki + 1 < nk) asm volatile("s_waitcnt vmcnt(8)" ::: "memory");
    else             asm volatile("s_waitcnt vmcnt(0)" ::: "memory");
    __builtin_amdgcn_s_barrier();
    bf16x8 ah[4], al[4], bh[4], bl[4];
#pragma unroll
    for (int m = 0; m < 4; m++){
      int u = ((wr*64 + m*16 + arow) << 2) + (agrp ^ perm);
      ah[m] = *(const bf16x8*)&sm[0][cb][u << 3];
      al[m] = *(const bf16x8*)&sm[1][cb][u << 3];
    }
#pragma unroll
    for (int n = 0; n < 4; n++){
      int u = ((wc*64 + n*16 + arow) << 2) + (agrp ^ perm);
      bh[n] = *(const bf16x8*)&sm[2][cb][u << 3];
      bl[n] = *(const bf16x8*)&sm[3][cb][u << 3];
    }
#pragma unroll
    for (int m = 0; m < 4; m++)
#pragma unroll
      for (int n = 0; n < 4; n++){
        acc[m][n] = __builtin_amdgcn_mfma_f32_16x16x32_bf16(ah[m], bh[n], acc[m][n], 0, 0, 0);
        acc[m][n] = __builtin_amdgcn_mfma_f32_16x16x32_bf16(ah[m], bl[n], acc[m][n], 0, 0, 0);
        acc[m][n] = __builtin_amdgcn_mfma_f32_16x16x32_bf16(al[m], bh[n], acc[m][n], 0, 0, 0);
      }
    __builtin_amdgcn_s_barrier();
    asm volatile("" ::: "memory");
    if (ki + 2 < nk) STAGE_G(cb, (ki + 2) << 5);
  }
#undef STAGE_G
#pragma unroll
  for (int m = 0; m < 4; m++){
#pragma unroll
    for (int n = 0; n < 4; n++){
      int col = colBase + wc*64 + n*16 + arow;
#pragma unroll
      for (int r2 = 0; r2 < 4; r2++){
        int row = rowBase + wr*64 + m*16 + agrp*4 + r2;
        float v = acc[m][n][r2];
        if (EPI == EPI_GELU){
          v += bias[col];
          v = 0.5f * v * (1.f + erff(v * 0.7071067811865475f));
          size_t idx = (size_t)row * D + col;
          uint16_t h = f2bf(v); oH[idx] = h; oL[idx] = f2bf(v - bf2f(h));
        }
        if (EPI == EPI_CUR){
          v += bias[col] + addend[(size_t)row * 1024 + col];
          D0[(size_t)row * 1024 + col] = v;
          size_t idx = (size_t)row * 3072 + col;
          uint16_t h = f2bf(v); oH[idx] = h; oL[idx] = f2bf(v - bf2f(h));
          o8[(size_t)row * 1024 + col] = f2fp8(v);
        }
        if (EPI == EPI_PRE){
          if (col < 2048) D0[(size_t)row * 2048 + col] = v / (1.f + expf(-v));
          else D1[(size_t)row * 128 + col - 2048] = v;
        }
        if (EPI == EPI_QROUTE){
          if (isRoute){
            D3[((size_t)blockIdx.x * N_TOK + row) * 128 + col] = v;
          } else {
            if (col < 1024) D0[(size_t)row * 1024 + col] = v;
            else if (col < 4096) D1[(size_t)row * 3072 + col - 1024] = v + bias[col - 1024];
            else if (col < 4160) D2[(size_t)row * 128 + col - 4096] = v;
          }
        }
      }
    }
  }
}

// ---------------- sparse expert up: fp8, persistent, depth-3, XCD-grouped -------
// 1-D grid of 768: bid = ex*192 + ey  (192 % 8 == 0 => the 4 ex-blocks of one
// tile ey share bid%8 == ey%8 -> same XCD -> one L2 copy of the W tile).
__global__ __launch_bounds__(256)
void expert_up_mfma(const uint8_t* __restrict__ A8, const uint8_t* __restrict__ U8,
                    const int* __restrict__ cnt, const int* __restrict__ gidx,
                    uint16_t* __restrict__ HH)
{
  int bid = blockIdx.x;
  int ex = bid / 192;
  int ey = bid - ex * 192;
  if (ey >= 188) return;
  int e = 0;
#pragma unroll
  for (int i = 1; i < 11; i++) if (ey >= c_cum[i]) e = i;
  int ct = ey - c_cum[e];
  int dcols = c_dims[e];
  int ne = cnt[e];
  const uint8_t* W = U8 + (size_t)e * DMAX * IN_D + (size_t)ct * 128 * IN_D;

  __shared__ __align__(16) uint8_t smem[32768];
  int tid = threadIdx.x, lane = tid & 63, wave = tid >> 6;
  int wr = wave >> 1, wc = wave & 1;
  int arow = lane & 15, agrp = lane >> 4;
  int actid = c_acts[e];
  size_t base_e = (size_t)N_TOK * c_offs[e];
  int rHalf = tid >> 1;
  // both-sides 16B swizzle: source half inverts the read swizzle
  int h16 = (((tid & 1) ^ ((tid >> 3) & 1)) << 4);
  // lane-constant read offset within the 32B row-pair (2-way banks = free)
  int off = ((((agrp >> 1) ^ ((arow >> 2) & 1)) << 4) | ((agrp & 1) << 3));

#define STAGE_E(b, k0) do { \
    gload16b(&A8[(size_t)tok * IN_D + (k0) + h16], &smem[(b)*8192 + tid*16]); \
    gload16b(&W[(size_t)rHalf * IN_D + (k0) + h16], &smem[(b)*8192 + 4096 + tid*16]); \
  } while(0)

#pragma unroll 1
  for (int rowBase = ex * 128; rowBase < ne; rowBase += 4 * 128){
    int slot = rowBase + rHalf;
    int tok = (slot < ne) ? gidx[e * N_TOK + slot] : 0;

    f32x4 acc[4][4];
#pragma unroll
    for (int m = 0; m < 4; m++)
#pragma unroll
      for (int n = 0; n < 4; n++){ f32x4 z = {0.f,0.f,0.f,0.f}; acc[m][n] = z; }

    STAGE_E(0, 0);
    STAGE_E(1, 32);
    STAGE_E(2, 64);
    int cb = 0;
#pragma unroll 1
    for (int ki = 0; ki < 32; ki++){
      if (ki < 30)       asm volatile("s_waitcnt vmcnt(4)" ::: "memory");
      else if (ki == 30) asm volatile("s_waitcnt vmcnt(2)" ::: "memory");
      else               asm volatile("s_waitcnt vmcnt(0)" ::: "memory");
      __builtin_amdgcn_s_barrier();
      long a[4], b[4];
#pragma unroll
      for (int m = 0; m < 4; m++)
        a[m] = *(const long*)&smem[cb*8192 + (wr*64 + m*16 + arow)*32 + off];
#pragma unroll
      for (int n = 0; n < 4; n++)
        b[n] = *(const long*)&smem[cb*8192 + 4096 + (wc*64 + n*16 + arow)*32 + off];
#pragma unroll
      for (int m = 0; m < 4; m++)
#pragma unroll
        for (int n = 0; n < 4; n++)
          acc[m][n] = __builtin_amdgcn_mfma_f32_16x16x32_fp8_fp8(a[m], b[n], acc[m][n], 0, 0, 0);
      __builtin_amdgcn_s_barrier();
      asm volatile("" ::: "memory");
      if (ki + 3 < 32) STAGE_E(cb, (ki + 3) << 5);
      cb = (cb == 2) ? 0 : cb + 1;
    }
    uint16_t* Ht = (uint16_t*)smem;
#pragma unroll
    for (int m = 0; m < 4; m++){
      int rb0 = wr*64 + m*16 + agrp*4;
#pragma unroll
      for (int n = 0; n < 4; n++){
        int col = wc*64 + n*16 + arow;
#pragma unroll
        for (int r2 = 0; r2 < 4; r2++){
          int row = rb0 + r2;
          float v = actf(actid, acc[m][n][r2]);
          Ht[row * 128 + (col ^ ((row & 7) << 3))] = f2bf(v);
        }
      }
    }
    __syncthreads();
#pragma unroll
    for (int i = 0; i < 8; i++){
      int c = tid + i * 256;
      int row = c >> 4, chunk = c & 15;
      int schunk = (chunk & 8) | ((chunk ^ row) & 7);
      int4 val = *(const int4*)&Ht[row * 128 + schunk * 8];
      *(int4*)&HH[base_e + (size_t)(rowBase + row) * dcols
                  + (size_t)ct * 128 + chunk * 8] = val;
    }
    __syncthreads();
  }
#undef STAGE_E
}

// ---------------- ctx_enr: mem softmax, depth attn, mctx/dctx/enriched/LN ------
__global__ __launch_bounds__(256)
void ctx_enr_kernel(const float* __restrict__ qaux, const float* __restrict__ dqbuf,
                    const float* __restrict__ Ac, const float* __restrict__ W0,
                    const float* __restrict__ W1, const float* __restrict__ W2,
                    const float* __restrict__ mvi,
                    const float* __restrict__ t0, const float* __restrict__ t1,
                    const float* __restrict__ t2, const float* __restrict__ cur,
                    const float* __restrict__ sab, const float* __restrict__ sbw,
                    const float* __restrict__ sbb, const float* __restrict__ lng,
                    const float* __restrict__ lnbv,
                    float* __restrict__ enr, uint16_t* __restrict__ lnh,
                    uint16_t* __restrict__ lnl, uint16_t* __restrict__ Arh,
                    uint16_t* __restrict__ Arl, int t)
{
  int row = blockIdx.x, tid = threadIdx.x;
  __shared__ float su[24], ss[3], s40[40], red[12], redm[8];
  if (tid < 64){
    float pj = (tid < 24) ? qaux[(size_t)row * 128 + tid] * 0.03125f : -1e30f;
    float mx = wmax(pj);
    float ex = (tid < 24) ? expf(pj - mx) : 0.f;
    float sum = wred(ex);
    float attn = ex / sum;
    if (tid < 24) su[tid] = attn * Ac[row * 24 + tid];
    float w0v = (t > 0 && tid < 24) ? W0[row * 24 + tid] : 0.f;
    float s0 = wred(attn * w0v);
    float w1v = (t > 1 && tid < 24) ? W1[row * 24 + tid] : 0.f;
    float s1 = wred(attn * w1v);
    float w2v = (t > 2 && tid < 24) ? W2[row * 24 + tid] : 0.f;
    float s2 = wred(attn * w2v);
    if (tid == 0){ ss[0] = s0; ss[1] = s1; ss[2] = s2; }
    if (tid < 40) s40[tid] = tanhf(qaux[(size_t)row * 128 + 24 + tid] + sab[tid]);
  }
  size_t tb = (size_t)row * 3072;
  if (t > 0){
    float a0 = 0.f, a1 = 0.f, a2 = 0.f;
#pragma unroll
    for (int j = 0; j < 4; j++){
      int d = tid + j * 256;
      float dq = dqbuf[(size_t)row * 1024 + d];
      a0 = fmaf(dq, t0[tb + d], a0);
      if (t > 1) a1 = fmaf(dq, t1[tb + d], a1);
      if (t > 2) a2 = fmaf(dq, t2[tb + d], a2);
    }
    a0 = wred(a0); a1 = wred(a1); a2 = wred(a2);
    if ((tid & 63) == 0){ int w = tid >> 6; red[w] = a0; red[4+w] = a1; red[8+w] = a2; }
  }
  __syncthreads();
  float e0 = 0.f, e1 = 0.f, e2 = 0.f;
  if (t > 0){
    float A0 = (red[0]+red[1]+red[2]+red[3]) * 0.03125f;
    float A1 = (red[4]+red[5]+red[6]+red[7]) * 0.03125f;
    float A2 = (red[8]+red[9]+red[10]+red[11]) * 0.03125f;
    float dmx = A0;
    if (t > 1) dmx = fmaxf(dmx, A1);
    if (t > 2) dmx = fmaxf(dmx, A2);
    e0 = expf(A0 - dmx);
    e1 = (t > 1) ? expf(A1 - dmx) : 0.f;
    e2 = (t > 2) ? expf(A2 - dmx) : 0.f;
    float dinv = 1.f / (e0 + e1 + e2);
    e0 *= dinv; e1 *= dinv; e2 *= dinv;
  }
  size_t ar = (size_t)row * 3072;
  float ev[4];
  float part = 0.f;
#pragma unroll
  for (int j = 0; j < 4; j++){
    int d = tid + j * 256;
    size_t idx = (size_t)row * IN_D + d;
    float mv = 0.f;
#pragma unroll
    for (int m = 0; m < 24; m++) mv = fmaf(su[m], mvi[m * IN_D + d], mv);
    float dv = 0.f;
    if (t > 0){
      mv = fmaf(ss[0], t0[tb + 2048 + d], mv);
      dv = e0 * t0[tb + 1024 + d];
      if (t > 1){ mv = fmaf(ss[1], t1[tb + 2048 + d], mv); dv = fmaf(e1, t1[tb + 1024 + d], dv); }
      if (t > 2){ mv = fmaf(ss[2], t2[tb + 2048 + d], mv); dv = fmaf(e2, t2[tb + 1024 + d], dv); }
    }
    float sv = sbb[d];
#pragma unroll
    for (int o = 0; o < 40; o++) sv = fmaf(s40[o], sbw[d * 40 + o], sv);
    float v = cur[idx] + 0.34f * mv + 0.22f * dv + 0.18f * sv;
    uint16_t mh = f2bf(mv);
    Arh[ar + 1024 + d] = mh; Arl[ar + 1024 + d] = f2bf(mv - bf2f(mh));
    uint16_t dh = f2bf(dv);
    Arh[ar + 2048 + d] = dh; Arl[ar + 2048 + d] = f2bf(dv - bf2f(dh));
    ev[j] = v; part += v;
  }
  part = wred(part);
  if ((tid & 63) == 0) redm[tid >> 6] = part;
  __syncthreads();
  float mean = (redm[0] + redm[1] + redm[2] + redm[3]) * (1.f / 1024.f);
  float vp = 0.f;
#pragma unroll
  for (int j = 0; j < 4; j++){ float dd = ev[j] - mean; vp += dd * dd; }
  vp = wred(vp);
  if ((tid & 63) == 0) redm[4 + (tid >> 6)] = vp;
  __syncthreads();
  float var = (redm[4] + redm[5] + redm[6] + redm[7]) * (1.f / 1024.f);
  float rs = 1.f / sqrtf(var + 1e-5f);
#pragma unroll
  for (int j = 0; j < 4; j++){
    int d = tid + j * 256;
    size_t idx = (size_t)row * IN_D + d;
    enr[idx] = ev[j];
    float v = (ev[j] - mean) * rs * lng[t * IN_D + d] + lnbv[t * IN_D + d];
    uint16_t h = f2bf(v);
    lnh[idx] = h;
    lnl[idx] = f2bf(v - bf2f(h));
  }
}

// ---------------- route_fin: sums 4 K-split partials, softmaxes, top-k ----------
__global__ __launch_bounds__(256)
void route_fin(const float* __restrict__ ROq, const float* __restrict__ mmb,
               const float* __restrict__ msb, const float* __restrict__ ebias,
               const float* __restrict__ bb, const float* __restrict__ wgb,
               const float* __restrict__ hb,
               float* __restrict__ sg, float* __restrict__ haltb,
               float* __restrict__ Ac, float* __restrict__ W0,
               float* __restrict__ W1, float* __restrict__ W2,
               int* __restrict__ cnt, int* __restrict__ gidx,
               int* __restrict__ pos, float* __restrict__ routeS, int t)
{
  int row = blockIdx.x * 256 + threadIdx.x;
  int lane = threadIdx.x & 63;
  const size_t P = (size_t)N_TOK * 128;
  const float* r0 = ROq + (size_t)row * 128;
  const float* r1 = r0 + P;
  const float* r2 = r0 + 2 * P;
  const float* r3 = r0 + 3 * P;
  auto R = [&](int j){ return r0[j] + r1[j] + r2[j] + r3[j]; };
  float pm[4];
#pragma unroll
  for (int o = 0; o < 4; o++) pm[o] = R(40 + o) + mmb[o];
  float mmx = fmaxf(fmaxf(pm[0], pm[1]), fmaxf(pm[2], pm[3]));
  float msum = 0.f;
#pragma unroll
  for (int o = 0; o < 4; o++){ pm[o] = expf(pm[o] - mmx); msum += pm[o]; }
  float minv = 1.f / msum;
  float gl[10];
#pragma unroll
  for (int e = 0; e < 10; e++){
    float g = ebias[e];
#pragma unroll
    for (int s2 = 0; s2 < 4; s2++)
      g = fmaf(pm[s2] * minv, R(s2 * 10 + e) + msb[s2 * 10 + e], g);
    gl[e] = g;
  }
  float gmx = gl[0];
#pragma unroll
  for (int e = 1; e < 10; e++) gmx = fmaxf(gmx, gl[e]);
  float gs = 0.f;
#pragma unroll
  for (int e = 0; e < 10; e++){ gl[e] = expf(gl[e] - gmx); gs += gl[e]; }
  float ginv = 1.f / gs;
#pragma unroll
  for (int e = 0; e < 10; e++) gl[e] *= ginv;
  float pb0 = R(44) + bb[0], pb1 = R(45) + bb[1], pb2 = R(46) + bb[2], pb3 = R(47) + bb[3];
  int bud = 1; float bbest = pb0;
  if (pb1 > bbest){ bbest = pb1; bud = 2; }
  if (pb2 > bbest){ bbest = pb2; bud = 3; }
  if (pb3 > bbest){ bbest = pb3; bud = 4; }
  float tv[4]; int ti[4]; unsigned used = 0;
#pragma unroll
  for (int j = 0; j < 4; j++){
    float best = -1e30f; int bi = 0;
#pragma unroll
    for (int e = 0; e < 10; e++){
      bool ok = (!((used >> e) & 1u)) && (gl[e] > best);
      if (ok){ best = gl[e]; bi = e; }
    }
    tv[j] = best; ti[j] = bi; used |= (1u << bi);
  }
  float ssum = tv[0];
  if (bud > 1) ssum += tv[1];
  if (bud > 2) ssum += tv[2];
  if (bud > 3) ssum += tv[3];
  float den = fmaxf(ssum, 1e-6f);
  float sup = 1.f - tv[0] / den;
  float sgv[10];
#pragma unroll
  for (int e = 0; e < 10; e++){
    float sv = 0.f;
#pragma unroll
    for (int j = 0; j < 4; j++) if (j < bud && ti[j] == e) sv = tv[j] / den;
    sgv[e] = sv;
    sg[row * 10 + e] = sv;
  }
  float pw[24];
#pragma unroll
  for (int m = 0; m < 24; m++) pw[m] = R(48 + m) + wgb[m];
  float wmx2 = pw[0];
#pragma unroll
  for (int m = 1; m < 24; m++) wmx2 = fmaxf(wmx2, pw[m]);
  float wsum = 0.f;
#pragma unroll
  for (int m = 0; m < 24; m++){ pw[m] = expf(pw[m] - wmx2); wsum += pw[m]; }
  float winv = 1.f / wsum;
#pragma unroll
  for (int m = 0; m < 24; m++){
    float c = sup * pw[m] * winv;
    float om = 1.f - c;
    Ac[row * 24 + m] *= om;
    if (t > 0) W0[row * 24 + m] *= om;
    if (t > 1) W1[row * 24 + m] *= om;
    if (t > 2) W2[row * 24 + m] *= om;
    if (t == 0)      W0[row * 24 + m] = c;
    else if (t == 1) W1[row * 24 + m] = c;
    else if (t == 2) W2[row * 24 + m] = c;
  }
  haltb[row] = 1.f / (1.f + expf(-(R(72) + hb[t])));
#pragma unroll
  for (int i = 0; i < 30; i++) routeS[row * 32 + i] = R(73 + i);
#pragma unroll
  for (int e = 0; e < 10; e++){
    bool act = sgv[e] != 0.f;
    unsigned long long mask = __ballot(act);
    int cw = __popcll(mask);
    int b0 = 0;
    if (lane == 0 && cw > 0) b0 = atomicAdd(&cnt[e], cw);
    b0 = __shfl(b0, 0, 64);
    if (act){
      int slot = b0 + __popcll(mask & ((1ull << lane) - 1ull));
      gidx[e * N_TOK + slot] = row;
      pos[row * 10 + e] = slot;
    }
  }
}

// ---------------- downfin: expert down + LN + gated acc + step finalize --------
__global__ __launch_bounds__(256)
void downfin_kernel(const uint16_t* __restrict__ HH, const int* __restrict__ pos,
                    const float* __restrict__ ED, const float* __restrict__ sg,
                    const float* __restrict__ eng, const float* __restrict__ enb,
                    const float* __restrict__ routeS, const float* __restrict__ haltb,
                    float* __restrict__ total, float* __restrict__ cumh)
{
  int lane = threadIdx.x & 63;
  int row = blockIdx.x * 4 + (threadIdx.x >> 6);
  float out[10] = {};
  for (int e = 0; e < NEXP; e++){
    float g = sg[row * 10 + e];
    if (g != 0.0f){
      int d = c_dims[e];
      int slot = pos[row * 10 + e];
      const uint16_t* hr = HH + (size_t)N_TOK * c_offs[e] + (size_t)slot * d;
      const float* wd = ED + (size_t)e * 10 * DMAX;
      float p[10] = {};
      for (int k = lane * 4; k < d; k += 256){
        uint2 hv = *(const uint2*)&hr[k];
        float h0 = bf2f((uint16_t)hv.x), h1 = bf2f((uint16_t)(hv.x >> 16));
        float h2 = bf2f((uint16_t)hv.y), h3 = bf2f((uint16_t)(hv.y >> 16));
#pragma unroll
        for (int o = 0; o < 10; o++){
          float4 w4 = *(const float4*)&wd[o * DMAX + k];
          p[o] = fmaf(h0, w4.x, fmaf(h1, w4.y, fmaf(h2, w4.z, fmaf(h3, w4.w, p[o]))));
        }
      }
#pragma unroll
      for (int o = 0; o < 10; o++) p[o] = wred(p[o]);
      float mean = 0.f;
#pragma unroll
      for (int o = 0; o < 10; o++) mean += p[o];
      mean *= 0.1f;
      float var = 0.f;
#pragma unroll
      for (int o = 0; o < 10; o++){ float dd = p[o] - mean; var += dd * dd; }
      var *= 0.1f;
      float rs = 1.f / sqrtf(var + 1e-5f);
#pragma unroll
      for (int o = 0; o < 10; o++)
        out[o] += g * ((p[o] - mean) * rs * eng[e * 10 + o] + enb[e * 10 + o]);
    }
  }
  if (lane == 0){
    const float* r = routeS + (size_t)row * 32;
    float rem = 1.f - cumh[row];
#pragma unroll
    for (int o = 0; o < 10; o++)
      total[row * 10 + o] += rem * (out[o] + 0.22f * r[o] + 0.14f * r[10 + o]);
    cumh[row] += rem * haltb[row];
  }
}

// ---------------- shared branch --------------------------------------------------
__global__ __launch_bounds__(256)
void shared_kernel(const float* __restrict__ shpre, const float* __restrict__ sdw,
                   const float* __restrict__ g, const float* __restrict__ b,
                   float* __restrict__ outp)
{
  int lane = threadIdx.x & 63;
  int row = blockIdx.x * 4 + (threadIdx.x >> 6);
  const float* xr = shpre + (size_t)row * SHD;
  float p[10];
#pragma unroll
  for (int o = 0; o < 10; o++) p[o] = 0.f;
  for (int k = lane; k < SHD; k += 64){
    float xv = xr[k];
#pragma unroll
    for (int o = 0; o < 10; o++) p[o] = fmaf(xv, sdw[o * SHD + k], p[o]);
  }
#pragma unroll
  for (int o = 0; o < 10; o++) p[o] = wred(p[o]);
  float mean = 0.f;
#pragma unroll
  for (int o = 0; o < 10; o++) mean += p[o];
  mean *= 0.1f;
  float var = 0.f;
#pragma unroll
  for (int o = 0; o < 10; o++){ float dd = p[o] - mean; var += dd * dd; }
  var *= 0.1f;
  float rs = 1.f / sqrtf(var + 1e-5f);
  if (lane == 0){
#pragma unroll
    for (int o = 0; o < 10; o++) outp[row * 10 + o] = (p[o] - mean) * rs * g[o] + b[o];
  }
}

// ---------------- final output (lite) --------------------------------------------
__global__ __launch_bounds__(256)
void final_lite(const float* __restrict__ qaux, const float* __restrict__ biasp,
                const float* __restrict__ sharedp, const float* __restrict__ total,
                const float* __restrict__ routeS, const float* __restrict__ sscale,
                const float* __restrict__ alphap, const float* __restrict__ betap,
                float* __restrict__ outp)
{
  int row = blockIdx.x * 256 + threadIdx.x;
  float ss = sscale[0], av = alphap[0] + 1e-4f, bv = betap[0];
#pragma unroll
  for (int o = 0; o < 10; o++)
    outp[row * 10 + o] = (qaux[(size_t)row * 128 + 64 + o] + biasp[o])
                       + ss * sharedp[row * 10 + o]
                       + av * (total[row * 10 + o] * 0.25f)
                       + bv * routeS[(size_t)row * 32 + 20 + o];
}

// ====================================================================================
extern "C" void kernel_launch(void* const* d_in, const int* in_sizes, int n_in,
                              void* d_out, int out_size, void* d_ws, size_t ws_size,
                              hipStream_t stream)
{
  const float* x     = (const float*)d_in[0];
  const float* wgt   = (const float*)d_in[1];
  const float* bias  = (const float*)d_in[2];
  const float* suw   = (const float*)d_in[3];
  const float* sdw   = (const float*)d_in[4];
  const float* sng   = (const float*)d_in[5];
  const float* snb   = (const float*)d_in[6];
  const float* sscale= (const float*)d_in[7];
  const float* keys  = (const float*)d_in[8];
  const float* mvi   = (const float*)d_in[9];
  const float* mqw   = (const float*)d_in[10];
  const float* mow   = (const float*)d_in[11];
  const float* wgw   = (const float*)d_in[12];
  const float* wgb   = (const float*)d_in[13];
  const float* wvw   = (const float*)d_in[14];
  const float* wvb   = (const float*)d_in[15];
  const float* dqw   = (const float*)d_in[16];
  const float* dkw   = (const float*)d_in[17];
  const float* dvw   = (const float*)d_in[18];
  const float* dow   = (const float*)d_in[19];
  const float* clng  = (const float*)d_in[20];
  const float* clnb  = (const float*)d_in[21];
  const float* fc1w  = (const float*)d_in[22];
  const float* fc1b  = (const float*)d_in[23];
  const float* fc2w  = (const float*)d_in[24];
  const float* fc2b  = (const float*)d_in[25];
  const float* saw   = (const float*)d_in[26];
  const float* sab   = (const float*)d_in[27];
  const float* sbw   = (const float*)d_in[28];
  const float* sbb   = (const float*)d_in[29];
  const float* msw   = (const float*)d_in[30];
  const float* msb   = (const float*)d_in[31];
  const float* mmw   = (const float*)d_in[32];
  const float* mmb   = (const float*)d_in[33];
  const float* ebias = (const float*)d_in[34];
  const float* bw    = (const float*)d_in[35];
  const float* bb    = (const float*)d_in[36];
  const float* eup   = (const float*)d_in[37];
  const float* edn   = (const float*)d_in[38];
  const float* eng   = (const float*)d_in[39];
  const float* enb   = (const float*)d_in[40];
  const float* hw    = (const float*)d_in[41];
  const float* hb    = (const float*)d_in[42];
  const float* alphap= (const float*)d_in[43];
  const float* betap = (const float*)d_in[44];
  float* outp = (float*)d_out;

  char* wsb = (char*)d_ws;
  size_t off = 0;
  auto AL = [&](size_t bytes) -> void* {
    void* p = wsb + off;
    off = (off + bytes + 255) & ~(size_t)255;
    return p;
  };
  const size_t NI = (size_t)N_TOK * IN_D;
  float* cur    = (float*)AL(NI * 4);
  float* enr    = (float*)AL(NI * 4);
  float* dqbuf  = (float*)AL(NI * 4);
  float* qaux   = (float*)AL((size_t)N_TOK * 128 * 4);
  float* routeQ = (float*)AL((size_t)4 * N_TOK * 128 * 4);
  float* routeS = (float*)AL((size_t)N_TOK * 32 * 4);
  float* trio0  = (float*)AL((size_t)N_TOK * 3072 * 4);
  float* trio1  = (float*)AL((size_t)N_TOK * 3072 * 4);
  float* trio2  = (float*)AL((size_t)N_TOK * 3072 * 4);
  float* Ac     = (float*)AL((size_t)N_TOK * 24 * 4);
  float* W0     = (float*)AL((size_t)N_TOK * 24 * 4);
  float* W1     = (float*)AL((size_t)N_TOK * 24 * 4);
  float* W2     = (float*)AL((size_t)N_TOK * 24 * 4);
  float* sg     = (float*)AL((size_t)N_TOK * 10 * 4);
  float* haltb  = (float*)AL((size_t)N_TOK * 4);
  char*  zblk   = (char*)AL((size_t)N_TOK * 10 * 4 + N_TOK * 4 + 4 * 16 * 4);
  float* total  = (float*)zblk;
  float* cumh   = (float*)(zblk + (size_t)N_TOK * 10 * 4);
  int*   cnt    = (int*)(zblk + (size_t)N_TOK * 10 * 4 + N_TOK * 4);
  int*   gidx   = (int*)AL((size_t)NEXP * N_TOK * 4);
  int*   pos    = (int*)AL((size_t)N_TOK * NEXP * 4);
  float* sharedp= (float*)AL((size_t)N_TOK * 10 * 4);
  float* cbias  = (float*)AL(3072 * 4);
  float* K2f    = (float*)AL((size_t)24 * 1024 * 4);
  uint16_t* lnh  = (uint16_t*)AL(NI * 2);
  uint16_t* lnl  = (uint16_t*)AL(NI * 2);
  uint16_t* h7h  = (uint16_t*)AL((size_t)N_TOK * INNER * 2);
  uint16_t* h7l  = (uint16_t*)AL((size_t)N_TOK * INNER * 2);
  uint16_t* Arh  = (uint16_t*)AL((size_t)N_TOK * 3072 * 2);
  uint16_t* Arl  = (uint16_t*)AL((size_t)N_TOK * 3072 * 2);
  const size_t W1M = (size_t)IN_D * IN_D;
  uint16_t* preWh  = (uint16_t*)AL((size_t)2176 * 1024 * 2);
  uint16_t* preWl  = (uint16_t*)AL((size_t)2176 * 1024 * 2);
  uint16_t* qtWh   = (uint16_t*)AL((size_t)4224 * 1024 * 2);
  uint16_t* qtWl   = (uint16_t*)AL((size_t)4224 * 1024 * 2);
  uint16_t* rtWh   = (uint16_t*)AL((size_t)4 * 128 * 3072 * 2);
  uint16_t* rtWl   = (uint16_t*)AL((size_t)4 * 128 * 3072 * 2);
  const size_t WFC = (size_t)NSTEP * INNER * IN_D;
  uint16_t* fc1wh = (uint16_t*)AL(WFC * 2); uint16_t* fc1wl = (uint16_t*)AL(WFC * 2);
  uint16_t* fc2wh = (uint16_t*)AL(WFC * 2); uint16_t* fc2wl = (uint16_t*)AL(WFC * 2);
  uint8_t* upbf8 = (uint8_t*)AL((size_t)NEXP * DMAX * IN_D);
  uint8_t* A8    = (uint8_t*)AL(NI);
  uint16_t* HHc  = (uint16_t*)AL((size_t)N_TOK * DSUM * 2);
  float* shpre  = (float*)HHc;   // alias: consumed before HHc is written

  // ---- init ----
  hipMemsetAsync(zblk, 0, (size_t)N_TOK * 10 * 4 + N_TOK * 4 + 4 * 16 * 4, stream);
  hipMemsetAsync(cbias, 0, 3072 * 4, stream);
  hipMemcpyAsync(cbias + 2048, wvb, 1024 * 4, hipMemcpyDeviceToDevice, stream);
  hipMemcpyAsync(cur, x, NI * 4, hipMemcpyDeviceToDevice, stream);
  fill1_kernel<<<(N_TOK * 24 + 255) / 256, 256, 0, stream>>>(Ac, N_TOK * 24);
  cvt_fp8_kernel<<<2048, 256, 0, stream>>>(eup, upbf8, (size_t)NEXP * DMAX * IN_D);

  split_strided<<<1024, 256, 0, stream>>>(x, Arh, Arl, N_TOK, 1024, 3072);
  split_kernel<<<1024, 256, 0, stream>>>(suw, preWh, preWl, (size_t)SHD * 1024);
  split_kernel<<<256, 256, 0, stream>>>(saw, preWh + (size_t)2072*1024, preWl + (size_t)2072*1024, (size_t)40 * 1024);
  split_kernel<<<256, 256, 0, stream>>>(wgt, preWh + (size_t)2112*1024, preWl + (size_t)2112*1024, (size_t)10 * 1024);
  hipMemsetAsync(preWh + (size_t)2122*1024, 0, (size_t)54 * 1024 * 2, stream);
  hipMemsetAsync(preWl + (size_t)2122*1024, 0, (size_t)54 * 1024 * 2, stream);
  split_kernel<<<1024, 256, 0, stream>>>(dqw, qtWh, qtWl, W1M);
  split_kernel<<<1024, 256, 0, stream>>>(dkw, qtWh + W1M, qtWl + W1M, W1M);
  split_kernel<<<1024, 256, 0, stream>>>(dvw, qtWh + 2*W1M, qtWl + 2*W1M, W1M);
  split_kernel<<<1024, 256, 0, stream>>>(wvw, qtWh + 3*W1M, qtWl + 3*W1M, W1M);
  split_kernel<<<256, 256, 0, stream>>>(saw, qtWh + (size_t)4120*1024, qtWl + (size_t)4120*1024, (size_t)40 * 1024);
  hipMemsetAsync(qtWh + (size_t)4160*1024, 0, (size_t)64 * 1024 * 2, stream);
  hipMemsetAsync(qtWl + (size_t)4160*1024, 0, (size_t)64 * 1024 * 2, stream);
  k2_kernel<<<dim3(24, 4), 256, 0, stream>>>(keys, mqw, K2f);
  split_kernel<<<256, 256, 0, stream>>>(K2f, preWh + (size_t)2048*1024, preWl + (size_t)2048*1024, (size_t)24 * 1024);
  split_kernel<<<256, 256, 0, stream>>>(K2f, qtWh + (size_t)4096*1024, qtWl + (size_t)4096*1024, (size_t)24 * 1024);
  build_routew<<<2048, 256, 0, stream>>>(msw, mmw, bw, wgw, hw, mow, dow, rtWh, rtWl);
  split_kernel<<<1024, 256, 0, stream>>>(fc1w, fc1wh, fc1wl, WFC);
  split_kernel<<<1024, 256, 0, stream>>>(fc2w, fc2wh, fc2wl, WFC);

  gemm_sp<EPI_PRE><<<dim3(17, 16), 256, 0, stream>>>(
      Arh, Arl, 3072, preWh, preWl, nullptr, nullptr, nullptr, nullptr,
      shpre, qaux, nullptr, nullptr, nullptr, nullptr, nullptr, IN_D, 2176);
  shared_kernel<<<512, 256, 0, stream>>>(shpre, sdw, sng, snb, sharedp);

  float* trioB[3] = {trio0, trio1, trio2};

  for (int t = 0; t < NSTEP; t++){
    ctx_enr_kernel<<<2048, 256, 0, stream>>>(qaux, dqbuf, Ac, W0, W1, W2, mvi,
                                             trio0, trio1, trio2, cur, sab, sbw, sbb,
                                             clng, clnb, enr, lnh, lnl, Arh, Arl, t);
    gemm_sp<EPI_GELU><<<dim3(INNER/128, 16), 256, 0, stream>>>(
        lnh, lnl, 1024, fc1wh + (size_t)t * INNER * IN_D, fc1wl + (size_t)t * INNER * IN_D,
        nullptr, nullptr, fc1b + t * INNER, nullptr,
        nullptr, nullptr, nullptr, nullptr, nullptr, h7h, h7l, IN_D, INNER);
    gemm_sp<EPI_CUR><<<dim3(8, 16), 256, 0, stream>>>(
        h7h, h7l, 768, fc2wh + (size_t)t * IN_D * INNER, fc2wl + (size_t)t * IN_D * INNER,
        nullptr, nullptr, fc2b + t * IN_D, enr,
        cur, nullptr, nullptr, nullptr, A8, Arh, Arl, INNER, IN_D);
    gemm_sp<EPI_QROUTE><<<dim3(t < 3 ? 37 : 4, 16), 256, 0, stream>>>(
        Arh, Arl, 3072, qtWh, qtWl,
        rtWh + (size_t)t * 128 * 3072, rtWl + (size_t)t * 128 * 3072,
        cbias, nullptr, dqbuf, t < 3 ? trioB[t] : nullptr, qaux, routeQ,
        nullptr, nullptr, nullptr, IN_D, 4224);
    route_fin<<<8, 256, 0, stream>>>(routeQ, mmb, msb, ebias, bb, wgb, hb,
                                     sg, haltb, Ac, W0, W1, W2,
                                     cnt + t * 16, gidx, pos, routeS, t);
    expert_up_mfma<<<768, 256, 0, stream>>>(A8, upbf8, cnt + t * 16, gidx, HHc);
    downfin_kernel<<<512, 256, 0, stream>>>(HHc, pos, edn, sg, eng, enb,
                                            routeS, haltb, total, cumh);
  }
  final_lite<<<8, 256, 0, stream>>>(qaux, bias, sharedp, total, routeS,
                                    sscale, alphap, betap, outp);
}

// Round 16
// 2076.196 us; speedup vs baseline: 1.1185x; 1.0063x over previous
//
#include <hip/hip_runtime.h>
#include <stdint.h>

#define N_TOK 2048
#define IN_D  1024
#define NEXP  10
#define NSTEP 4
#define INNER 768
#define SHD   2048
#define DMAX  3328
#define DSUM  24064

typedef __attribute__((ext_vector_type(4))) float f32x4;
typedef __attribute__((ext_vector_type(8))) short bf16x8;

__device__ const int c_dims[10] = {1536,2048,2560,3072,1792,2304,2816,2048,2560,3328};
__device__ const int c_offs[10] = {0,1536,3584,6144,9216,11008,13312,16128,18176,20736};
__device__ const int c_acts[10] = {0,1,2,3,4,5,6,7,0,1};
__device__ const int c_cum[11]  = {0,12,28,48,72,86,104,126,142,162,188};

__device__ __forceinline__ float wred(float v){
#pragma unroll
  for (int s = 32; s > 0; s >>= 1) v += __shfl_xor(v, s, 64);
  return v;
}
__device__ __forceinline__ float wmax(float v){
#pragma unroll
  for (int s = 32; s > 0; s >>= 1) v = fmaxf(v, __shfl_xor(v, s, 64));
  return v;
}
__device__ __forceinline__ float bf2f(uint16_t u){
  return __uint_as_float(((uint32_t)u) << 16);
}
__device__ __forceinline__ uint16_t f2bf(float f){
  uint32_t u = __float_as_uint(f);
  return (uint16_t)((u + 0x7FFFu + ((u >> 16) & 1u)) >> 16);
}
// float -> OCP e4m3 (RNE, saturate-finite)
__device__ __forceinline__ uint8_t f2fp8(float f){
  uint32_t u = __float_as_uint(f);
  uint8_t sign = (uint8_t)((u >> 24) & 0x80u);
  uint32_t absu = u & 0x7FFFFFFFu;
  if (absu >= 0x43E00000u) return sign | 0x7Eu;
  if (absu < 0x3C800000u){
    float af = __uint_as_float(absu);
    int q = (int)rintf(af * 512.0f);
    return sign | (uint8_t)q;
  }
  uint32_t mant = absu & 0x7FFFFFu;
  uint32_t exp = absu >> 23;
  uint32_t lsb = (mant >> 20) & 1u;
  uint32_t rounded = mant + 0x7FFFFu + lsb;
  if (rounded >= 0x800000u){ exp += 1; rounded = 0; }
  uint32_t e8 = exp - 120;
  uint32_t m8 = (rounded >> 20) & 7u;
  if (e8 > 15u || (e8 == 15u && m8 == 7u)) return sign | 0x7Eu;
  return sign | (uint8_t)((e8 << 3) | m8);
}
__device__ __forceinline__ void gload16(const uint16_t* g, uint16_t* l){
  __builtin_amdgcn_global_load_lds(
      (const __attribute__((address_space(1))) uint32_t*)(const void*)g,
      (__attribute__((address_space(3))) uint32_t*)(void*)l, 16, 0, 0);
}
__device__ __forceinline__ void gload16b(const void* g, void* l){
  __builtin_amdgcn_global_load_lds(
      (const __attribute__((address_space(1))) uint32_t*)g,
      (__attribute__((address_space(3))) uint32_t*)l, 16, 0, 0);
}

__device__ __forceinline__ float actf(int a, float x){
  switch(a){
    case 0: return x / (1.f + expf(-x));
    case 1: return 0.5f * x * (1.f + erff(x * 0.7071067811865475f));
    case 2: { float sp = fmaxf(x,0.f) + log1pf(expf(-fabsf(x)));
              return x * tanhf(sp); }
    case 3: return fmaxf(x, 0.f);
    case 4: return x > 0.f ? 1.0507009873554805f * x
                           : 1.7580993408473768f * expm1f(x);
    case 5: return tanhf(x);
    case 6: return fmaxf(x,0.f) + log1pf(expf(-fabsf(x)));
    default: return x > 0.f ? x : expm1f(x);
  }
}

// ---------------- f32 -> (hi, lo) bf16 split ------------------------------------
__global__ void split_kernel(const float* __restrict__ src, uint16_t* __restrict__ hi,
                             uint16_t* __restrict__ lo, size_t n){
  size_t i = ((size_t)blockIdx.x * blockDim.x + threadIdx.x) << 2;
  size_t stride = ((size_t)gridDim.x * blockDim.x) << 2;
  for (; i < n; i += stride){
    float4 v = *(const float4*)(src + i);
    ushort4 h, l;
    h.x = f2bf(v.x); l.x = f2bf(v.x - bf2f(h.x));
    h.y = f2bf(v.y); l.y = f2bf(v.y - bf2f(h.y));
    h.z = f2bf(v.z); l.z = f2bf(v.z - bf2f(h.z));
    h.w = f2bf(v.w); l.w = f2bf(v.w - bf2f(h.w));
    *(ushort4*)(hi + i) = h;
    *(ushort4*)(lo + i) = l;
  }
}
__global__ void split_strided(const float* __restrict__ src, uint16_t* __restrict__ hi,
                              uint16_t* __restrict__ lo, int rows, int cols, int ldd){
  int nq = rows * (cols >> 2);
  for (int i = blockIdx.x * blockDim.x + threadIdx.x; i < nq; i += gridDim.x * blockDim.x){
    int r = i / (cols >> 2), c4 = (i - r * (cols >> 2)) << 2;
    float4 v = *(const float4*)(src + (size_t)r * cols + c4);
    ushort4 h, l;
    h.x = f2bf(v.x); l.x = f2bf(v.x - bf2f(h.x));
    h.y = f2bf(v.y); l.y = f2bf(v.y - bf2f(h.y));
    h.z = f2bf(v.z); l.z = f2bf(v.z - bf2f(h.z));
    h.w = f2bf(v.w); l.w = f2bf(v.w - bf2f(h.w));
    size_t d = (size_t)r * ldd + c4;
    *(ushort4*)(hi + d) = h;
    *(ushort4*)(lo + d) = l;
  }
}
__global__ void cvt_fp8_kernel(const float* __restrict__ src, uint8_t* __restrict__ dst, size_t n){
  size_t i = ((size_t)blockIdx.x * blockDim.x + threadIdx.x) << 2;
  size_t stride = ((size_t)gridDim.x * blockDim.x) << 2;
  for (; i < n; i += stride){
    float4 v = *(const float4*)(src + i);
    uchar4 q;
    q.x = f2fp8(v.x); q.y = f2fp8(v.y); q.z = f2fp8(v.z); q.w = f2fp8(v.w);
    *(uchar4*)(dst + i) = q;
  }
}
__global__ void fill1_kernel(float* __restrict__ p, int n){
  int i = blockIdx.x * blockDim.x + threadIdx.x;
  if (i < n) p[i] = 1.f;
}
// sbw [1024][40] -> sbwT [40][1024]
__global__ void tr_sbw_kernel(const float* __restrict__ src, float* __restrict__ dst){
  int i = blockIdx.x * 256 + threadIdx.x;
  if (i < 40 * 1024){
    int o = i >> 10, d = i & 1023;
    dst[i] = src[d * 40 + o];
  }
}

// ---------------- K2 = keys @ mqw  [24,1024] ------------------------------------
__global__ __launch_bounds__(256)
void k2_kernel(const float* __restrict__ keys, const float* __restrict__ mqw,
               float* __restrict__ K2){
  int m = blockIdx.x;
  int j = blockIdx.y * 256 + threadIdx.x;
  float acc = 0.f;
  for (int d = 0; d < 1024; d++)
    acc = fmaf(keys[m * 1024 + d], mqw[d * 1024 + j], acc);
  K2[m * 1024 + j] = acc;
}

// ---------------- route weight builder: 4 x [128 rows x 3072] -------------------
__global__ void build_routew(const float* __restrict__ msw, const float* __restrict__ mmw,
                             const float* __restrict__ bw, const float* __restrict__ wgw,
                             const float* __restrict__ hw, const float* __restrict__ mow,
                             const float* __restrict__ dow, uint16_t* __restrict__ Wh,
                             uint16_t* __restrict__ Wl){
  const int TOT = 4 * 128 * 3072;
  for (int i = blockIdx.x * 256 + threadIdx.x; i < TOT; i += gridDim.x * 256){
    int t = i / (128 * 3072);
    int rem = i - t * (128 * 3072);
    int row = rem / 3072, col = rem - row * 3072;
    float v = 0.f;
    if (row < 40){ if (col < 1024) v = msw[row * 1024 + col]; }
    else if (row < 44){ if (col < 1024) v = mmw[(row - 40) * 1024 + col]; }
    else if (row < 48){ if (col < 1024) v = bw[(row - 44) * 1024 + col]; }
    else if (row < 72){ if (col < 2048) v = wgw[(row - 48) * 2048 + col]; }
    else if (row == 72){
      if (col < 1024) v = hw[t * 1024 + col];
      else if (col < 2048) v = 0.2f * hw[t * 1024 + col - 1024];
      else v = 0.1f * hw[t * 1024 + col - 2048];
    }
    else if (row < 83){ if (col >= 1024 && col < 2048) v = mow[(row - 73) * 1024 + col - 1024]; }
    else if (row < 93){ if (col >= 2048) v = dow[(row - 83) * 1024 + col - 2048]; }
    else if (row < 103){ if (col < 1024) v = mow[(row - 93) * 1024 + col]; }
    uint16_t h = f2bf(v);
    Wh[i] = h; Wl[i] = f2bf(v - bf2f(h));
  }
}

// ---------------- split-bf16 MFMA GEMM, counted-vmcnt 2-deep pipeline -----------
enum { EPI_GELU=0, EPI_CUR=1, EPI_PRE=2, EPI_QROUTE=3 };

template<int EPI>
__global__ __launch_bounds__(256)
void gemm_sp(const uint16_t* __restrict__ Ah, const uint16_t* __restrict__ Al, int lda,
             const uint16_t* __restrict__ Wh, const uint16_t* __restrict__ Wl,
             const uint16_t* __restrict__ W2h, const uint16_t* __restrict__ W2l,
             const float* __restrict__ bias, const float* __restrict__ addend,
             float* __restrict__ D0, float* __restrict__ D1, float* __restrict__ D2,
             float* __restrict__ D3, uint8_t* __restrict__ o8,
             uint16_t* __restrict__ oH, uint16_t* __restrict__ oL,
             int K, int D)
{
  __shared__ __align__(16) uint16_t sm[4][2][4096];
  int tid = threadIdx.x, lane = tid & 63, wave = tid >> 6;
  int wr = wave >> 1, wc = wave & 1;
  int arow = lane & 15, agrp = lane >> 4;
  int rowBase = blockIdx.y * 128;
  bool isRoute = (EPI == EPI_QROUTE) && ((int)blockIdx.x < 4);
  const uint16_t* Wsh = isRoute ? W2h : Wh;
  const uint16_t* Wsl = isRoute ? W2l : Wl;
  int wst     = isRoute ? 3072 : K;
  int colBase = isRoute ? 0 : ((EPI == EPI_QROUTE ? (int)blockIdx.x - 4 : (int)blockIdx.x) * 128);
  int kBase   = isRoute ? (int)blockIdx.x * 768 : 0;
  int kLen    = isRoute ? 768 : K;
  f32x4 acc[4][4];
#pragma unroll
  for (int m = 0; m < 4; m++)
#pragma unroll
    for (int n = 0; n < 4; n++){ f32x4 z = {0.f,0.f,0.f,0.f}; acc[m][n] = z; }

#define STAGE_G(buf, k0) do { \
  _Pragma("unroll") \
  for (int s = 0; s < 2; s++){ \
    int u = tid + s * 256; \
    int rr = u >> 2; \
    int ch = (u & 3) ^ ((rr >> 1) & 3); \
    size_t ga = (size_t)(rowBase + rr) * lda + kBase + (k0) + ch * 8; \
    size_t gw = (size_t)(colBase + rr) * wst + kBase + (k0) + ch * 8; \
    gload16(&Ah[ga], &sm[0][buf][u << 3]); \
    gload16(&Al[ga], &sm[1][buf][u << 3]); \
    gload16(&Wsh[gw], &sm[2][buf][u << 3]); \
    gload16(&Wsl[gw], &sm[3][buf][u << 3]); \
  } } while(0)

  int nk = kLen >> 5;
  STAGE_G(0, 0);
  if (nk > 1) STAGE_G(1, 32);
  int perm = (arow >> 1) & 3;
#pragma unroll 1
  for (int ki = 0; ki < nk; ki++){
    int cb = ki & 1;
    if (ki + 1 < nk) asm volatile("s_waitcnt vmcnt(8)" ::: "memory");
    else             asm volatile("s_waitcnt vmcnt(0)" ::: "memory");
    __builtin_amdgcn_s_barrier();
    bf16x8 ah[4], al[4], bh[4], bl[4];
#pragma unroll
    for (int m = 0; m < 4; m++){
      int u = ((wr*64 + m*16 + arow) << 2) + (agrp ^ perm);
      ah[m] = *(const bf16x8*)&sm[0][cb][u << 3];
      al[m] = *(const bf16x8*)&sm[1][cb][u << 3];
    }
#pragma unroll
    for (int n = 0; n < 4; n++){
      int u = ((wc*64 + n*16 + arow) << 2) + (agrp ^ perm);
      bh[n] = *(const bf16x8*)&sm[2][cb][u << 3];
      bl[n] = *(const bf16x8*)&sm[3][cb][u << 3];
    }
#pragma unroll
    for (int m = 0; m < 4; m++)
#pragma unroll
      for (int n = 0; n < 4; n++){
        acc[m][n] = __builtin_amdgcn_mfma_f32_16x16x32_bf16(ah[m], bh[n], acc[m][n], 0, 0, 0);
        acc[m][n] = __builtin_amdgcn_mfma_f32_16x16x32_bf16(ah[m], bl[n], acc[m][n], 0, 0, 0);
        acc[m][n] = __builtin_amdgcn_mfma_f32_16x16x32_bf16(al[m], bh[n], acc[m][n], 0, 0, 0);
      }
    __builtin_amdgcn_s_barrier();
    asm volatile("" ::: "memory");
    if (ki + 2 < nk) STAGE_G(cb, (ki + 2) << 5);
  }
#undef STAGE_G
#pragma unroll
  for (int m = 0; m < 4; m++){
#pragma unroll
    for (int n = 0; n < 4; n++){
      int col = colBase + wc*64 + n*16 + arow;
#pragma unroll
      for (int r2 = 0; r2 < 4; r2++){
        int row = rowBase + wr*64 + m*16 + agrp*4 + r2;
        float v = acc[m][n][r2];
        if (EPI == EPI_GELU){
          v += bias[col];
          v = 0.5f * v * (1.f + erff(v * 0.7071067811865475f));
          size_t idx = (size_t)row * D + col;
          uint16_t h = f2bf(v); oH[idx] = h; oL[idx] = f2bf(v - bf2f(h));
        }
        if (EPI == EPI_CUR){
          v += bias[col] + addend[(size_t)row * 1024 + col];
          D0[(size_t)row * 1024 + col] = v;
          size_t idx = (size_t)row * 3072 + col;
          uint16_t h = f2bf(v); oH[idx] = h; oL[idx] = f2bf(v - bf2f(h));
          o8[(size_t)row * 1024 + col] = f2fp8(v);
        }
        if (EPI == EPI_PRE){
          if (col < 2048) D0[(size_t)row * 2048 + col] = v / (1.f + expf(-v));
          else D1[(size_t)row * 128 + col - 2048] = v;
        }
        if (EPI == EPI_QROUTE){
          if (isRoute){
            D3[((size_t)blockIdx.x * N_TOK + row) * 128 + col] = v;
          } else {
            if (col < 1024) D0[(size_t)row * 1024 + col] = v;
            else if (col < 4096) D1[(size_t)row * 3072 + col - 1024] = v + bias[col - 1024];
            else if (col < 4160) D2[(size_t)row * 128 + col - 4096] = v;
          }
        }
      }
    }
  }
}

// ---------------- sparse expert up: fp8, persistent, depth-3, XCD-grouped -------
// 1-D grid of 768: bid = ex*192 + ey  (192 % 8 == 0 => the 4 ex-blocks of one
// tile ey share bid%8 == ey%8 -> same XCD -> one L2 copy of the W tile).
__global__ __launch_bounds__(256)
void expert_up_mfma(const uint8_t* __restrict__ A8, const uint8_t* __restrict__ U8,
                    const int* __restrict__ cnt, const int* __restrict__ gidx,
                    uint16_t* __restrict__ HH)
{
  int bid = blockIdx.x;
  int ex = bid / 192;
  int ey = bid - ex * 192;
  if (ey >= 188) return;
  int e = 0;
#pragma unroll
  for (int i = 1; i < 11; i++) if (ey >= c_cum[i]) e = i;
  int ct = ey - c_cum[e];
  int dcols = c_dims[e];
  int ne = cnt[e];
  const uint8_t* W = U8 + (size_t)e * DMAX * IN_D + (size_t)ct * 128 * IN_D;

  __shared__ __align__(16) uint8_t smem[32768];
  int tid = threadIdx.x, lane = tid & 63, wave = tid >> 6;
  int wr = wave >> 1, wc = wave & 1;
  int arow = lane & 15, agrp = lane >> 4;
  int actid = c_acts[e];
  size_t base_e = (size_t)N_TOK * c_offs[e];
  int rHalf = tid >> 1;
  // both-sides 16B swizzle: source half inverts the read swizzle
  int h16 = (((tid & 1) ^ ((tid >> 3) & 1)) << 4);
  // lane-constant read offset within the 32B row-pair (2-way banks = free)
  int off = ((((agrp >> 1) ^ ((arow >> 2) & 1)) << 4) | ((agrp & 1) << 3));

#define STAGE_E(b, k0) do { \
    gload16b(&A8[(size_t)tok * IN_D + (k0) + h16], &smem[(b)*8192 + tid*16]); \
    gload16b(&W[(size_t)rHalf * IN_D + (k0) + h16], &smem[(b)*8192 + 4096 + tid*16]); \
  } while(0)

#pragma unroll 1
  for (int rowBase = ex * 128; rowBase < ne; rowBase += 4 * 128){
    int slot = rowBase + rHalf;
    int tok = (slot < ne) ? gidx[e * N_TOK + slot] : 0;

    f32x4 acc[4][4];
#pragma unroll
    for (int m = 0; m < 4; m++)
#pragma unroll
      for (int n = 0; n < 4; n++){ f32x4 z = {0.f,0.f,0.f,0.f}; acc[m][n] = z; }

    STAGE_E(0, 0);
    STAGE_E(1, 32);
    STAGE_E(2, 64);
    int cb = 0;
#pragma unroll 1
    for (int ki = 0; ki < 32; ki++){
      if (ki < 30)       asm volatile("s_waitcnt vmcnt(4)" ::: "memory");
      else if (ki == 30) asm volatile("s_waitcnt vmcnt(2)" ::: "memory");
      else               asm volatile("s_waitcnt vmcnt(0)" ::: "memory");
      __builtin_amdgcn_s_barrier();
      long a[4], b[4];
#pragma unroll
      for (int m = 0; m < 4; m++)
        a[m] = *(const long*)&smem[cb*8192 + (wr*64 + m*16 + arow)*32 + off];
#pragma unroll
      for (int n = 0; n < 4; n++)
        b[n] = *(const long*)&smem[cb*8192 + 4096 + (wc*64 + n*16 + arow)*32 + off];
#pragma unroll
      for (int m = 0; m < 4; m++)
#pragma unroll
        for (int n = 0; n < 4; n++)
          acc[m][n] = __builtin_amdgcn_mfma_f32_16x16x32_fp8_fp8(a[m], b[n], acc[m][n], 0, 0, 0);
      __builtin_amdgcn_s_barrier();
      asm volatile("" ::: "memory");
      if (ki + 3 < 32) STAGE_E(cb, (ki + 3) << 5);
      cb = (cb == 2) ? 0 : cb + 1;
    }
    uint16_t* Ht = (uint16_t*)smem;
#pragma unroll
    for (int m = 0; m < 4; m++){
      int rb0 = wr*64 + m*16 + agrp*4;
#pragma unroll
      for (int n = 0; n < 4; n++){
        int col = wc*64 + n*16 + arow;
#pragma unroll
        for (int r2 = 0; r2 < 4; r2++){
          int row = rb0 + r2;
          float v = actf(actid, acc[m][n][r2]);
          Ht[row * 128 + (col ^ ((row & 7) << 3))] = f2bf(v);
        }
      }
    }
    __syncthreads();
#pragma unroll
    for (int i = 0; i < 8; i++){
      int c = tid + i * 256;
      int row = c >> 4, chunk = c & 15;
      int schunk = (chunk & 8) | ((chunk ^ row) & 7);
      int4 val = *(const int4*)&Ht[row * 128 + schunk * 8];
      *(int4*)&HH[base_e + (size_t)(rowBase + row) * dcols
                  + (size_t)ct * 128 + chunk * 8] = val;
    }
    __syncthreads();
  }
#undef STAGE_E
}

// ---------------- ctx_enr: mem softmax, depth attn, mctx/dctx/enriched/LN ------
// sbwT is the transposed ssm_b weight [40][1024] for coalesced lane reads.
__global__ __launch_bounds__(256)
void ctx_enr_kernel(const float* __restrict__ qaux, const float* __restrict__ dqbuf,
                    const float* __restrict__ Ac, const float* __restrict__ W0,
                    const float* __restrict__ W1, const float* __restrict__ W2,
                    const float* __restrict__ mvi,
                    const float* __restrict__ t0, const float* __restrict__ t1,
                    const float* __restrict__ t2, const float* __restrict__ cur,
                    const float* __restrict__ sab, const float* __restrict__ sbwT,
                    const float* __restrict__ sbb, const float* __restrict__ lng,
                    const float* __restrict__ lnbv,
                    float* __restrict__ enr, uint16_t* __restrict__ lnh,
                    uint16_t* __restrict__ lnl, uint16_t* __restrict__ Arh,
                    uint16_t* __restrict__ Arl, int t)
{
  int row = blockIdx.x, tid = threadIdx.x;
  __shared__ float su[24], ss[3], s40[40], red[12], redm[8];
  if (tid < 64){
    float pj = (tid < 24) ? qaux[(size_t)row * 128 + tid] * 0.03125f : -1e30f;
    float mx = wmax(pj);
    float ex = (tid < 24) ? expf(pj - mx) : 0.f;
    float sum = wred(ex);
    float attn = ex / sum;
    if (tid < 24) su[tid] = attn * Ac[row * 24 + tid];
    float w0v = (t > 0 && tid < 24) ? W0[row * 24 + tid] : 0.f;
    float s0 = wred(attn * w0v);
    float w1v = (t > 1 && tid < 24) ? W1[row * 24 + tid] : 0.f;
    float s1 = wred(attn * w1v);
    float w2v = (t > 2 && tid < 24) ? W2[row * 24 + tid] : 0.f;
    float s2 = wred(attn * w2v);
    if (tid == 0){ ss[0] = s0; ss[1] = s1; ss[2] = s2; }
    if (tid < 40) s40[tid] = tanhf(qaux[(size_t)row * 128 + 24 + tid] + sab[tid]);
  }
  size_t tb = (size_t)row * 3072;
  if (t > 0){
    float a0 = 0.f, a1 = 0.f, a2 = 0.f;
#pragma unroll
    for (int j = 0; j < 4; j++){
      int d = tid + j * 256;
      float dq = dqbuf[(size_t)row * 1024 + d];
      a0 = fmaf(dq, t0[tb + d], a0);
      if (t > 1) a1 = fmaf(dq, t1[tb + d], a1);
      if (t > 2) a2 = fmaf(dq, t2[tb + d], a2);
    }
    a0 = wred(a0); a1 = wred(a1); a2 = wred(a2);
    if ((tid & 63) == 0){ int w = tid >> 6; red[w] = a0; red[4+w] = a1; red[8+w] = a2; }
  }
  __syncthreads();
  float e0 = 0.f, e1 = 0.f, e2 = 0.f;
  if (t > 0){
    float A0 = (red[0]+red[1]+red[2]+red[3]) * 0.03125f;
    float A1 = (red[4]+red[5]+red[6]+red[7]) * 0.03125f;
    float A2 = (red[8]+red[9]+red[10]+red[11]) * 0.03125f;
    float dmx = A0;
    if (t > 1) dmx = fmaxf(dmx, A1);
    if (t > 2) dmx = fmaxf(dmx, A2);
    e0 = expf(A0 - dmx);
    e1 = (t > 1) ? expf(A1 - dmx) : 0.f;
    e2 = (t > 2) ? expf(A2 - dmx) : 0.f;
    float dinv = 1.f / (e0 + e1 + e2);
    e0 *= dinv; e1 *= dinv; e2 *= dinv;
  }
  size_t ar = (size_t)row * 3072;
  float ev[4];
  float part = 0.f;
#pragma unroll
  for (int j = 0; j < 4; j++){
    int d = tid + j * 256;
    size_t idx = (size_t)row * IN_D + d;
    float mv = 0.f;
#pragma unroll
    for (int m = 0; m < 24; m++) mv = fmaf(su[m], mvi[m * IN_D + d], mv);
    float dv = 0.f;
    if (t > 0){
      mv = fmaf(ss[0], t0[tb + 2048 + d], mv);
      dv = e0 * t0[tb + 1024 + d];
      if (t > 1){ mv = fmaf(ss[1], t1[tb + 2048 + d], mv); dv = fmaf(e1, t1[tb + 1024 + d], dv); }
      if (t > 2){ mv = fmaf(ss[2], t2[tb + 2048 + d], mv); dv = fmaf(e2, t2[tb + 1024 + d], dv); }
    }
    float sv = sbb[d];
#pragma unroll
    for (int o = 0; o < 40; o++) sv = fmaf(s40[o], sbwT[o * 1024 + d], sv);
    float v = cur[idx] + 0.34f * mv + 0.22f * dv + 0.18f * sv;
    uint16_t mh = f2bf(mv);
    Arh[ar + 1024 + d] = mh; Arl[ar + 1024 + d] = f2bf(mv - bf2f(mh));
    uint16_t dh = f2bf(dv);
    Arh[ar + 2048 + d] = dh; Arl[ar + 2048 + d] = f2bf(dv - bf2f(dh));
    ev[j] = v; part += v;
  }
  part = wred(part);
  if ((tid & 63) == 0) redm[tid >> 6] = part;
  __syncthreads();
  float mean = (redm[0] + redm[1] + redm[2] + redm[3]) * (1.f / 1024.f);
  float vp = 0.f;
#pragma unroll
  for (int j = 0; j < 4; j++){ float dd = ev[j] - mean; vp += dd * dd; }
  vp = wred(vp);
  if ((tid & 63) == 0) redm[4 + (tid >> 6)] = vp;
  __syncthreads();
  float var = (redm[4] + redm[5] + redm[6] + redm[7]) * (1.f / 1024.f);
  float rs = 1.f / sqrtf(var + 1e-5f);
#pragma unroll
  for (int j = 0; j < 4; j++){
    int d = tid + j * 256;
    size_t idx = (size_t)row * IN_D + d;
    enr[idx] = ev[j];
    float v = (ev[j] - mean) * rs * lng[t * IN_D + d] + lnbv[t * IN_D + d];
    uint16_t h = f2bf(v);
    lnh[idx] = h;
    lnl[idx] = f2bf(v - bf2f(h));
  }
}

// ---------------- route_fin: sums 4 K-split partials, softmaxes, top-k ----------
__global__ __launch_bounds__(256)
void route_fin(const float* __restrict__ ROq, const float* __restrict__ mmb,
               const float* __restrict__ msb, const float* __restrict__ ebias,
               const float* __restrict__ bb, const float* __restrict__ wgb,
               const float* __restrict__ hb,
               float* __restrict__ sg, float* __restrict__ haltb,
               float* __restrict__ Ac, float* __restrict__ W0,
               float* __restrict__ W1, float* __restrict__ W2,
               int* __restrict__ cnt, int* __restrict__ gidx,
               int* __restrict__ pos, float* __restrict__ routeS, int t)
{
  int row = blockIdx.x * 256 + threadIdx.x;
  int lane = threadIdx.x & 63;
  const size_t P = (size_t)N_TOK * 128;
  const float* r0 = ROq + (size_t)row * 128;
  const float* r1 = r0 + P;
  const float* r2 = r0 + 2 * P;
  const float* r3 = r0 + 3 * P;
  auto R = [&](int j){ return r0[j] + r1[j] + r2[j] + r3[j]; };
  float pm[4];
#pragma unroll
  for (int o = 0; o < 4; o++) pm[o] = R(40 + o) + mmb[o];
  float mmx = fmaxf(fmaxf(pm[0], pm[1]), fmaxf(pm[2], pm[3]));
  float msum = 0.f;
#pragma unroll
  for (int o = 0; o < 4; o++){ pm[o] = expf(pm[o] - mmx); msum += pm[o]; }
  float minv = 1.f / msum;
  float gl[10];
#pragma unroll
  for (int e = 0; e < 10; e++){
    float g = ebias[e];
#pragma unroll
    for (int s2 = 0; s2 < 4; s2++)
      g = fmaf(pm[s2] * minv, R(s2 * 10 + e) + msb[s2 * 10 + e], g);
    gl[e] = g;
  }
  float gmx = gl[0];
#pragma unroll
  for (int e = 1; e < 10; e++) gmx = fmaxf(gmx, gl[e]);
  float gs = 0.f;
#pragma unroll
  for (int e = 0; e < 10; e++){ gl[e] = expf(gl[e] - gmx); gs += gl[e]; }
  float ginv = 1.f / gs;
#pragma unroll
  for (int e = 0; e < 10; e++) gl[e] *= ginv;
  float pb0 = R(44) + bb[0], pb1 = R(45) + bb[1], pb2 = R(46) + bb[2], pb3 = R(47) + bb[3];
  int bud = 1; float bbest = pb0;
  if (pb1 > bbest){ bbest = pb1; bud = 2; }
  if (pb2 > bbest){ bbest = pb2; bud = 3; }
  if (pb3 > bbest){ bbest = pb3; bud = 4; }
  float tv[4]; int ti[4]; unsigned used = 0;
#pragma unroll
  for (int j = 0; j < 4; j++){
    float best = -1e30f; int bi = 0;
#pragma unroll
    for (int e = 0; e < 10; e++){
      bool ok = (!((used >> e) & 1u)) && (gl[e] > best);
      if (ok){ best = gl[e]; bi = e; }
    }
    tv[j] = best; ti[j] = bi; used |= (1u << bi);
  }
  float ssum = tv[0];
  if (bud > 1) ssum += tv[1];
  if (bud > 2) ssum += tv[2];
  if (bud > 3) ssum += tv[3];
  float den = fmaxf(ssum, 1e-6f);
  float sup = 1.f - tv[0] / den;
  float sgv[10];
#pragma unroll
  for (int e = 0; e < 10; e++){
    float sv = 0.f;
#pragma unroll
    for (int j = 0; j < 4; j++) if (j < bud && ti[j] == e) sv = tv[j] / den;
    sgv[e] = sv;
    sg[row * 10 + e] = sv;
  }
  float pw[24];
#pragma unroll
  for (int m = 0; m < 24; m++) pw[m] = R(48 + m) + wgb[m];
  float wmx2 = pw[0];
#pragma unroll
  for (int m = 1; m < 24; m++) wmx2 = fmaxf(wmx2, pw[m]);
  float wsum = 0.f;
#pragma unroll
  for (int m = 0; m < 24; m++){ pw[m] = expf(pw[m] - wmx2); wsum += pw[m]; }
  float winv = 1.f / wsum;
#pragma unroll
  for (int m = 0; m < 24; m++){
    float c = sup * pw[m] * winv;
    float om = 1.f - c;
    Ac[row * 24 + m] *= om;
    if (t > 0) W0[row * 24 + m] *= om;
    if (t > 1) W1[row * 24 + m] *= om;
    if (t > 2) W2[row * 24 + m] *= om;
    if (t == 0)      W0[row * 24 + m] = c;
    else if (t == 1) W1[row * 24 + m] = c;
    else if (t == 2) W2[row * 24 + m] = c;
  }
  haltb[row] = 1.f / (1.f + expf(-(R(72) + hb[t])));
#pragma unroll
  for (int i = 0; i < 30; i++) routeS[row * 32 + i] = R(73 + i);
#pragma unroll
  for (int e = 0; e < 10; e++){
    bool act = sgv[e] != 0.f;
    unsigned long long mask = __ballot(act);
    int cw = __popcll(mask);
    int b0 = 0;
    if (lane == 0 && cw > 0) b0 = atomicAdd(&cnt[e], cw);
    b0 = __shfl(b0, 0, 64);
    if (act){
      int slot = b0 + __popcll(mask & ((1ull << lane) - 1ull));
      gidx[e * N_TOK + slot] = row;
      pos[row * 10 + e] = slot;
    }
  }
}

// ---------------- downfin: expert down + LN + gated acc + step finalize --------
__global__ __launch_bounds__(256)
void downfin_kernel(const uint16_t* __restrict__ HH, const int* __restrict__ pos,
                    const float* __restrict__ ED, const float* __restrict__ sg,
                    const float* __restrict__ eng, const float* __restrict__ enb,
                    const float* __restrict__ routeS, const float* __restrict__ haltb,
                    float* __restrict__ total, float* __restrict__ cumh)
{
  int lane = threadIdx.x & 63;
  int row = blockIdx.x * 4 + (threadIdx.x >> 6);
  float out[10] = {};
  for (int e = 0; e < NEXP; e++){
    float g = sg[row * 10 + e];
    if (g != 0.0f){
      int d = c_dims[e];
      int slot = pos[row * 10 + e];
      const uint16_t* hr = HH + (size_t)N_TOK * c_offs[e] + (size_t)slot * d;
      const float* wd = ED + (size_t)e * 10 * DMAX;
      float p[10] = {};
      for (int k = lane * 4; k < d; k += 256){
        uint2 hv = *(const uint2*)&hr[k];
        float h0 = bf2f((uint16_t)hv.x), h1 = bf2f((uint16_t)(hv.x >> 16));
        float h2 = bf2f((uint16_t)hv.y), h3 = bf2f((uint16_t)(hv.y >> 16));
#pragma unroll
        for (int o = 0; o < 10; o++){
          float4 w4 = *(const float4*)&wd[o * DMAX + k];
          p[o] = fmaf(h0, w4.x, fmaf(h1, w4.y, fmaf(h2, w4.z, fmaf(h3, w4.w, p[o]))));
        }
      }
#pragma unroll
      for (int o = 0; o < 10; o++) p[o] = wred(p[o]);
      float mean = 0.f;
#pragma unroll
      for (int o = 0; o < 10; o++) mean += p[o];
      mean *= 0.1f;
      float var = 0.f;
#pragma unroll
      for (int o = 0; o < 10; o++){ float dd = p[o] - mean; var += dd * dd; }
      var *= 0.1f;
      float rs = 1.f / sqrtf(var + 1e-5f);
#pragma unroll
      for (int o = 0; o < 10; o++)
        out[o] += g * ((p[o] - mean) * rs * eng[e * 10 + o] + enb[e * 10 + o]);
    }
  }
  if (lane == 0){
    const float* r = routeS + (size_t)row * 32;
    float rem = 1.f - cumh[row];
#pragma unroll
    for (int o = 0; o < 10; o++)
      total[row * 10 + o] += rem * (out[o] + 0.22f * r[o] + 0.14f * r[10 + o]);
    cumh[row] += rem * haltb[row];
  }
}

// ---------------- shared branch --------------------------------------------------
__global__ __launch_bounds__(256)
void shared_kernel(const float* __restrict__ shpre, const float* __restrict__ sdw,
                   const float* __restrict__ g, const float* __restrict__ b,
                   float* __restrict__ outp)
{
  int lane = threadIdx.x & 63;
  int row = blockIdx.x * 4 + (threadIdx.x >> 6);
  const float* xr = shpre + (size_t)row * SHD;
  float p[10];
#pragma unroll
  for (int o = 0; o < 10; o++) p[o] = 0.f;
  for (int k = lane; k < SHD; k += 64){
    float xv = xr[k];
#pragma unroll
    for (int o = 0; o < 10; o++) p[o] = fmaf(xv, sdw[o * SHD + k], p[o]);
  }
#pragma unroll
  for (int o = 0; o < 10; o++) p[o] = wred(p[o]);
  float mean = 0.f;
#pragma unroll
  for (int o = 0; o < 10; o++) mean += p[o];
  mean *= 0.1f;
  float var = 0.f;
#pragma unroll
  for (int o = 0; o < 10; o++){ float dd = p[o] - mean; var += dd * dd; }
  var *= 0.1f;
  float rs = 1.f / sqrtf(var + 1e-5f);
  if (lane == 0){
#pragma unroll
    for (int o = 0; o < 10; o++) outp[row * 10 + o] = (p[o] - mean) * rs * g[o] + b[o];
  }
}

// ---------------- final output (lite) --------------------------------------------
__global__ __launch_bounds__(256)
void final_lite(const float* __restrict__ qaux, const float* __restrict__ biasp,
                const float* __restrict__ sharedp, const float* __restrict__ total,
                const float* __restrict__ routeS, const float* __restrict__ sscale,
                const float* __restrict__ alphap, const float* __restrict__ betap,
                float* __restrict__ outp)
{
  int row = blockIdx.x * 256 + threadIdx.x;
  float ss = sscale[0], av = alphap[0] + 1e-4f, bv = betap[0];
#pragma unroll
  for (int o = 0; o < 10; o++)
    outp[row * 10 + o] = (qaux[(size_t)row * 128 + 64 + o] + biasp[o])
                       + ss * sharedp[row * 10 + o]
                       + av * (total[row * 10 + o] * 0.25f)
                       + bv * routeS[(size_t)row * 32 + 20 + o];
}

// ====================================================================================
extern "C" void kernel_launch(void* const* d_in, const int* in_sizes, int n_in,
                              void* d_out, int out_size, void* d_ws, size_t ws_size,
                              hipStream_t stream)
{
  const float* x     = (const float*)d_in[0];
  const float* wgt   = (const float*)d_in[1];
  const float* bias  = (const float*)d_in[2];
  const float* suw   = (const float*)d_in[3];
  const float* sdw   = (const float*)d_in[4];
  const float* sng   = (const float*)d_in[5];
  const float* snb   = (const float*)d_in[6];
  const float* sscale= (const float*)d_in[7];
  const float* keys  = (const float*)d_in[8];
  const float* mvi   = (const float*)d_in[9];
  const float* mqw   = (const float*)d_in[10];
  const float* mow   = (const float*)d_in[11];
  const float* wgw   = (const float*)d_in[12];
  const float* wgb   = (const float*)d_in[13];
  const float* wvw   = (const float*)d_in[14];
  const float* wvb   = (const float*)d_in[15];
  const float* dqw   = (const float*)d_in[16];
  const float* dkw   = (const float*)d_in[17];
  const float* dvw   = (const float*)d_in[18];
  const float* dow   = (const float*)d_in[19];
  const float* clng  = (const float*)d_in[20];
  const float* clnb  = (const float*)d_in[21];
  const float* fc1w  = (const float*)d_in[22];
  const float* fc1b  = (const float*)d_in[23];
  const float* fc2w  = (const float*)d_in[24];
  const float* fc2b  = (const float*)d_in[25];
  const float* saw   = (const float*)d_in[26];
  const float* sab   = (const float*)d_in[27];
  const float* sbw   = (const float*)d_in[28];
  const float* sbb   = (const float*)d_in[29];
  const float* msw   = (const float*)d_in[30];
  const float* msb   = (const float*)d_in[31];
  const float* mmw   = (const float*)d_in[32];
  const float* mmb   = (const float*)d_in[33];
  const float* ebias = (const float*)d_in[34];
  const float* bw    = (const float*)d_in[35];
  const float* bb    = (const float*)d_in[36];
  const float* eup   = (const float*)d_in[37];
  const float* edn   = (const float*)d_in[38];
  const float* eng   = (const float*)d_in[39];
  const float* enb   = (const float*)d_in[40];
  const float* hw    = (const float*)d_in[41];
  const float* hb    = (const float*)d_in[42];
  const float* alphap= (const float*)d_in[43];
  const float* betap = (const float*)d_in[44];
  float* outp = (float*)d_out;

  char* wsb = (char*)d_ws;
  size_t off = 0;
  auto AL = [&](size_t bytes) -> void* {
    void* p = wsb + off;
    off = (off + bytes + 255) & ~(size_t)255;
    return p;
  };
  const size_t NI = (size_t)N_TOK * IN_D;
  float* cur    = (float*)AL(NI * 4);
  float* enr    = (float*)AL(NI * 4);
  float* dqbuf  = (float*)AL(NI * 4);
  float* qaux   = (float*)AL((size_t)N_TOK * 128 * 4);
  float* routeQ = (float*)AL((size_t)4 * N_TOK * 128 * 4);
  float* routeS = (float*)AL((size_t)N_TOK * 32 * 4);
  float* trio0  = (float*)AL((size_t)N_TOK * 3072 * 4);
  float* trio1  = (float*)AL((size_t)N_TOK * 3072 * 4);
  float* trio2  = (float*)AL((size_t)N_TOK * 3072 * 4);
  float* Ac     = (float*)AL((size_t)N_TOK * 24 * 4);
  float* W0     = (float*)AL((size_t)N_TOK * 24 * 4);
  float* W1     = (float*)AL((size_t)N_TOK * 24 * 4);
  float* W2     = (float*)AL((size_t)N_TOK * 24 * 4);
  float* sg     = (float*)AL((size_t)N_TOK * 10 * 4);
  float* haltb  = (float*)AL((size_t)N_TOK * 4);
  char*  zblk   = (char*)AL((size_t)N_TOK * 10 * 4 + N_TOK * 4 + 4 * 16 * 4);
  float* total  = (float*)zblk;
  float* cumh   = (float*)(zblk + (size_t)N_TOK * 10 * 4);
  int*   cnt    = (int*)(zblk + (size_t)N_TOK * 10 * 4 + N_TOK * 4);
  int*   gidx   = (int*)AL((size_t)NEXP * N_TOK * 4);
  int*   pos    = (int*)AL((size_t)N_TOK * NEXP * 4);
  float* sharedp= (float*)AL((size_t)N_TOK * 10 * 4);
  float* cbias  = (float*)AL(3072 * 4);
  float* K2f    = (float*)AL((size_t)24 * 1024 * 4);
  float* sbwT   = (float*)AL((size_t)40 * 1024 * 4);
  uint16_t* lnh  = (uint16_t*)AL(NI * 2);
  uint16_t* lnl  = (uint16_t*)AL(NI * 2);
  uint16_t* h7h  = (uint16_t*)AL((size_t)N_TOK * INNER * 2);
  uint16_t* h7l  = (uint16_t*)AL((size_t)N_TOK * INNER * 2);
  uint16_t* Arh  = (uint16_t*)AL((size_t)N_TOK * 3072 * 2);
  uint16_t* Arl  = (uint16_t*)AL((size_t)N_TOK * 3072 * 2);
  const size_t W1M = (size_t)IN_D * IN_D;
  uint16_t* preWh  = (uint16_t*)AL((size_t)2176 * 1024 * 2);
  uint16_t* preWl  = (uint16_t*)AL((size_t)2176 * 1024 * 2);
  uint16_t* qtWh   = (uint16_t*)AL((size_t)4224 * 1024 * 2);
  uint16_t* qtWl   = (uint16_t*)AL((size_t)4224 * 1024 * 2);
  uint16_t* rtWh   = (uint16_t*)AL((size_t)4 * 128 * 3072 * 2);
  uint16_t* rtWl   = (uint16_t*)AL((size_t)4 * 128 * 3072 * 2);
  const size_t WFC = (size_t)NSTEP * INNER * IN_D;
  uint16_t* fc1wh = (uint16_t*)AL(WFC * 2); uint16_t* fc1wl = (uint16_t*)AL(WFC * 2);
  uint16_t* fc2wh = (uint16_t*)AL(WFC * 2); uint16_t* fc2wl = (uint16_t*)AL(WFC * 2);
  uint8_t* upbf8 = (uint8_t*)AL((size_t)NEXP * DMAX * IN_D);
  uint8_t* A8    = (uint8_t*)AL(NI);
  uint16_t* HHc  = (uint16_t*)AL((size_t)N_TOK * DSUM * 2);
  float* shpre  = (float*)HHc;   // alias: consumed before HHc is written

  // ---- init ----
  hipMemsetAsync(zblk, 0, (size_t)N_TOK * 10 * 4 + N_TOK * 4 + 4 * 16 * 4, stream);
  hipMemsetAsync(cbias, 0, 3072 * 4, stream);
  hipMemcpyAsync(cbias + 2048, wvb, 1024 * 4, hipMemcpyDeviceToDevice, stream);
  hipMemcpyAsync(cur, x, NI * 4, hipMemcpyDeviceToDevice, stream);
  fill1_kernel<<<(N_TOK * 24 + 255) / 256, 256, 0, stream>>>(Ac, N_TOK * 24);
  cvt_fp8_kernel<<<2048, 256, 0, stream>>>(eup, upbf8, (size_t)NEXP * DMAX * IN_D);
  tr_sbw_kernel<<<160, 256, 0, stream>>>(sbw, sbwT);

  split_strided<<<1024, 256, 0, stream>>>(x, Arh, Arl, N_TOK, 1024, 3072);
  split_kernel<<<1024, 256, 0, stream>>>(suw, preWh, preWl, (size_t)SHD * 1024);
  split_kernel<<<256, 256, 0, stream>>>(saw, preWh + (size_t)2072*1024, preWl + (size_t)2072*1024, (size_t)40 * 1024);
  split_kernel<<<256, 256, 0, stream>>>(wgt, preWh + (size_t)2112*1024, preWl + (size_t)2112*1024, (size_t)10 * 1024);
  hipMemsetAsync(preWh + (size_t)2122*1024, 0, (size_t)54 * 1024 * 2, stream);
  hipMemsetAsync(preWl + (size_t)2122*1024, 0, (size_t)54 * 1024 * 2, stream);
  split_kernel<<<1024, 256, 0, stream>>>(dqw, qtWh, qtWl, W1M);
  split_kernel<<<1024, 256, 0, stream>>>(dkw, qtWh + W1M, qtWl + W1M, W1M);
  split_kernel<<<1024, 256, 0, stream>>>(dvw, qtWh + 2*W1M, qtWl + 2*W1M, W1M);
  split_kernel<<<1024, 256, 0, stream>>>(wvw, qtWh + 3*W1M, qtWl + 3*W1M, W1M);
  split_kernel<<<256, 256, 0, stream>>>(saw, qtWh + (size_t)4120*1024, qtWl + (size_t)4120*1024, (size_t)40 * 1024);
  hipMemsetAsync(qtWh + (size_t)4160*1024, 0, (size_t)64 * 1024 * 2, stream);
  hipMemsetAsync(qtWl + (size_t)4160*1024, 0, (size_t)64 * 1024 * 2, stream);
  k2_kernel<<<dim3(24, 4), 256, 0, stream>>>(keys, mqw, K2f);
  split_kernel<<<256, 256, 0, stream>>>(K2f, preWh + (size_t)2048*1024, preWl + (size_t)2048*1024, (size_t)24 * 1024);
  split_kernel<<<256, 256, 0, stream>>>(K2f, qtWh + (size_t)4096*1024, qtWl + (size_t)4096*1024, (size_t)24 * 1024);
  build_routew<<<2048, 256, 0, stream>>>(msw, mmw, bw, wgw, hw, mow, dow, rtWh, rtWl);
  split_kernel<<<1024, 256, 0, stream>>>(fc1w, fc1wh, fc1wl, WFC);
  split_kernel<<<1024, 256, 0, stream>>>(fc2w, fc2wh, fc2wl, WFC);

  gemm_sp<EPI_PRE><<<dim3(17, 16), 256, 0, stream>>>(
      Arh, Arl, 3072, preWh, preWl, nullptr, nullptr, nullptr, nullptr,
      shpre, qaux, nullptr, nullptr, nullptr, nullptr, nullptr, IN_D, 2176);
  shared_kernel<<<512, 256, 0, stream>>>(shpre, sdw, sng, snb, sharedp);

  float* trioB[3] = {trio0, trio1, trio2};

  for (int t = 0; t < NSTEP; t++){
    ctx_enr_kernel<<<2048, 256, 0, stream>>>(qaux, dqbuf, Ac, W0, W1, W2, mvi,
                                             trio0, trio1, trio2, cur, sab, sbwT, sbb,
                                             clng, clnb, enr, lnh, lnl, Arh, Arl, t);
    gemm_sp<EPI_GELU><<<dim3(INNER/128, 16), 256, 0, stream>>>(
        lnh, lnl, 1024, fc1wh + (size_t)t * INNER * IN_D, fc1wl + (size_t)t * INNER * IN_D,
        nullptr, nullptr, fc1b + t * INNER, nullptr,
        nullptr, nullptr, nullptr, nullptr, nullptr, h7h, h7l, IN_D, INNER);
    gemm_sp<EPI_CUR><<<dim3(8, 16), 256, 0, stream>>>(
        h7h, h7l, 768, fc2wh + (size_t)t * IN_D * INNER, fc2wl + (size_t)t * IN_D * INNER,
        nullptr, nullptr, fc2b + t * IN_D, enr,
        cur, nullptr, nullptr, nullptr, A8, Arh, Arl, INNER, IN_D);
    gemm_sp<EPI_QROUTE><<<dim3(t < 3 ? 37 : 4, 16), 256, 0, stream>>>(
        Arh, Arl, 3072, qtWh, qtWl,
        rtWh + (size_t)t * 128 * 3072, rtWl + (size_t)t * 128 * 3072,
        cbias, nullptr, dqbuf, t < 3 ? trioB[t] : nullptr, qaux, routeQ,
        nullptr, nullptr, nullptr, IN_D, 4224);
    route_fin<<<8, 256, 0, stream>>>(routeQ, mmb, msb, ebias, bb, wgb, hb,
                                     sg, haltb, Ac, W0, W1, W2,
                                     cnt + t * 16, gidx, pos, routeS, t);
    expert_up_mfma<<<768, 256, 0, stream>>>(A8, upbf8, cnt + t * 16, gidx, HHc);
    downfin_kernel<<<512, 256, 0, stream>>>(HHc, pos, edn, sg, eng, enb,
                                            routeS, haltb, total, cumh);
  }
  final_lite<<<8, 256, 0, stream>>>(qaux, bias, sharedp, total, routeS,
                                    sscale, alphap, betap, outp);
}

// Round 17
// 1783.019 us; speedup vs baseline: 1.3024x; 1.1644x over previous
//
#include <hip/hip_runtime.h>
#include <stdint.h>

#define N_TOK 2048
#define IN_D  1024
#define NEXP  10
#define NSTEP 4
#define INNER 768
#define SHD   2048
#define DMAX  3328
#define DSUM  24064

typedef __attribute__((ext_vector_type(4))) float f32x4;
typedef __attribute__((ext_vector_type(8))) short bf16x8;

__device__ const int c_dims[10] = {1536,2048,2560,3072,1792,2304,2816,2048,2560,3328};
__device__ const int c_offs[10] = {0,1536,3584,6144,9216,11008,13312,16128,18176,20736};
__device__ const int c_acts[10] = {0,1,2,3,4,5,6,7,0,1};
__device__ const int c_cum[11]  = {0,12,28,48,72,86,104,126,142,162,188};

__device__ __forceinline__ float wred(float v){
#pragma unroll
  for (int s = 32; s > 0; s >>= 1) v += __shfl_xor(v, s, 64);
  return v;
}
__device__ __forceinline__ float wmax(float v){
#pragma unroll
  for (int s = 32; s > 0; s >>= 1) v = fmaxf(v, __shfl_xor(v, s, 64));
  return v;
}
__device__ __forceinline__ float bf2f(uint16_t u){
  return __uint_as_float(((uint32_t)u) << 16);
}
__device__ __forceinline__ uint16_t f2bf(float f){
  uint32_t u = __float_as_uint(f);
  return (uint16_t)((u + 0x7FFFu + ((u >> 16) & 1u)) >> 16);
}
// float -> OCP e4m3 (RNE, saturate-finite)
__device__ __forceinline__ uint8_t f2fp8(float f){
  uint32_t u = __float_as_uint(f);
  uint8_t sign = (uint8_t)((u >> 24) & 0x80u);
  uint32_t absu = u & 0x7FFFFFFFu;
  if (absu >= 0x43E00000u) return sign | 0x7Eu;
  if (absu < 0x3C800000u){
    float af = __uint_as_float(absu);
    int q = (int)rintf(af * 512.0f);
    return sign | (uint8_t)q;
  }
  uint32_t mant = absu & 0x7FFFFFu;
  uint32_t exp = absu >> 23;
  uint32_t lsb = (mant >> 20) & 1u;
  uint32_t rounded = mant + 0x7FFFFu + lsb;
  if (rounded >= 0x800000u){ exp += 1; rounded = 0; }
  uint32_t e8 = exp - 120;
  uint32_t m8 = (rounded >> 20) & 7u;
  if (e8 > 15u || (e8 == 15u && m8 == 7u)) return sign | 0x7Eu;
  return sign | (uint8_t)((e8 << 3) | m8);
}
__device__ __forceinline__ void gload16(const uint16_t* g, uint16_t* l){
  __builtin_amdgcn_global_load_lds(
      (const __attribute__((address_space(1))) uint32_t*)(const void*)g,
      (__attribute__((address_space(3))) uint32_t*)(void*)l, 16, 0, 0);
}
__device__ __forceinline__ void gload16b(const void* g, void* l){
  __builtin_amdgcn_global_load_lds(
      (const __attribute__((address_space(1))) uint32_t*)g,
      (__attribute__((address_space(3))) uint32_t*)l, 16, 0, 0);
}

__device__ __forceinline__ float actf(int a, float x){
  switch(a){
    case 0: return x / (1.f + expf(-x));
    case 1: return 0.5f * x * (1.f + erff(x * 0.7071067811865475f));
    case 2: { float sp = fmaxf(x,0.f) + log1pf(expf(-fabsf(x)));
              return x * tanhf(sp); }
    case 3: return fmaxf(x, 0.f);
    case 4: return x > 0.f ? 1.0507009873554805f * x
                           : 1.7580993408473768f * expm1f(x);
    case 5: return tanhf(x);
    case 6: return fmaxf(x,0.f) + log1pf(expf(-fabsf(x)));
    default: return x > 0.f ? x : expm1f(x);
  }
}

// ---------------- f32 -> (hi, lo) bf16 split ------------------------------------
__global__ void split_kernel(const float* __restrict__ src, uint16_t* __restrict__ hi,
                             uint16_t* __restrict__ lo, size_t n){
  size_t i = ((size_t)blockIdx.x * blockDim.x + threadIdx.x) << 2;
  size_t stride = ((size_t)gridDim.x * blockDim.x) << 2;
  for (; i < n; i += stride){
    float4 v = *(const float4*)(src + i);
    ushort4 h, l;
    h.x = f2bf(v.x); l.x = f2bf(v.x - bf2f(h.x));
    h.y = f2bf(v.y); l.y = f2bf(v.y - bf2f(h.y));
    h.z = f2bf(v.z); l.z = f2bf(v.z - bf2f(h.z));
    h.w = f2bf(v.w); l.w = f2bf(v.w - bf2f(h.w));
    *(ushort4*)(hi + i) = h;
    *(ushort4*)(lo + i) = l;
  }
}
__global__ void split_strided(const float* __restrict__ src, uint16_t* __restrict__ hi,
                              uint16_t* __restrict__ lo, int rows, int cols, int ldd){
  int nq = rows * (cols >> 2);
  for (int i = blockIdx.x * blockDim.x + threadIdx.x; i < nq; i += gridDim.x * blockDim.x){
    int r = i / (cols >> 2), c4 = (i - r * (cols >> 2)) << 2;
    float4 v = *(const float4*)(src + (size_t)r * cols + c4);
    ushort4 h, l;
    h.x = f2bf(v.x); l.x = f2bf(v.x - bf2f(h.x));
    h.y = f2bf(v.y); l.y = f2bf(v.y - bf2f(h.y));
    h.z = f2bf(v.z); l.z = f2bf(v.z - bf2f(h.z));
    h.w = f2bf(v.w); l.w = f2bf(v.w - bf2f(h.w));
    size_t d = (size_t)r * ldd + c4;
    *(ushort4*)(hi + d) = h;
    *(ushort4*)(lo + d) = l;
  }
}
__global__ void cvt_fp8_kernel(const float* __restrict__ src, uint8_t* __restrict__ dst, size_t n){
  size_t i = ((size_t)blockIdx.x * blockDim.x + threadIdx.x) << 2;
  size_t stride = ((size_t)gridDim.x * blockDim.x) << 2;
  for (; i < n; i += stride){
    float4 v = *(const float4*)(src + i);
    uchar4 q;
    q.x = f2fp8(v.x); q.y = f2fp8(v.y); q.z = f2fp8(v.z); q.w = f2fp8(v.w);
    *(uchar4*)(dst + i) = q;
  }
}
__global__ void fill1_kernel(float* __restrict__ p, int n){
  int i = blockIdx.x * blockDim.x + threadIdx.x;
  if (i < n) p[i] = 1.f;
}
// sbw [1024][40] -> sbwT [40][1024]
__global__ void tr_sbw_kernel(const float* __restrict__ src, float* __restrict__ dst){
  int i = blockIdx.x * 256 + threadIdx.x;
  if (i < 40 * 1024){
    int o = i >> 10, d = i & 1023;
    dst[i] = src[d * 40 + o];
  }
}

// ---------------- K2 = keys @ mqw  [24,1024] ------------------------------------
__global__ __launch_bounds__(256)
void k2_kernel(const float* __restrict__ keys, const float* __restrict__ mqw,
               float* __restrict__ K2){
  int m = blockIdx.x;
  int j = blockIdx.y * 256 + threadIdx.x;
  float acc = 0.f;
  for (int d = 0; d < 1024; d++)
    acc = fmaf(keys[m * 1024 + d], mqw[d * 1024 + j], acc);
  K2[m * 1024 + j] = acc;
}

// ---------------- route weight builder: 4 x [128 rows x 3072] -------------------
__global__ void build_routew(const float* __restrict__ msw, const float* __restrict__ mmw,
                             const float* __restrict__ bw, const float* __restrict__ wgw,
                             const float* __restrict__ hw, const float* __restrict__ mow,
                             const float* __restrict__ dow, uint16_t* __restrict__ Wh,
                             uint16_t* __restrict__ Wl){
  const int TOT = 4 * 128 * 3072;
  for (int i = blockIdx.x * 256 + threadIdx.x; i < TOT; i += gridDim.x * 256){
    int t = i / (128 * 3072);
    int rem = i - t * (128 * 3072);
    int row = rem / 3072, col = rem - row * 3072;
    float v = 0.f;
    if (row < 40){ if (col < 1024) v = msw[row * 1024 + col]; }
    else if (row < 44){ if (col < 1024) v = mmw[(row - 40) * 1024 + col]; }
    else if (row < 48){ if (col < 1024) v = bw[(row - 44) * 1024 + col]; }
    else if (row < 72){ if (col < 2048) v = wgw[(row - 48) * 2048 + col]; }
    else if (row == 72){
      if (col < 1024) v = hw[t * 1024 + col];
      else if (col < 2048) v = 0.2f * hw[t * 1024 + col - 1024];
      else v = 0.1f * hw[t * 1024 + col - 2048];
    }
    else if (row < 83){ if (col >= 1024 && col < 2048) v = mow[(row - 73) * 1024 + col - 1024]; }
    else if (row < 93){ if (col >= 2048) v = dow[(row - 83) * 1024 + col - 2048]; }
    else if (row < 103){ if (col < 1024) v = mow[(row - 93) * 1024 + col]; }
    uint16_t h = f2bf(v);
    Wh[i] = h; Wl[i] = f2bf(v - bf2f(h));
  }
}

// ---------------- split-bf16 MFMA GEMM, counted-vmcnt 2-deep pipeline -----------
enum { EPI_GELU=0, EPI_CUR=1, EPI_PRE=2, EPI_QROUTE=3 };

template<int EPI>
__global__ __launch_bounds__(256)
void gemm_sp(const uint16_t* __restrict__ Ah, const uint16_t* __restrict__ Al, int lda,
             const uint16_t* __restrict__ Wh, const uint16_t* __restrict__ Wl,
             const uint16_t* __restrict__ W2h, const uint16_t* __restrict__ W2l,
             const float* __restrict__ bias, const float* __restrict__ addend,
             float* __restrict__ D0, float* __restrict__ D1, float* __restrict__ D2,
             float* __restrict__ D3, uint8_t* __restrict__ o8,
             uint16_t* __restrict__ oH, uint16_t* __restrict__ oL,
             int K, int D)
{
  __shared__ __align__(16) uint16_t sm[4][2][4096];
  int tid = threadIdx.x, lane = tid & 63, wave = tid >> 6;
  int wr = wave >> 1, wc = wave & 1;
  int arow = lane & 15, agrp = lane >> 4;
  int rowBase = blockIdx.y * 128;
  bool isRoute = (EPI == EPI_QROUTE) && ((int)blockIdx.x < 4);
  const uint16_t* Wsh = isRoute ? W2h : Wh;
  const uint16_t* Wsl = isRoute ? W2l : Wl;
  int wst     = isRoute ? 3072 : K;
  int colBase = isRoute ? 0 : ((EPI == EPI_QROUTE ? (int)blockIdx.x - 4 : (int)blockIdx.x) * 128);
  int kBase   = isRoute ? (int)blockIdx.x * 768 : 0;
  int kLen    = isRoute ? 768 : K;
  f32x4 acc[4][4];
#pragma unroll
  for (int m = 0; m < 4; m++)
#pragma unroll
    for (int n = 0; n < 4; n++){ f32x4 z = {0.f,0.f,0.f,0.f}; acc[m][n] = z; }

#define STAGE_G(buf, k0) do { \
  _Pragma("unroll") \
  for (int s = 0; s < 2; s++){ \
    int u = tid + s * 256; \
    int rr = u >> 2; \
    int ch = (u & 3) ^ ((rr >> 1) & 3); \
    size_t ga = (size_t)(rowBase + rr) * lda + kBase + (k0) + ch * 8; \
    size_t gw = (size_t)(colBase + rr) * wst + kBase + (k0) + ch * 8; \
    gload16(&Ah[ga], &sm[0][buf][u << 3]); \
    gload16(&Al[ga], &sm[1][buf][u << 3]); \
    gload16(&Wsh[gw], &sm[2][buf][u << 3]); \
    gload16(&Wsl[gw], &sm[3][buf][u << 3]); \
  } } while(0)

  int nk = kLen >> 5;
  STAGE_G(0, 0);
  if (nk > 1) STAGE_G(1, 32);
  int perm = (arow >> 1) & 3;
#pragma unroll 1
  for (int ki = 0; ki < nk; ki++){
    int cb = ki & 1;
    if (ki + 1 < nk) asm volatile("s_waitcnt vmcnt(8)" ::: "memory");
    else             asm volatile("s_waitcnt vmcnt(0)" ::: "memory");
    __builtin_amdgcn_s_barrier();
    bf16x8 ah[4], al[4], bh[4], bl[4];
#pragma unroll
    for (int m = 0; m < 4; m++){
      int u = ((wr*64 + m*16 + arow) << 2) + (agrp ^ perm);
      ah[m] = *(const bf16x8*)&sm[0][cb][u << 3];
      al[m] = *(const bf16x8*)&sm[1][cb][u << 3];
    }
#pragma unroll
    for (int n = 0; n < 4; n++){
      int u = ((wc*64 + n*16 + arow) << 2) + (agrp ^ perm);
      bh[n] = *(const bf16x8*)&sm[2][cb][u << 3];
      bl[n] = *(const bf16x8*)&sm[3][cb][u << 3];
    }
#pragma unroll
    for (int m = 0; m < 4; m++)
#pragma unroll
      for (int n = 0; n < 4; n++){
        acc[m][n] = __builtin_amdgcn_mfma_f32_16x16x32_bf16(ah[m], bh[n], acc[m][n], 0, 0, 0);
        acc[m][n] = __builtin_amdgcn_mfma_f32_16x16x32_bf16(ah[m], bl[n], acc[m][n], 0, 0, 0);
        acc[m][n] = __builtin_amdgcn_mfma_f32_16x16x32_bf16(al[m], bh[n], acc[m][n], 0, 0, 0);
      }
    __builtin_amdgcn_s_barrier();
    asm volatile("" ::: "memory");
    if (ki + 2 < nk) STAGE_G(cb, (ki + 2) << 5);
  }
#undef STAGE_G
#pragma unroll
  for (int m = 0; m < 4; m++){
#pragma unroll
    for (int n = 0; n < 4; n++){
      int col = colBase + wc*64 + n*16 + arow;
#pragma unroll
      for (int r2 = 0; r2 < 4; r2++){
        int row = rowBase + wr*64 + m*16 + agrp*4 + r2;
        float v = acc[m][n][r2];
        if (EPI == EPI_GELU){
          v += bias[col];
          v = 0.5f * v * (1.f + erff(v * 0.7071067811865475f));
          size_t idx = (size_t)row * D + col;
          uint16_t h = f2bf(v); oH[idx] = h; oL[idx] = f2bf(v - bf2f(h));
        }
        if (EPI == EPI_CUR){
          v += bias[col] + addend[(size_t)row * 1024 + col];
          D0[(size_t)row * 1024 + col] = v;
          size_t idx = (size_t)row * 3072 + col;
          uint16_t h = f2bf(v); oH[idx] = h; oL[idx] = f2bf(v - bf2f(h));
          o8[(size_t)row * 1024 + col] = f2fp8(v);
        }
        if (EPI == EPI_PRE){
          if (col < 2048) D0[(size_t)row * 2048 + col] = v / (1.f + expf(-v));
          else D1[(size_t)row * 128 + col - 2048] = v;
        }
        if (EPI == EPI_QROUTE){
          if (isRoute){
            D3[((size_t)blockIdx.x * N_TOK + row) * 128 + col] = v;
          } else {
            if (col < 1024) D0[(size_t)row * 1024 + col] = v;
            else if (col < 4096) D1[(size_t)row * 3072 + col - 1024] = v + bias[col - 1024];
            else if (col < 4160) D2[(size_t)row * 128 + col - 4096] = v;
          }
        }
      }
    }
  }
}

// ---------------- sparse expert up: fp8, persistent, depth-3, XCD-grouped -------
__global__ __launch_bounds__(256)
void expert_up_mfma(const uint8_t* __restrict__ A8, const uint8_t* __restrict__ U8,
                    const int* __restrict__ cnt, const int* __restrict__ gidx,
                    uint16_t* __restrict__ HH)
{
  int bid = blockIdx.x;
  int ex = bid / 192;
  int ey = bid - ex * 192;
  if (ey >= 188) return;
  int e = 0;
#pragma unroll
  for (int i = 1; i < 11; i++) if (ey >= c_cum[i]) e = i;
  int ct = ey - c_cum[e];
  int dcols = c_dims[e];
  int ne = cnt[e];
  const uint8_t* W = U8 + (size_t)e * DMAX * IN_D + (size_t)ct * 128 * IN_D;

  __shared__ __align__(16) uint8_t smem[32768];
  int tid = threadIdx.x, lane = tid & 63, wave = tid >> 6;
  int wr = wave >> 1, wc = wave & 1;
  int arow = lane & 15, agrp = lane >> 4;
  int actid = c_acts[e];
  size_t base_e = (size_t)N_TOK * c_offs[e];
  int rHalf = tid >> 1;
  int h16 = (((tid & 1) ^ ((tid >> 3) & 1)) << 4);
  int off = ((((agrp >> 1) ^ ((arow >> 2) & 1)) << 4) | ((agrp & 1) << 3));

#define STAGE_E(b, k0) do { \
    gload16b(&A8[(size_t)tok * IN_D + (k0) + h16], &smem[(b)*8192 + tid*16]); \
    gload16b(&W[(size_t)rHalf * IN_D + (k0) + h16], &smem[(b)*8192 + 4096 + tid*16]); \
  } while(0)

#pragma unroll 1
  for (int rowBase = ex * 128; rowBase < ne; rowBase += 4 * 128){
    int slot = rowBase + rHalf;
    int tok = (slot < ne) ? gidx[e * N_TOK + slot] : 0;

    f32x4 acc[4][4];
#pragma unroll
    for (int m = 0; m < 4; m++)
#pragma unroll
      for (int n = 0; n < 4; n++){ f32x4 z = {0.f,0.f,0.f,0.f}; acc[m][n] = z; }

    STAGE_E(0, 0);
    STAGE_E(1, 32);
    STAGE_E(2, 64);
    int cb = 0;
#pragma unroll 1
    for (int ki = 0; ki < 32; ki++){
      if (ki < 30)       asm volatile("s_waitcnt vmcnt(4)" ::: "memory");
      else if (ki == 30) asm volatile("s_waitcnt vmcnt(2)" ::: "memory");
      else               asm volatile("s_waitcnt vmcnt(0)" ::: "memory");
      __builtin_amdgcn_s_barrier();
      long a[4], b[4];
#pragma unroll
      for (int m = 0; m < 4; m++)
        a[m] = *(const long*)&smem[cb*8192 + (wr*64 + m*16 + arow)*32 + off];
#pragma unroll
      for (int n = 0; n < 4; n++)
        b[n] = *(const long*)&smem[cb*8192 + 4096 + (wc*64 + n*16 + arow)*32 + off];
#pragma unroll
      for (int m = 0; m < 4; m++)
#pragma unroll
        for (int n = 0; n < 4; n++)
          acc[m][n] = __builtin_amdgcn_mfma_f32_16x16x32_fp8_fp8(a[m], b[n], acc[m][n], 0, 0, 0);
      __builtin_amdgcn_s_barrier();
      asm volatile("" ::: "memory");
      if (ki + 3 < 32) STAGE_E(cb, (ki + 3) << 5);
      cb = (cb == 2) ? 0 : cb + 1;
    }
    uint16_t* Ht = (uint16_t*)smem;
#pragma unroll
    for (int m = 0; m < 4; m++){
      int rb0 = wr*64 + m*16 + agrp*4;
#pragma unroll
      for (int n = 0; n < 4; n++){
        int col = wc*64 + n*16 + arow;
#pragma unroll
        for (int r2 = 0; r2 < 4; r2++){
          int row = rb0 + r2;
          float v = actf(actid, acc[m][n][r2]);
          Ht[row * 128 + (col ^ ((row & 7) << 3))] = f2bf(v);
        }
      }
    }
    __syncthreads();
#pragma unroll
    for (int i = 0; i < 8; i++){
      int c = tid + i * 256;
      int row = c >> 4, chunk = c & 15;
      int schunk = (chunk & 8) | ((chunk ^ row) & 7);
      int4 val = *(const int4*)&Ht[row * 128 + schunk * 8];
      *(int4*)&HH[base_e + (size_t)(rowBase + row) * dcols
                  + (size_t)ct * 128 + chunk * 8] = val;
    }
    __syncthreads();
  }
#undef STAGE_E
}

// ---------------- ctx_enr: 4 rows/block; mvi & sbwT loads amortized over rows ---
__global__ __launch_bounds__(256)
void ctx_enr_kernel(const float* __restrict__ qaux, const float* __restrict__ dqbuf,
                    const float* __restrict__ Ac, const float* __restrict__ W0,
                    const float* __restrict__ W1, const float* __restrict__ W2,
                    const float* __restrict__ mvi,
                    const float* __restrict__ t0, const float* __restrict__ t1,
                    const float* __restrict__ t2, const float* __restrict__ cur,
                    const float* __restrict__ sab, const float* __restrict__ sbwT,
                    const float* __restrict__ sbb, const float* __restrict__ lng,
                    const float* __restrict__ lnbv,
                    float* __restrict__ enr, uint16_t* __restrict__ lnh,
                    uint16_t* __restrict__ lnl, uint16_t* __restrict__ Arh,
                    uint16_t* __restrict__ Arl, int t)
{
  int row0 = blockIdx.x * 4;
  int tid = threadIdx.x, lane = tid & 63, wave = tid >> 6;
  int roww = row0 + wave;                        // row owned by this wave (A/B)
  __shared__ float su[4][24], ss[4][3], de[4][3], s40[4][40], redm[4][8];
  __shared__ float sev[4][1024];
  // phase A: per-wave mem softmax + s40
  {
    float pj = (lane < 24) ? qaux[(size_t)roww * 128 + lane] * 0.03125f : -1e30f;
    float mx = wmax(pj);
    float ex = (lane < 24) ? expf(pj - mx) : 0.f;
    float sum = wred(ex);
    float attn = ex / sum;
    if (lane < 24) su[wave][lane] = attn * Ac[roww * 24 + lane];
    float w0v = (t > 0 && lane < 24) ? W0[roww * 24 + lane] : 0.f;
    float s0 = wred(attn * w0v);
    float w1v = (t > 1 && lane < 24) ? W1[roww * 24 + lane] : 0.f;
    float s1 = wred(attn * w1v);
    float w2v = (t > 2 && lane < 24) ? W2[roww * 24 + lane] : 0.f;
    float s2 = wred(attn * w2v);
    if (lane == 0){ ss[wave][0] = s0; ss[wave][1] = s1; ss[wave][2] = s2; }
    if (lane < 40) s40[wave][lane] = tanhf(qaux[(size_t)roww * 128 + 24 + lane] + sab[lane]);
  }
  // phase B: per-wave depth softmax
  if (t > 0){
    size_t tbw = (size_t)roww * 3072;
    float a0 = 0.f, a1 = 0.f, a2 = 0.f;
    for (int d = lane; d < 1024; d += 64){
      float dq = dqbuf[(size_t)roww * 1024 + d];
      a0 = fmaf(dq, t0[tbw + d], a0);
      if (t > 1) a1 = fmaf(dq, t1[tbw + d], a1);
      if (t > 2) a2 = fmaf(dq, t2[tbw + d], a2);
    }
    a0 = wred(a0) * 0.03125f; a1 = wred(a1) * 0.03125f; a2 = wred(a2) * 0.03125f;
    float dmx = a0;
    if (t > 1) dmx = fmaxf(dmx, a1);
    if (t > 2) dmx = fmaxf(dmx, a2);
    float e0 = expf(a0 - dmx);
    float e1 = (t > 1) ? expf(a1 - dmx) : 0.f;
    float e2 = (t > 2) ? expf(a2 - dmx) : 0.f;
    float dinv = 1.f / (e0 + e1 + e2);
    if (lane == 0){ de[wave][0] = e0 * dinv; de[wave][1] = e1 * dinv; de[wave][2] = e2 * dinv; }
  } else if (lane == 0){ de[wave][0] = 0.f; de[wave][1] = 0.f; de[wave][2] = 0.f; }
  __syncthreads();
  // main pass: mvi/sbwT loads shared across the 4 rows
  float part0 = 0.f, part1 = 0.f, part2 = 0.f, part3 = 0.f;
#pragma unroll 1
  for (int j = 0; j < 4; j++){
    int d = tid + j * 256;
    float mv[4] = {0.f,0.f,0.f,0.f};
    float sv[4] = {0.f,0.f,0.f,0.f};
#pragma unroll 8
    for (int m = 0; m < 24; m++){
      float w = mvi[m * 1024 + d];
#pragma unroll
      for (int r = 0; r < 4; r++) mv[r] = fmaf(su[r][m], w, mv[r]);
    }
#pragma unroll 8
    for (int o = 0; o < 40; o++){
      float w = sbwT[o * 1024 + d];
#pragma unroll
      for (int r = 0; r < 4; r++) sv[r] = fmaf(s40[r][o], w, sv[r]);
    }
    float sbbv = sbb[d];
#pragma unroll
    for (int r = 0; r < 4; r++){
      int row = row0 + r;
      size_t tb = (size_t)row * 3072;
      float mvr = mv[r], dvr = 0.f;
      if (t > 0){
        mvr = fmaf(ss[r][0], t0[tb + 2048 + d], mvr);
        dvr = de[r][0] * t0[tb + 1024 + d];
        if (t > 1){ mvr = fmaf(ss[r][1], t1[tb + 2048 + d], mvr); dvr = fmaf(de[r][1], t1[tb + 1024 + d], dvr); }
        if (t > 2){ mvr = fmaf(ss[r][2], t2[tb + 2048 + d], mvr); dvr = fmaf(de[r][2], t2[tb + 1024 + d], dvr); }
      }
      float v = cur[(size_t)row * 1024 + d] + 0.34f * mvr + 0.22f * dvr
              + 0.18f * (sbbv + sv[r]);
      size_t ar = (size_t)row * 3072;
      uint16_t mh = f2bf(mvr);
      Arh[ar + 1024 + d] = mh; Arl[ar + 1024 + d] = f2bf(mvr - bf2f(mh));
      uint16_t dh = f2bf(dvr);
      Arh[ar + 2048 + d] = dh; Arl[ar + 2048 + d] = f2bf(dvr - bf2f(dh));
      sev[r][d] = v;
      if (r == 0) part0 += v; else if (r == 1) part1 += v;
      else if (r == 2) part2 += v; else part3 += v;
    }
  }
  // per-row mean
  {
    float p0 = wred(part0), p1 = wred(part1), p2 = wred(part2), p3 = wred(part3);
    if (lane == 0){ redm[0][wave] = p0; redm[1][wave] = p1; redm[2][wave] = p2; redm[3][wave] = p3; }
  }
  __syncthreads();
  float mean0 = (redm[0][0]+redm[0][1]+redm[0][2]+redm[0][3]) * (1.f/1024.f);
  float mean1 = (redm[1][0]+redm[1][1]+redm[1][2]+redm[1][3]) * (1.f/1024.f);
  float mean2 = (redm[2][0]+redm[2][1]+redm[2][2]+redm[2][3]) * (1.f/1024.f);
  float mean3 = (redm[3][0]+redm[3][1]+redm[3][2]+redm[3][3]) * (1.f/1024.f);
  float vp0 = 0.f, vp1 = 0.f, vp2 = 0.f, vp3 = 0.f;
#pragma unroll
  for (int j = 0; j < 4; j++){
    int d = tid + j * 256;
    float d0 = sev[0][d] - mean0; vp0 = fmaf(d0, d0, vp0);
    float d1 = sev[1][d] - mean1; vp1 = fmaf(d1, d1, vp1);
    float d2 = sev[2][d] - mean2; vp2 = fmaf(d2, d2, vp2);
    float d3 = sev[3][d] - mean3; vp3 = fmaf(d3, d3, vp3);
  }
  {
    float p0 = wred(vp0), p1 = wred(vp1), p2 = wred(vp2), p3 = wred(vp3);
    if (lane == 0){ redm[0][4+wave] = p0; redm[1][4+wave] = p1; redm[2][4+wave] = p2; redm[3][4+wave] = p3; }
  }
  __syncthreads();
  float rs0 = 1.f / sqrtf((redm[0][4]+redm[0][5]+redm[0][6]+redm[0][7]) * (1.f/1024.f) + 1e-5f);
  float rs1 = 1.f / sqrtf((redm[1][4]+redm[1][5]+redm[1][6]+redm[1][7]) * (1.f/1024.f) + 1e-5f);
  float rs2 = 1.f / sqrtf((redm[2][4]+redm[2][5]+redm[2][6]+redm[2][7]) * (1.f/1024.f) + 1e-5f);
  float rs3 = 1.f / sqrtf((redm[3][4]+redm[3][5]+redm[3][6]+redm[3][7]) * (1.f/1024.f) + 1e-5f);
#pragma unroll 1
  for (int j = 0; j < 4; j++){
    int d = tid + j * 256;
    float lg = lng[t * 1024 + d], lb = lnbv[t * 1024 + d];
    float mean[4] = {mean0, mean1, mean2, mean3};
    float rs[4] = {rs0, rs1, rs2, rs3};
#pragma unroll
    for (int r = 0; r < 4; r++){
      int row = row0 + r;
      size_t idx = (size_t)row * 1024 + d;
      float v0 = sev[r][d];
      enr[idx] = v0;
      float v = (v0 - mean[r]) * rs[r] * lg + lb;
      uint16_t h = f2bf(v);
      lnh[idx] = h;
      lnl[idx] = f2bf(v - bf2f(h));
    }
  }
}

// ---------------- route_fin: sums 4 K-split partials, softmaxes, top-k ----------
__global__ __launch_bounds__(256)
void route_fin(const float* __restrict__ ROq, const float* __restrict__ mmb,
               const float* __restrict__ msb, const float* __restrict__ ebias,
               const float* __restrict__ bb, const float* __restrict__ wgb,
               const float* __restrict__ hb,
               float* __restrict__ sg, float* __restrict__ haltb,
               float* __restrict__ Ac, float* __restrict__ W0,
               float* __restrict__ W1, float* __restrict__ W2,
               int* __restrict__ cnt, int* __restrict__ gidx,
               int* __restrict__ pos, float* __restrict__ routeS, int t)
{
  int row = blockIdx.x * 256 + threadIdx.x;
  int lane = threadIdx.x & 63;
  const size_t P = (size_t)N_TOK * 128;
  const float* r0 = ROq + (size_t)row * 128;
  const float* r1 = r0 + P;
  const float* r2 = r0 + 2 * P;
  const float* r3 = r0 + 3 * P;
  auto R = [&](int j){ return r0[j] + r1[j] + r2[j] + r3[j]; };
  float pm[4];
#pragma unroll
  for (int o = 0; o < 4; o++) pm[o] = R(40 + o) + mmb[o];
  float mmx = fmaxf(fmaxf(pm[0], pm[1]), fmaxf(pm[2], pm[3]));
  float msum = 0.f;
#pragma unroll
  for (int o = 0; o < 4; o++){ pm[o] = expf(pm[o] - mmx); msum += pm[o]; }
  float minv = 1.f / msum;
  float gl[10];
#pragma unroll
  for (int e = 0; e < 10; e++){
    float g = ebias[e];
#pragma unroll
    for (int s2 = 0; s2 < 4; s2++)
      g = fmaf(pm[s2] * minv, R(s2 * 10 + e) + msb[s2 * 10 + e], g);
    gl[e] = g;
  }
  float gmx = gl[0];
#pragma unroll
  for (int e = 1; e < 10; e++) gmx = fmaxf(gmx, gl[e]);
  float gs = 0.f;
#pragma unroll
  for (int e = 0; e < 10; e++){ gl[e] = expf(gl[e] - gmx); gs += gl[e]; }
  float ginv = 1.f / gs;
#pragma unroll
  for (int e = 0; e < 10; e++) gl[e] *= ginv;
  float pb0 = R(44) + bb[0], pb1 = R(45) + bb[1], pb2 = R(46) + bb[2], pb3 = R(47) + bb[3];
  int bud = 1; float bbest = pb0;
  if (pb1 > bbest){ bbest = pb1; bud = 2; }
  if (pb2 > bbest){ bbest = pb2; bud = 3; }
  if (pb3 > bbest){ bbest = pb3; bud = 4; }
  float tv[4]; int ti[4]; unsigned used = 0;
#pragma unroll
  for (int j = 0; j < 4; j++){
    float best = -1e30f; int bi = 0;
#pragma unroll
    for (int e = 0; e < 10; e++){
      bool ok = (!((used >> e) & 1u)) && (gl[e] > best);
      if (ok){ best = gl[e]; bi = e; }
    }
    tv[j] = best; ti[j] = bi; used |= (1u << bi);
  }
  float ssum = tv[0];
  if (bud > 1) ssum += tv[1];
  if (bud > 2) ssum += tv[2];
  if (bud > 3) ssum += tv[3];
  float den = fmaxf(ssum, 1e-6f);
  float sup = 1.f - tv[0] / den;
  float sgv[10];
#pragma unroll
  for (int e = 0; e < 10; e++){
    float sv = 0.f;
#pragma unroll
    for (int j = 0; j < 4; j++) if (j < bud && ti[j] == e) sv = tv[j] / den;
    sgv[e] = sv;
    sg[row * 10 + e] = sv;
  }
  float pw[24];
#pragma unroll
  for (int m = 0; m < 24; m++) pw[m] = R(48 + m) + wgb[m];
  float wmx2 = pw[0];
#pragma unroll
  for (int m = 1; m < 24; m++) wmx2 = fmaxf(wmx2, pw[m]);
  float wsum = 0.f;
#pragma unroll
  for (int m = 0; m < 24; m++){ pw[m] = expf(pw[m] - wmx2); wsum += pw[m]; }
  float winv = 1.f / wsum;
#pragma unroll
  for (int m = 0; m < 24; m++){
    float c = sup * pw[m] * winv;
    float om = 1.f - c;
    Ac[row * 24 + m] *= om;
    if (t > 0) W0[row * 24 + m] *= om;
    if (t > 1) W1[row * 24 + m] *= om;
    if (t > 2) W2[row * 24 + m] *= om;
    if (t == 0)      W0[row * 24 + m] = c;
    else if (t == 1) W1[row * 24 + m] = c;
    else if (t == 2) W2[row * 24 + m] = c;
  }
  haltb[row] = 1.f / (1.f + expf(-(R(72) + hb[t])));
#pragma unroll
  for (int i = 0; i < 30; i++) routeS[row * 32 + i] = R(73 + i);
#pragma unroll
  for (int e = 0; e < 10; e++){
    bool act = sgv[e] != 0.f;
    unsigned long long mask = __ballot(act);
    int cw = __popcll(mask);
    int b0 = 0;
    if (lane == 0 && cw > 0) b0 = atomicAdd(&cnt[e], cw);
    b0 = __shfl(b0, 0, 64);
    if (act){
      int slot = b0 + __popcll(mask & ((1ull << lane) - 1ull));
      gidx[e * N_TOK + slot] = row;
      pos[row * 10 + e] = slot;
    }
  }
}

// ---------------- downfin: expert down + LN + gated acc + step finalize --------
__global__ __launch_bounds__(256)
void downfin_kernel(const uint16_t* __restrict__ HH, const int* __restrict__ pos,
                    const float* __restrict__ ED, const float* __restrict__ sg,
                    const float* __restrict__ eng, const float* __restrict__ enb,
                    const float* __restrict__ routeS, const float* __restrict__ haltb,
                    float* __restrict__ total, float* __restrict__ cumh)
{
  int lane = threadIdx.x & 63;
  int row = blockIdx.x * 4 + (threadIdx.x >> 6);
  float out[10] = {};
  for (int e = 0; e < NEXP; e++){
    float g = sg[row * 10 + e];
    if (g != 0.0f){
      int d = c_dims[e];
      int slot = pos[row * 10 + e];
      const uint16_t* hr = HH + (size_t)N_TOK * c_offs[e] + (size_t)slot * d;
      const float* wd = ED + (size_t)e * 10 * DMAX;
      float p[10] = {};
      for (int k = lane * 4; k < d; k += 256){
        uint2 hv = *(const uint2*)&hr[k];
        float h0 = bf2f((uint16_t)hv.x), h1 = bf2f((uint16_t)(hv.x >> 16));
        float h2 = bf2f((uint16_t)hv.y), h3 = bf2f((uint16_t)(hv.y >> 16));
#pragma unroll
        for (int o = 0; o < 10; o++){
          float4 w4 = *(const float4*)&wd[o * DMAX + k];
          p[o] = fmaf(h0, w4.x, fmaf(h1, w4.y, fmaf(h2, w4.z, fmaf(h3, w4.w, p[o]))));
        }
      }
#pragma unroll
      for (int o = 0; o < 10; o++) p[o] = wred(p[o]);
      float mean = 0.f;
#pragma unroll
      for (int o = 0; o < 10; o++) mean += p[o];
      mean *= 0.1f;
      float var = 0.f;
#pragma unroll
      for (int o = 0; o < 10; o++){ float dd = p[o] - mean; var += dd * dd; }
      var *= 0.1f;
      float rs = 1.f / sqrtf(var + 1e-5f);
#pragma unroll
      for (int o = 0; o < 10; o++)
        out[o] += g * ((p[o] - mean) * rs * eng[e * 10 + o] + enb[e * 10 + o]);
    }
  }
  if (lane == 0){
    const float* r = routeS + (size_t)row * 32;
    float rem = 1.f - cumh[row];
#pragma unroll
    for (int o = 0; o < 10; o++)
      total[row * 10 + o] += rem * (out[o] + 0.22f * r[o] + 0.14f * r[10 + o]);
    cumh[row] += rem * haltb[row];
  }
}

// ---------------- shared branch --------------------------------------------------
__global__ __launch_bounds__(256)
void shared_kernel(const float* __restrict__ shpre, const float* __restrict__ sdw,
                   const float* __restrict__ g, const float* __restrict__ b,
                   float* __restrict__ outp)
{
  int lane = threadIdx.x & 63;
  int row = blockIdx.x * 4 + (threadIdx.x >> 6);
  const float* xr = shpre + (size_t)row * SHD;
  float p[10];
#pragma unroll
  for (int o = 0; o < 10; o++) p[o] = 0.f;
  for (int k = lane; k < SHD; k += 64){
    float xv = xr[k];
#pragma unroll
    for (int o = 0; o < 10; o++) p[o] = fmaf(xv, sdw[o * SHD + k], p[o]);
  }
#pragma unroll
  for (int o = 0; o < 10; o++) p[o] = wred(p[o]);
  float mean = 0.f;
#pragma unroll
  for (int o = 0; o < 10; o++) mean += p[o];
  mean *= 0.1f;
  float var = 0.f;
#pragma unroll
  for (int o = 0; o < 10; o++){ float dd = p[o] - mean; var += dd * dd; }
  var *= 0.1f;
  float rs = 1.f / sqrtf(var + 1e-5f);
  if (lane == 0){
#pragma unroll
    for (int o = 0; o < 10; o++) outp[row * 10 + o] = (p[o] - mean) * rs * g[o] + b[o];
  }
}

// ---------------- final output (lite) --------------------------------------------
__global__ __launch_bounds__(256)
void final_lite(const float* __restrict__ qaux, const float* __restrict__ biasp,
                const float* __restrict__ sharedp, const float* __restrict__ total,
                const float* __restrict__ routeS, const float* __restrict__ sscale,
                const float* __restrict__ alphap, const float* __restrict__ betap,
                float* __restrict__ outp)
{
  int row = blockIdx.x * 256 + threadIdx.x;
  float ss = sscale[0], av = alphap[0] + 1e-4f, bv = betap[0];
#pragma unroll
  for (int o = 0; o < 10; o++)
    outp[row * 10 + o] = (qaux[(size_t)row * 128 + 64 + o] + biasp[o])
                       + ss * sharedp[row * 10 + o]
                       + av * (total[row * 10 + o] * 0.25f)
                       + bv * routeS[(size_t)row * 32 + 20 + o];
}

// ====================================================================================
extern "C" void kernel_launch(void* const* d_in, const int* in_sizes, int n_in,
                              void* d_out, int out_size, void* d_ws, size_t ws_size,
                              hipStream_t stream)
{
  const float* x     = (const float*)d_in[0];
  const float* wgt   = (const float*)d_in[1];
  const float* bias  = (const float*)d_in[2];
  const float* suw   = (const float*)d_in[3];
  const float* sdw   = (const float*)d_in[4];
  const float* sng   = (const float*)d_in[5];
  const float* snb   = (const float*)d_in[6];
  const float* sscale= (const float*)d_in[7];
  const float* keys  = (const float*)d_in[8];
  const float* mvi   = (const float*)d_in[9];
  const float* mqw   = (const float*)d_in[10];
  const float* mow   = (const float*)d_in[11];
  const float* wgw   = (const float*)d_in[12];
  const float* wgb   = (const float*)d_in[13];
  const float* wvw   = (const float*)d_in[14];
  const float* wvb   = (const float*)d_in[15];
  const float* dqw   = (const float*)d_in[16];
  const float* dkw   = (const float*)d_in[17];
  const float* dvw   = (const float*)d_in[18];
  const float* dow   = (const float*)d_in[19];
  const float* clng  = (const float*)d_in[20];
  const float* clnb  = (const float*)d_in[21];
  const float* fc1w  = (const float*)d_in[22];
  const float* fc1b  = (const float*)d_in[23];
  const float* fc2w  = (const float*)d_in[24];
  const float* fc2b  = (const float*)d_in[25];
  const float* saw   = (const float*)d_in[26];
  const float* sab   = (const float*)d_in[27];
  const float* sbw   = (const float*)d_in[28];
  const float* sbb   = (const float*)d_in[29];
  const float* msw   = (const float*)d_in[30];
  const float* msb   = (const float*)d_in[31];
  const float* mmw   = (const float*)d_in[32];
  const float* mmb   = (const float*)d_in[33];
  const float* ebias = (const float*)d_in[34];
  const float* bw    = (const float*)d_in[35];
  const float* bb    = (const float*)d_in[36];
  const float* eup   = (const float*)d_in[37];
  const float* edn   = (const float*)d_in[38];
  const float* eng   = (const float*)d_in[39];
  const float* enb   = (const float*)d_in[40];
  const float* hw    = (const float*)d_in[41];
  const float* hb    = (const float*)d_in[42];
  const float* alphap= (const float*)d_in[43];
  const float* betap = (const float*)d_in[44];
  float* outp = (float*)d_out;

  char* wsb = (char*)d_ws;
  size_t off = 0;
  auto AL = [&](size_t bytes) -> void* {
    void* p = wsb + off;
    off = (off + bytes + 255) & ~(size_t)255;
    return p;
  };
  const size_t NI = (size_t)N_TOK * IN_D;
  float* cur    = (float*)AL(NI * 4);
  float* enr    = (float*)AL(NI * 4);
  float* dqbuf  = (float*)AL(NI * 4);
  float* qaux   = (float*)AL((size_t)N_TOK * 128 * 4);
  float* routeQ = (float*)AL((size_t)4 * N_TOK * 128 * 4);
  float* routeS = (float*)AL((size_t)N_TOK * 32 * 4);
  float* trio0  = (float*)AL((size_t)N_TOK * 3072 * 4);
  float* trio1  = (float*)AL((size_t)N_TOK * 3072 * 4);
  float* trio2  = (float*)AL((size_t)N_TOK * 3072 * 4);
  float* Ac     = (float*)AL((size_t)N_TOK * 24 * 4);
  float* W0     = (float*)AL((size_t)N_TOK * 24 * 4);
  float* W1     = (float*)AL((size_t)N_TOK * 24 * 4);
  float* W2     = (float*)AL((size_t)N_TOK * 24 * 4);
  float* sg     = (float*)AL((size_t)N_TOK * 10 * 4);
  float* haltb  = (float*)AL((size_t)N_TOK * 4);
  char*  zblk   = (char*)AL((size_t)N_TOK * 10 * 4 + N_TOK * 4 + 4 * 16 * 4);
  float* total  = (float*)zblk;
  float* cumh   = (float*)(zblk + (size_t)N_TOK * 10 * 4);
  int*   cnt    = (int*)(zblk + (size_t)N_TOK * 10 * 4 + N_TOK * 4);
  int*   gidx   = (int*)AL((size_t)NEXP * N_TOK * 4);
  int*   pos    = (int*)AL((size_t)N_TOK * NEXP * 4);
  float* sharedp= (float*)AL((size_t)N_TOK * 10 * 4);
  float* cbias  = (float*)AL(3072 * 4);
  float* K2f    = (float*)AL((size_t)24 * 1024 * 4);
  float* sbwT   = (float*)AL((size_t)40 * 1024 * 4);
  uint16_t* lnh  = (uint16_t*)AL(NI * 2);
  uint16_t* lnl  = (uint16_t*)AL(NI * 2);
  uint16_t* h7h  = (uint16_t*)AL((size_t)N_TOK * INNER * 2);
  uint16_t* h7l  = (uint16_t*)AL((size_t)N_TOK * INNER * 2);
  uint16_t* Arh  = (uint16_t*)AL((size_t)N_TOK * 3072 * 2);
  uint16_t* Arl  = (uint16_t*)AL((size_t)N_TOK * 3072 * 2);
  const size_t W1M = (size_t)IN_D * IN_D;
  uint16_t* preWh  = (uint16_t*)AL((size_t)2176 * 1024 * 2);
  uint16_t* preWl  = (uint16_t*)AL((size_t)2176 * 1024 * 2);
  uint16_t* qtWh   = (uint16_t*)AL((size_t)4224 * 1024 * 2);
  uint16_t* qtWl   = (uint16_t*)AL((size_t)4224 * 1024 * 2);
  uint16_t* rtWh   = (uint16_t*)AL((size_t)4 * 128 * 3072 * 2);
  uint16_t* rtWl   = (uint16_t*)AL((size_t)4 * 128 * 3072 * 2);
  const size_t WFC = (size_t)NSTEP * INNER * IN_D;
  uint16_t* fc1wh = (uint16_t*)AL(WFC * 2); uint16_t* fc1wl = (uint16_t*)AL(WFC * 2);
  uint16_t* fc2wh = (uint16_t*)AL(WFC * 2); uint16_t* fc2wl = (uint16_t*)AL(WFC * 2);
  uint8_t* upbf8 = (uint8_t*)AL((size_t)NEXP * DMAX * IN_D);
  uint8_t* A8    = (uint8_t*)AL(NI);
  uint16_t* HHc  = (uint16_t*)AL((size_t)N_TOK * DSUM * 2);
  float* shpre  = (float*)HHc;   // alias: consumed before HHc is written

  // ---- init ----
  hipMemsetAsync(zblk, 0, (size_t)N_TOK * 10 * 4 + N_TOK * 4 + 4 * 16 * 4, stream);
  hipMemsetAsync(cbias, 0, 3072 * 4, stream);
  hipMemcpyAsync(cbias + 2048, wvb, 1024 * 4, hipMemcpyDeviceToDevice, stream);
  hipMemcpyAsync(cur, x, NI * 4, hipMemcpyDeviceToDevice, stream);
  fill1_kernel<<<(N_TOK * 24 + 255) / 256, 256, 0, stream>>>(Ac, N_TOK * 24);
  cvt_fp8_kernel<<<2048, 256, 0, stream>>>(eup, upbf8, (size_t)NEXP * DMAX * IN_D);
  tr_sbw_kernel<<<160, 256, 0, stream>>>(sbw, sbwT);

  split_strided<<<1024, 256, 0, stream>>>(x, Arh, Arl, N_TOK, 1024, 3072);
  split_kernel<<<1024, 256, 0, stream>>>(suw, preWh, preWl, (size_t)SHD * 1024);
  split_kernel<<<256, 256, 0, stream>>>(saw, preWh + (size_t)2072*1024, preWl + (size_t)2072*1024, (size_t)40 * 1024);
  split_kernel<<<256, 256, 0, stream>>>(wgt, preWh + (size_t)2112*1024, preWl + (size_t)2112*1024, (size_t)10 * 1024);
  hipMemsetAsync(preWh + (size_t)2122*1024, 0, (size_t)54 * 1024 * 2, stream);
  hipMemsetAsync(preWl + (size_t)2122*1024, 0, (size_t)54 * 1024 * 2, stream);
  split_kernel<<<1024, 256, 0, stream>>>(dqw, qtWh, qtWl, W1M);
  split_kernel<<<1024, 256, 0, stream>>>(dkw, qtWh + W1M, qtWl + W1M, W1M);
  split_kernel<<<1024, 256, 0, stream>>>(dvw, qtWh + 2*W1M, qtWl + 2*W1M, W1M);
  split_kernel<<<1024, 256, 0, stream>>>(wvw, qtWh + 3*W1M, qtWl + 3*W1M, W1M);
  split_kernel<<<256, 256, 0, stream>>>(saw, qtWh + (size_t)4120*1024, qtWl + (size_t)4120*1024, (size_t)40 * 1024);
  hipMemsetAsync(qtWh + (size_t)4160*1024, 0, (size_t)64 * 1024 * 2, stream);
  hipMemsetAsync(qtWl + (size_t)4160*1024, 0, (size_t)64 * 1024 * 2, stream);
  k2_kernel<<<dim3(24, 4), 256, 0, stream>>>(keys, mqw, K2f);
  split_kernel<<<256, 256, 0, stream>>>(K2f, preWh + (size_t)2048*1024, preWl + (size_t)2048*1024, (size_t)24 * 1024);
  split_kernel<<<256, 256, 0, stream>>>(K2f, qtWh + (size_t)4096*1024, qtWl + (size_t)4096*1024, (size_t)24 * 1024);
  build_routew<<<2048, 256, 0, stream>>>(msw, mmw, bw, wgw, hw, mow, dow, rtWh, rtWl);
  split_kernel<<<1024, 256, 0, stream>>>(fc1w, fc1wh, fc1wl, WFC);
  split_kernel<<<1024, 256, 0, stream>>>(fc2w, fc2wh, fc2wl, WFC);

  gemm_sp<EPI_PRE><<<dim3(17, 16), 256, 0, stream>>>(
      Arh, Arl, 3072, preWh, preWl, nullptr, nullptr, nullptr, nullptr,
      shpre, qaux, nullptr, nullptr, nullptr, nullptr, nullptr, IN_D, 2176);
  shared_kernel<<<512, 256, 0, stream>>>(shpre, sdw, sng, snb, sharedp);

  float* trioB[3] = {trio0, trio1, trio2};

  for (int t = 0; t < NSTEP; t++){
    ctx_enr_kernel<<<512, 256, 0, stream>>>(qaux, dqbuf, Ac, W0, W1, W2, mvi,
                                            trio0, trio1, trio2, cur, sab, sbwT, sbb,
                                            clng, clnb, enr, lnh, lnl, Arh, Arl, t);
    gemm_sp<EPI_GELU><<<dim3(INNER/128, 16), 256, 0, stream>>>(
        lnh, lnl, 1024, fc1wh + (size_t)t * INNER * IN_D, fc1wl + (size_t)t * INNER * IN_D,
        nullptr, nullptr, fc1b + t * INNER, nullptr,
        nullptr, nullptr, nullptr, nullptr, nullptr, h7h, h7l, IN_D, INNER);
    gemm_sp<EPI_CUR><<<dim3(8, 16), 256, 0, stream>>>(
        h7h, h7l, 768, fc2wh + (size_t)t * IN_D * INNER, fc2wl + (size_t)t * IN_D * INNER,
        nullptr, nullptr, fc2b + t * IN_D, enr,
        cur, nullptr, nullptr, nullptr, A8, Arh, Arl, INNER, IN_D);
    gemm_sp<EPI_QROUTE><<<dim3(t < 3 ? 37 : 4, 16), 256, 0, stream>>>(
        Arh, Arl, 3072, qtWh, qtWl,
        rtWh + (size_t)t * 128 * 3072, rtWl + (size_t)t * 128 * 3072,
        cbias, nullptr, dqbuf, t < 3 ? trioB[t] : nullptr, qaux, routeQ,
        nullptr, nullptr, nullptr, IN_D, 4224);
    route_fin<<<8, 256, 0, stream>>>(routeQ, mmb, msb, ebias, bb, wgb, hb,
                                     sg, haltb, Ac, W0, W1, W2,
                                     cnt + t * 16, gidx, pos, routeS, t);
    expert_up_mfma<<<768, 256, 0, stream>>>(A8, upbf8, cnt + t * 16, gidx, HHc);
    downfin_kernel<<<512, 256, 0, stream>>>(HHc, pos, edn, sg, eng, enb,
                                            routeS, haltb, total, cumh);
  }
  final_lite<<<8, 256, 0, stream>>>(qaux, bias, sharedp, total, routeS,
                                    sscale, alphap, betap, outp);
}